// Round 12
// baseline (239.102 us; speedup 1.0000x reference)
//
#include <hip/hip_runtime.h>
#include <hip/hip_bf16.h>
#include <math.h>

// Problem constants: x [8,64,64,64] fp32 NCHW, W_std [64,64,3,3] fp32 OIHW.
#define BB 8
#define CC 64
#define HH 64
#define WW 64
#define NPIX (HH*WW)   // 4096
#define LOG2E 1.44269504088896340736f

typedef __attribute__((ext_vector_type(8))) short bf16x8;            // MFMA A/B frag
typedef __attribute__((ext_vector_type(4))) float floatx4;           // MFMA C/D frag
typedef __attribute__((ext_vector_type(8))) unsigned short ushort8;  // 16B unit

__device__ inline unsigned short f2bf(float x) {
  __hip_bfloat16 h = __float2bfloat16(x);
  return *reinterpret_cast<unsigned short*>(&h);
}
__device__ inline float bf2f(unsigned short u) {
  __hip_bfloat16 h = *reinterpret_cast<__hip_bfloat16*>(&u);
  return __bfloat162float(h);
}

// XOR swizzle: 16B channel-chunks permuted within each 128B row so MFMA
// fragment reads from LDS (lane stride 128B) spread across all 32 banks.
__device__ inline int swzoff(int n, int c) {
  return (((c >> 3) ^ (n & 7)) << 3) | (c & 7);
}
__device__ inline int swzvslot(int key, int c) {
  return (((key >> 3) ^ (c & 7)) << 3) | (key & 7);
}

// 16B global -> LDS DMA
#define GLD_LDS16(gp, lp)                                                     \
  __builtin_amdgcn_global_load_lds(                                           \
      (const __attribute__((address_space(1))) void*)(gp),                    \
      (__attribute__((address_space(3))) void*)(lp), 16, 0, 0)

// ---------------------------------------------------------------------------
// wprep: WT[tap][o][c] bf16 hi/lo with the depthwise Laplacian FOLDED IN.
// ---------------------------------------------------------------------------
__global__ void wprep_kernel(const float* __restrict__ w,
                             unsigned short* __restrict__ wth,
                             unsigned short* __restrict__ wtl) {
  const int idx = blockIdx.x * 256 + threadIdx.x;   // 9*64*64 = 36864
  const int c   = idx & 63;
  const int o   = (idx >> 6) & 63;
  const int tap = idx >> 12;                        // 0..8
  float v = w[((o * 64 + c) * 9) + tap];
  if (o == c) {
    const float lapk[9] = {0.f, 1.f, 0.f, 1.f, -4.f, 1.f, 0.f, 1.f, 0.f};
    v += lapk[tap];
  }
  const unsigned short hi = f2bf(v);
  wth[(tap * 64 + o) * 64 + c] = hi;
  wtl[(tap * 64 + o) * 64 + c] = f2bf(v - bf2f(hi));
}

// ---------------------------------------------------------------------------
// xt: x [b][c][y][x] fp32 -> XT [b][n][c] bf16 hi/lo, swizzled like fh.
// ---------------------------------------------------------------------------
__global__ __launch_bounds__(256) void xt_kernel(
    const float* __restrict__ xin,
    unsigned short* __restrict__ xth, unsigned short* __restrict__ xtl) {
  __shared__ float XL[64][65];
  const int tid = threadIdx.x;
  const int y = blockIdx.x, b = blockIdx.y;
  const int xq = tid & 15, cw = tid >> 4;
  const float* xb = xin + (size_t)b * CC * NPIX + y * WW;
#pragma unroll
  for (int p = 0; p < 4; ++p) {
    const int c = p * 16 + cw;
    const float4 v = *(const float4*)(xb + (size_t)c * NPIX + xq * 4);
    XL[c][xq * 4 + 0] = v.x; XL[c][xq * 4 + 1] = v.y;
    XL[c][xq * 4 + 2] = v.z; XL[c][xq * 4 + 3] = v.w;
  }
  __syncthreads();
  const int px = tid & 63, cp = tid >> 6;
  const size_t nb = ((size_t)b * NPIX + y * WW + px) * CC;
  ushort8 vh[2], vl[2];
#pragma unroll
  for (int j = 0; j < 16; ++j) {
    const float v = XL[cp * 16 + j][px];
    const unsigned short hh = f2bf(v);
    vh[j >> 3][j & 7] = hh;
    vl[j >> 3][j & 7] = f2bf(v - bf2f(hh));
  }
#pragma unroll
  for (int k = 0; k < 2; ++k) {
    const int ch = cp * 2 + k;
    const int off = ((ch ^ (px & 7)) << 3);
    *(ushort8*)(xth + nb + off) = vh[k];
    *(ushort8*)(xtl + nb + off) = vl[k];
  }
}

// ---------------------------------------------------------------------------
// conv_mfma: implicit-GEMM conv (unchanged from round 7).
// ---------------------------------------------------------------------------
__global__ __launch_bounds__(256, 2) void conv_mfma(
    const unsigned short* __restrict__ xth,
    const unsigned short* __restrict__ xtl,
    const unsigned short* __restrict__ wth,
    const unsigned short* __restrict__ wtl,
    unsigned short* __restrict__ fh, unsigned short* __restrict__ fl,
    unsigned short* __restrict__ fv) {
  __shared__ __align__(16) unsigned short XS[6 * 4096];

  const int tid  = threadIdx.x;
  const int lane = tid & 63;
  const int wave = tid >> 6;
  const int r16  = lane & 15;
  const int quad = lane >> 4;
  const int y = blockIdx.x, b = blockIdx.y;

#pragma unroll
  for (int r = 0; r < 3; ++r) {
    const int yy = min(max(y - 1 + r, 0), HH - 1);
    const unsigned short* sh = xth + ((size_t)b * NPIX + yy * WW) * CC;
    const unsigned short* sl = xtl + ((size_t)b * NPIX + yy * WW) * CC;
    GLD_LDS16(sh + tid * 8,        &XS[r * 4096 + tid * 8]);
    GLD_LDS16(sh + 2048 + tid * 8, &XS[r * 4096 + 2048 + tid * 8]);
    GLD_LDS16(sl + tid * 8,        &XS[(3 + r) * 4096 + tid * 8]);
    GLD_LDS16(sl + 2048 + tid * 8, &XS[(3 + r) * 4096 + 2048 + tid * 8]);
  }
  __syncthreads();

  floatx4 acc[4];
#pragma unroll
  for (int t = 0; t < 4; ++t) acc[t] = (floatx4){0.f, 0.f, 0.f, 0.f};
  const bf16x8 ZF = {0, 0, 0, 0, 0, 0, 0, 0};
  const int og = wave * 16 + r16;

#pragma unroll
  for (int tap = 0; tap < 9; ++tap) {
    const int ky = tap / 3, kx = tap % 3;
    const int yy = y + ky - 1;
    if (yy < 0 || yy >= HH) continue;
    const unsigned short* wt = wth + ((tap * 64 + og) << 6);
    const unsigned short* wl = wtl + ((tap * 64 + og) << 6);
    const bf16x8 Wh0 = *(const bf16x8*)(wt + quad * 8);
    const bf16x8 Wh1 = *(const bf16x8*)(wt + 32 + quad * 8);
    const bf16x8 Wl0 = *(const bf16x8*)(wl + quad * 8);
    const bf16x8 Wl1 = *(const bf16x8*)(wl + 32 + quad * 8);
#pragma unroll
    for (int t = 0; t < 4; ++t) {
      const int px = t * 16 + r16 + kx - 1;
      const bool ok = (px >= 0) && (px < WW);
      const int pxc = ok ? px : 0;
      const int bh = ky * 4096 + pxc * 64;
      const int bl = bh + 3 * 4096;
      const int o0 = ((quad ^ (pxc & 7)) << 3);
      const int o1 = (((4 + quad) ^ (pxc & 7)) << 3);
      bf16x8 Ah0 = *(const bf16x8*)(XS + bh + o0);
      bf16x8 Ah1 = *(const bf16x8*)(XS + bh + o1);
      bf16x8 Al0 = *(const bf16x8*)(XS + bl + o0);
      bf16x8 Al1 = *(const bf16x8*)(XS + bl + o1);
      if (!ok) { Ah0 = ZF; Ah1 = ZF; Al0 = ZF; Al1 = ZF; }
      acc[t] = __builtin_amdgcn_mfma_f32_16x16x32_bf16(Ah0, Wh0, acc[t], 0, 0, 0);
      acc[t] = __builtin_amdgcn_mfma_f32_16x16x32_bf16(Ah1, Wh1, acc[t], 0, 0, 0);
      acc[t] = __builtin_amdgcn_mfma_f32_16x16x32_bf16(Ah0, Wl0, acc[t], 0, 0, 0);
      acc[t] = __builtin_amdgcn_mfma_f32_16x16x32_bf16(Ah1, Wl1, acc[t], 0, 0, 0);
      acc[t] = __builtin_amdgcn_mfma_f32_16x16x32_bf16(Al0, Wh0, acc[t], 0, 0, 0);
      acc[t] = __builtin_amdgcn_mfma_f32_16x16x32_bf16(Al1, Wh1, acc[t], 0, 0, 0);
    }
  }

#pragma unroll
  for (int t = 0; t < 4; ++t)
#pragma unroll
    for (int r = 0; r < 4; ++r) {
      const int key = t * 16 + quad * 4 + r;
      const int n = y * WW + key;
      const float v = acc[t][r];
      const unsigned short hi = f2bf(v);
      const unsigned short lo = f2bf(v - bf2f(hi));
      fh[((size_t)b * NPIX + n) * CC + swzoff(n, og)] = hi;
      fl[((size_t)b * NPIX + n) * CC + swzoff(n, og)] = lo;
      fv[(((size_t)b * (NPIX >> 6) + y) * CC + og) * 64 + swzvslot(key, og)] = hi;
    }
}

// ---------------------------------------------------------------------------
// 2x2 average pool on swizzled layout (unchanged).
// ---------------------------------------------------------------------------
__global__ void pool2_kernel(const unsigned short* __restrict__ in_h,
                             const unsigned short* __restrict__ in_l,
                             unsigned short* __restrict__ out_h,
                             unsigned short* __restrict__ out_l,
                             unsigned short* __restrict__ out_v, int hw_out) {
  const int idx = blockIdx.x * blockDim.x + threadIdx.x;
  const int c  = idx & 63;
  const int t  = idx >> 6;
  const int xo = t % hw_out;
  const int r  = t / hw_out;
  const int yo = r % hw_out;
  const int b  = r / hw_out;
  const int win = 2 * hw_out;
  const size_t ibase = (size_t)b * win * win * CC;
  float s = 0.f;
#pragma unroll
  for (int dy = 0; dy < 2; ++dy)
#pragma unroll
    for (int dx = 0; dx < 2; ++dx) {
      const int nin = (2*yo+dy) * win + (2*xo+dx);
      const size_t a = ibase + (size_t)nin * CC + swzoff(nin, c);
      s += bf2f(in_h[a]) + bf2f(in_l[a]);
    }
  const float vv = 0.25f * s;
  const unsigned short hi = f2bf(vv);
  const unsigned short lo = f2bf(vv - bf2f(hi));
  const int nout = yo * hw_out + xo;
  const int Nout = hw_out * hw_out;
  const size_t ob = ((size_t)b * Nout + nout) * CC + swzoff(nout, c);
  out_h[ob] = hi;
  out_l[ob] = lo;
  out_v[(((size_t)b * (Nout >> 6) + (nout >> 6)) * CC + c) * 64
        + swzvslot(nout & 63, c)] = hi;
}

// ---------------------------------------------------------------------------
// MFMA flash attention <NH, KS>. Round-12 change: V^T is NOT staged in LDS —
// V-frags read straight from global fv (per-XCD L2-resident via b=blk&7
// swizzle; only 8 b128/tile/wave). LDS drops 57.4 -> 42 KB => 3 blocks/CU
// (12 waves/CU, +50% chain overlap). Rounds 9/11 showed 86us invariant to
// NH/KS at 2 blocks/CU => latency-chain-bound; occupancy is the lever.
// launch_bounds(256,3) caps VGPR at 168 (NH=2 compiled at 100 in round 9).
// ---------------------------------------------------------------------------
#define STR 72   // P-tile LDS row stride (shorts); 144B keeps b128 aligned

template <int NH, int KS>
__global__ __launch_bounds__(256, 3) void attn_mfma(
    const unsigned short* __restrict__ fh,
    const unsigned short* __restrict__ fl,
    const unsigned short* __restrict__ fv,
    float* __restrict__ outF, unsigned short* __restrict__ outB,
    float* __restrict__ outL, int N) {
  __shared__ __align__(16) unsigned short KVT[2][2 * 4096];  // Kh | Kl only
  __shared__ __align__(16) unsigned short Pt[4][16 * STR];

  const int tid  = threadIdx.x;
  const int lane = tid & 63;
  const int wave = tid >> 6;
  const int b    = blockIdx.x & 7;              // XCD-local batch grouping
  const int rest = blockIdx.x >> 3;
  const int nq   = N / (64 * NH);
  const int qt   = rest % nq;
  const int ks   = rest / nq;                   // 0..KS-1
  const int q0   = qt * (64 * NH) + wave * (16 * NH);
  const int nt   = (N >> 6) / KS;
  const int t0   = ks * nt;
  const int r16  = lane & 15;
  const int quad = lane >> 4;
  const int swb  = r16 & 7;

  const unsigned short* fhB = fh + (size_t)b * N * CC;
  const unsigned short* flB = fl + (size_t)b * N * CC;
  const unsigned short* fvB = fv + (size_t)b * N * CC;   // tile-major V^T

  // ---- stage first K-tile via DMA: 16 chunks of 512 shorts; wave takes 4 --
  {
    const size_t tb = (size_t)t0 * 4096;
#pragma unroll
    for (int j = 0; j < 4; ++j) {
      const int cid = wave * 4 + j;
      const int arr = cid >> 3, sub = (cid & 7) << 9;
      const unsigned short* g = (arr == 0 ? fhB : flB) + tb + sub + lane * 8;
      GLD_LDS16(g, &KVT[0][arr * 4096 + sub + lane * 8]);
    }
  }

  // ---- Q fragments per half: scale by log2e, re-split hi/lo, compute M ----
  bf16x8 Qh[NH][2], Ql[NH][2];
  float Mq[NH][4];
#pragma unroll
  for (int h = 0; h < NH; ++h) {
    float Mpart = 0.f;
#pragma unroll
    for (int kss = 0; kss < 2; ++kss) {
      const size_t off = (size_t)(q0 + h * 16 + r16) * CC
                         + ((((kss << 2) + quad) ^ swb) << 3);
      const bf16x8 hh = *(const bf16x8*)(fhB + off);
      const bf16x8 ll = *(const bf16x8*)(flB + off);
      bf16x8 sh, sl;
#pragma unroll
      for (int j = 0; j < 8; ++j) {
        const float f = bf2f((unsigned short)hh[j]) + bf2f((unsigned short)ll[j]);
        const float g = f * LOG2E;
        const unsigned short gh = f2bf(g);
        sh[j] = (short)gh;
        sl[j] = (short)f2bf(g - bf2f(gh));
        Mpart += g * f;                  // = log2e * sum f^2 (partial)
      }
      Qh[h][kss] = sh;
      Ql[h][kss] = sl;
    }
    Mpart += __shfl_xor(Mpart, 16, 64);
    Mpart += __shfl_xor(Mpart, 32, 64);  // per-row |q|^2*log2e at lane r16
#pragma unroll
    for (int r = 0; r < 4; ++r) Mq[h][r] = __shfl(Mpart, quad * 4 + r, 64);
  }

  floatx4 O[NH][4];
  float lrun[NH][4];
#pragma unroll
  for (int h = 0; h < NH; ++h)
#pragma unroll
    for (int ch = 0; ch < 4; ++ch) {
      O[h][ch] = (floatx4){0.f, 0.f, 0.f, 0.f};
      lrun[h][ch] = 0.f;
    }
  unsigned short* pt = Pt[wave];

  int koff[2];
#pragma unroll
  for (int kss = 0; kss < 2; ++kss) koff[kss] = (((kss << 2) + quad) ^ swb) << 3;

  for (int t = 0; t < nt; ++t) {
    const int cur = t & 1;
    __syncthreads();                    // drains DMA for tile t, syncs block
    if (t + 1 < nt) {                   // issue K-DMA for tile t+1 now
      const size_t tb = (size_t)(t0 + t + 1) * 4096;
#pragma unroll
      for (int j = 0; j < 4; ++j) {
        const int cid = wave * 4 + j;
        const int arr = cid >> 3, sub = (cid & 7) << 9;
        const unsigned short* g = (arr == 0 ? fhB : flB) + tb + sub + lane * 8;
        GLD_LDS16(g, &KVT[cur ^ 1][arr * 4096 + sub + lane * 8]);
      }
    }
    const unsigned short* kh = &KVT[cur][0];
    const unsigned short* kl = &KVT[cur][4096];
    const unsigned short* vg = fvB + (size_t)(t0 + t) * 4096;  // V from global

    // ---- S-tiles: K-frags read once, shared across all NH halves ----
    floatx4 S[NH][4];
#pragma unroll
    for (int tt = 0; tt < 4; ++tt) {
      const int kbase = (tt * 16 + r16) * 64;
      const bf16x8 Kh0 = *(const bf16x8*)(kh + kbase + koff[0]);
      const bf16x8 Kh1 = *(const bf16x8*)(kh + kbase + koff[1]);
      const bf16x8 Kl0 = *(const bf16x8*)(kl + kbase + koff[0]);
      const bf16x8 Kl1 = *(const bf16x8*)(kl + kbase + koff[1]);
#pragma unroll
      for (int h = 0; h < NH; ++h) {
        floatx4 s = (floatx4){0.f, 0.f, 0.f, 0.f};
        s = __builtin_amdgcn_mfma_f32_16x16x32_bf16(Qh[h][0], Kh0, s, 0, 0, 0);
        s = __builtin_amdgcn_mfma_f32_16x16x32_bf16(Qh[h][1], Kh1, s, 0, 0, 0);
        s = __builtin_amdgcn_mfma_f32_16x16x32_bf16(Ql[h][0], Kh0, s, 0, 0, 0);
        s = __builtin_amdgcn_mfma_f32_16x16x32_bf16(Ql[h][1], Kh1, s, 0, 0, 0);
        s = __builtin_amdgcn_mfma_f32_16x16x32_bf16(Qh[h][0], Kl0, s, 0, 0, 0);
        s = __builtin_amdgcn_mfma_f32_16x16x32_bf16(Qh[h][1], Kl1, s, 0, 0, 0);
        S[h][tt] = s;
      }
    }

    // ---- per half: fixed-shift softmax, P round-trip (shared Pt rows) ----
    bf16x8 Pf[NH][2];
#pragma unroll
    for (int h = 0; h < NH; ++h) {
#pragma unroll
      for (int r = 0; r < 4; ++r) {
        float ls = 0.f;
#pragma unroll
        for (int tt = 0; tt < 4; ++tt) {
          const float p = __builtin_amdgcn_exp2f(S[h][tt][r] - Mq[h][r]);
          S[h][tt][r] = p;
          ls += p;
        }
        lrun[h][r] += ls;
      }
#pragma unroll
      for (int tt = 0; tt < 4; ++tt)
#pragma unroll
        for (int r = 0; r < 4; ++r)
          pt[(quad * 4 + r) * STR + tt * 16 + r16] = f2bf(S[h][tt][r]);
#pragma unroll
      for (int kss = 0; kss < 2; ++kss)
        Pf[h][kss] = *(const bf16x8*)(pt + r16 * STR + kss * 32 + quad * 8);
    }

    // ---- O += P*V: V-frags from global (L2), shared across halves ----
#pragma unroll
    for (int kss = 0; kss < 2; ++kss)
#pragma unroll
      for (int ch = 0; ch < 4; ++ch) {
        const bf16x8 Vf =
            *(const bf16x8*)(vg + (ch * 16 + r16) * 64 + koff[kss]);
#pragma unroll
        for (int h = 0; h < NH; ++h)
          O[h][ch] = __builtin_amdgcn_mfma_f32_16x16x32_bf16(Pf[h][kss], Vf,
                                                            O[h][ch], 0, 0, 0);
      }
  }

  // ---- epilogue ----
#pragma unroll
  for (int h = 0; h < NH; ++h) {
#pragma unroll
    for (int r = 0; r < 4; ++r) {
      float lt = lrun[h][r];
      lt += __shfl_xor(lt, 1, 16);
      lt += __shfl_xor(lt, 2, 16);
      lt += __shfl_xor(lt, 4, 16);
      lt += __shfl_xor(lt, 8, 16);
      if (KS == 1) {
        lrun[h][r] = 1.f / lt;
      } else if (r16 == 0) {
        outL[(size_t)ks * BB * N + (size_t)b * N + q0 + h * 16 + quad * 4 + r] = lt;
      }
    }
#pragma unroll
    for (int ch = 0; ch < 4; ++ch)
#pragma unroll
      for (int r = 0; r < 4; ++r) {
        const size_t qi = (size_t)b * N + q0 + h * 16 + quad * 4 + r;
        if (KS == 1) {
          outF[qi * CC + ch * 16 + r16] = O[h][ch][r] * lrun[h][r];
        } else {
          outB[(size_t)ks * BB * N * CC + qi * CC + ch * 16 + r16] =
              f2bf(O[h][ch][r]);
        }
      }
  }
}

// ---------------------------------------------------------------------------
// combine: sum KS bf16 O-partials + KS l-partials (coalesced along c),
// normalize, LDS-transpose, write CHANNEL-MAJOR fp32 outC[b][c][n].
// ---------------------------------------------------------------------------
template <int KS>
__global__ __launch_bounds__(256) void combine_kernel(
    const unsigned short* __restrict__ Op, const float* __restrict__ Lp,
    float* __restrict__ outC, int N) {
  __shared__ float T[64][65];
  const int tid = threadIdx.x;
  const int nt  = N >> 6;
  const int b   = blockIdx.x / nt;
  const int n0  = (blockIdx.x % nt) * 64;
  const int nl  = tid >> 2;            // local n (0..63)
  const int ck  = (tid & 3) * 16;      // c chunk base
  const int n   = n0 + nl;

  float lv = 0.f;
#pragma unroll
  for (int ks = 0; ks < KS; ++ks)
    lv += Lp[(size_t)ks * BB * N + (size_t)b * N + n];
  const float inv = 1.f / lv;

  float v[16];
#pragma unroll
  for (int j = 0; j < 16; ++j) v[j] = 0.f;
#pragma unroll
  for (int ks = 0; ks < KS; ++ks) {
    const unsigned short* src =
        Op + (size_t)ks * BB * N * CC + ((size_t)b * N + n) * CC + ck;
    const ushort8 u0 = *(const ushort8*)(src);
    const ushort8 u1 = *(const ushort8*)(src + 8);
#pragma unroll
    for (int j = 0; j < 8; ++j) {
      v[j]     += bf2f(u0[j]);
      v[8 + j] += bf2f(u1[j]);
    }
  }
#pragma unroll
  for (int j = 0; j < 16; ++j) T[ck + j][nl] = v[j] * inv;
  __syncthreads();

  const int cw = tid >> 2;             // channel row to write
  const int nk = (tid & 3) * 16;       // n chunk
  float* dst = outC + ((size_t)b * CC + cw) * N + n0 + nk;
#pragma unroll
  for (int j = 0; j < 16; j += 4) {
    *(float4*)(dst + j) = make_float4(T[cw][nk + j], T[cw][nk + j + 1],
                                      T[cw][nk + j + 2], T[cw][nk + j + 3]);
  }
}

// ---------------------------------------------------------------------------
// out[b][c][y][x] = x + a1c + bilinear_up2(a2c) + bilinear_up4(a4)
// ---------------------------------------------------------------------------
__global__ __launch_bounds__(256) void final_kernel(
    const float* __restrict__ xin,
    const float* __restrict__ a1c, const float* __restrict__ a2c,
    const float* __restrict__ a4, float* __restrict__ out) {
  const int xc = threadIdx.x & 63;
  const int yl = threadIdx.x >> 6;
  const int y  = blockIdx.x * 4 + yl;
  const int c  = blockIdx.y;
  const int b  = blockIdx.z;

  float r = xin[(((size_t)b * CC + c) * HH + y) * WW + xc];
  r += a1c[((size_t)b * CC + c) * NPIX + y * WW + xc];

  {  // scale 2: 32x32 channel-major source. src = y/2 - 0.25
    const float ty = y * 0.5f - 0.25f;
    const float tx = xc * 0.5f - 0.25f;
    const int iy = (int)floorf(ty), ix = (int)floorf(tx);
    const float wy = ty - iy, wx = tx - ix;
    const int iy0 = max(iy, 0), iy1 = min(iy + 1, 31);
    const int ix0 = max(ix, 0), ix1 = min(ix + 1, 31);
    const float* base = a2c + ((size_t)b * CC + c) * 1024;
    const float v00 = base[iy0 * 32 + ix0], v01 = base[iy0 * 32 + ix1];
    const float v10 = base[iy1 * 32 + ix0], v11 = base[iy1 * 32 + ix1];
    r += (1.f-wy)*((1.f-wx)*v00 + wx*v01) + wy*((1.f-wx)*v10 + wx*v11);
  }
  {  // scale 4: 16x16 [n][c] source (already normalized). src = y/4 - 0.375
    const float ty = y * 0.25f - 0.375f;
    const float tx = xc * 0.25f - 0.375f;
    const int iy = (int)floorf(ty), ix = (int)floorf(tx);
    const float wy = ty - iy, wx = tx - ix;
    const int iy0 = max(iy, 0), iy1 = min(iy + 1, 15);
    const int ix0 = max(ix, 0), ix1 = min(ix + 1, 15);
    const float* base = a4 + (size_t)b * 256 * 64 + c;
    const float v00 = base[(iy0*16+ix0)*64], v01 = base[(iy0*16+ix1)*64];
    const float v10 = base[(iy1*16+ix0)*64], v11 = base[(iy1*16+ix1)*64];
    r += (1.f-wy)*((1.f-wx)*v00 + wx*v01) + wy*((1.f-wx)*v10 + wx*v11);
  }
  out[(((size_t)b * CC + c) * HH + y) * WW + xc] = r;
}

// ---------------------------------------------------------------------------
extern "C" void kernel_launch(void* const* d_in, const int* in_sizes, int n_in,
                              void* d_out, int out_size, void* d_ws,
                              size_t ws_size, hipStream_t stream) {
  const float* x = (const float*)d_in[0];
  const float* w = (const float*)d_in[1];
  float* out = (float*)d_out;

  unsigned short* fh1 = (unsigned short*)d_ws;            // [8][4096][64] swz
  unsigned short* fl1 = fh1 + (size_t)BB*NPIX*CC;
  unsigned short* fv1 = fl1 + (size_t)BB*NPIX*CC;         // tile-major V^T
  unsigned short* fh2 = fv1 + (size_t)BB*NPIX*CC;         // [8][1024][64]
  unsigned short* fl2 = fh2 + (size_t)BB*1024*CC;
  unsigned short* fv2 = fl2 + (size_t)BB*1024*CC;
  unsigned short* fh4 = fv2 + (size_t)BB*1024*CC;         // [8][256][64]
  unsigned short* fl4 = fh4 + (size_t)BB*256*CC;
  unsigned short* fv4 = fl4 + (size_t)BB*256*CC;
  unsigned short* Op1 = fv4 + (size_t)BB*256*CC;          // [4][8][4096][64] bf16
  float* Lp1 = (float*)(Op1 + 4*(size_t)BB*NPIX*CC);      // [4][8][4096]
  unsigned short* Op2 = (unsigned short*)(Lp1 + 4*(size_t)BB*NPIX);  // [4][8][1024][64]
  float* Lp2 = (float*)(Op2 + 4*(size_t)BB*1024*CC);      // [4][8][1024]
  float* a4  = Lp2 + 4*(size_t)BB*1024;                   // [8][256][64] fp32

  // Dead-time aliases (zero workspace growth)
  unsigned short* xth = (unsigned short*)Op1;             // 4.19 MB
  unsigned short* xtl = xth + (size_t)BB*NPIX*CC;         // 4.19 MB
  unsigned short* wth = (unsigned short*)Op2;             // 72 KB
  unsigned short* wtl = wth + 9*64*64;                    // 72 KB
  float* a1c = (float*)fh1;                               // [8][64][4096] fp32
  float* a2c = (float*)fh2;                               // [8][64][1024] fp32

  wprep_kernel<<<144, 256, 0, stream>>>(w, wth, wtl);
  xt_kernel<<<dim3(64, 8), 256, 0, stream>>>(x, xth, xtl);
  conv_mfma<<<dim3(64, 8), 256, 0, stream>>>(xth, xtl, wth, wtl, fh1, fl1, fv1);
  pool2_kernel<<<(BB*1024*CC)/256, 256, 0, stream>>>(fh1, fl1, fh2, fl2, fv2, 32);
  pool2_kernel<<<(BB*256*CC)/256, 256, 0, stream>>>(fh2, fl2, fh4, fl4, fv4, 16);
  // scale 1: NH=2, KS=4 -> 8*32*4 = 1024 blocks, 3 resident/CU (42KB LDS)
  attn_mfma<2, 4><<<8 * 32 * 4, 256, 0, stream>>>(fh1, fl1, fv1, nullptr, Op1,
                                                  Lp1, NPIX);
  // scale 2: NH=1, KS=4 -> 512 blocks
  attn_mfma<1, 4><<<8 * 16 * 4, 256, 0, stream>>>(fh2, fl2, fv2, nullptr, Op2,
                                                  Lp2, 1024);
  // scale 4: tiny, direct normalized fp32
  attn_mfma<1, 1><<<8 * 4, 256, 0, stream>>>(fh4, fl4, fv4, a4, nullptr,
                                             nullptr, 256);
  combine_kernel<4><<<BB * (NPIX / 64), 256, 0, stream>>>(Op1, Lp1, a1c, NPIX);
  combine_kernel<4><<<BB * (1024 / 64), 256, 0, stream>>>(Op2, Lp2, a2c, 1024);
  final_kernel<<<dim3(16, 64, 8), 256, 0, stream>>>(x, a1c, a2c, a4, out);
}

// Round 13
// 210.039 us; speedup vs baseline: 1.1384x; 1.1384x over previous
//
#include <hip/hip_runtime.h>
#include <hip/hip_bf16.h>
#include <math.h>

// Problem constants: x [8,64,64,64] fp32 NCHW, W_std [64,64,3,3] fp32 OIHW.
#define BB 8
#define CC 64
#define HH 64
#define WW 64
#define NPIX (HH*WW)   // 4096
#define LOG2E 1.44269504088896340736f

typedef __attribute__((ext_vector_type(8))) short bf16x8;            // MFMA A/B frag
typedef __attribute__((ext_vector_type(4))) float floatx4;           // MFMA C/D frag
typedef __attribute__((ext_vector_type(8))) unsigned short ushort8;  // 16B unit

__device__ inline unsigned short f2bf(float x) {
  __hip_bfloat16 h = __float2bfloat16(x);
  return *reinterpret_cast<unsigned short*>(&h);
}
__device__ inline float bf2f(unsigned short u) {
  __hip_bfloat16 h = *reinterpret_cast<__hip_bfloat16*>(&u);
  return __bfloat162float(h);
}

// XOR swizzle: 16B channel-chunks permuted within each 128B row so MFMA
// fragment reads from LDS (lane stride 128B) spread across all 32 banks.
__device__ inline int swzoff(int n, int c) {
  return (((c >> 3) ^ (n & 7)) << 3) | (c & 7);
}
__device__ inline int swzvslot(int key, int c) {
  return (((key >> 3) ^ (c & 7)) << 3) | (key & 7);
}

// 16B global -> LDS DMA
#define GLD_LDS16(gp, lp)                                                     \
  __builtin_amdgcn_global_load_lds(                                           \
      (const __attribute__((address_space(1))) void*)(gp),                    \
      (__attribute__((address_space(3))) void*)(lp), 16, 0, 0)

// ---------------------------------------------------------------------------
// prep: merged xt (512 blocks) + wprep (144 blocks).
//   xt:    x [b][c][y][x] fp32 -> XT [b][n][c] bf16 hi/lo, swizzled like fh.
//   wprep: WT[tap][o][c] bf16 hi/lo, depthwise Laplacian FOLDED IN.
// ---------------------------------------------------------------------------
__global__ __launch_bounds__(256) void prep_kernel(
    const float* __restrict__ xin, const float* __restrict__ w,
    unsigned short* __restrict__ xth, unsigned short* __restrict__ xtl,
    unsigned short* __restrict__ wth, unsigned short* __restrict__ wtl) {
  __shared__ float XL[64][65];
  const int bid = blockIdx.x;
  const int tid = threadIdx.x;
  if (bid < 512) {            // ---- xt ----
    const int y = bid & 63, b = bid >> 6;
    const int xq = tid & 15, cw = tid >> 4;
    const float* xb = xin + (size_t)b * CC * NPIX + y * WW;
#pragma unroll
    for (int p = 0; p < 4; ++p) {
      const int c = p * 16 + cw;
      const float4 v = *(const float4*)(xb + (size_t)c * NPIX + xq * 4);
      XL[c][xq * 4 + 0] = v.x; XL[c][xq * 4 + 1] = v.y;
      XL[c][xq * 4 + 2] = v.z; XL[c][xq * 4 + 3] = v.w;
    }
    __syncthreads();
    const int px = tid & 63, cp = tid >> 6;
    const size_t nb = ((size_t)b * NPIX + y * WW + px) * CC;
    ushort8 vh[2], vl[2];
#pragma unroll
    for (int j = 0; j < 16; ++j) {
      const float v = XL[cp * 16 + j][px];
      const unsigned short hh = f2bf(v);
      vh[j >> 3][j & 7] = hh;
      vl[j >> 3][j & 7] = f2bf(v - bf2f(hh));
    }
#pragma unroll
    for (int k = 0; k < 2; ++k) {
      const int ch = cp * 2 + k;
      const int off = ((ch ^ (px & 7)) << 3);
      *(ushort8*)(xth + nb + off) = vh[k];
      *(ushort8*)(xtl + nb + off) = vl[k];
    }
  } else {                    // ---- wprep ----
    const int idx = (bid - 512) * 256 + tid;    // 9*64*64 = 36864
    const int c   = idx & 63;
    const int o   = (idx >> 6) & 63;
    const int tap = idx >> 12;
    float v = w[((o * 64 + c) * 9) + tap];
    if (o == c) {
      const float lapk[9] = {0.f, 1.f, 0.f, 1.f, -4.f, 1.f, 0.f, 1.f, 0.f};
      v += lapk[tap];
    }
    const unsigned short hi = f2bf(v);
    wth[(tap * 64 + o) * 64 + c] = hi;
    wtl[(tap * 64 + o) * 64 + c] = f2bf(v - bf2f(hi));
  }
}

// ---------------------------------------------------------------------------
// conv_mfma: implicit-GEMM conv (unchanged from round 7).
// ---------------------------------------------------------------------------
__global__ __launch_bounds__(256, 2) void conv_mfma(
    const unsigned short* __restrict__ xth,
    const unsigned short* __restrict__ xtl,
    const unsigned short* __restrict__ wth,
    const unsigned short* __restrict__ wtl,
    unsigned short* __restrict__ fh, unsigned short* __restrict__ fl,
    unsigned short* __restrict__ fv) {
  __shared__ __align__(16) unsigned short XS[6 * 4096];

  const int tid  = threadIdx.x;
  const int lane = tid & 63;
  const int wave = tid >> 6;
  const int r16  = lane & 15;
  const int quad = lane >> 4;
  const int y = blockIdx.x, b = blockIdx.y;

#pragma unroll
  for (int r = 0; r < 3; ++r) {
    const int yy = min(max(y - 1 + r, 0), HH - 1);
    const unsigned short* sh = xth + ((size_t)b * NPIX + yy * WW) * CC;
    const unsigned short* sl = xtl + ((size_t)b * NPIX + yy * WW) * CC;
    GLD_LDS16(sh + tid * 8,        &XS[r * 4096 + tid * 8]);
    GLD_LDS16(sh + 2048 + tid * 8, &XS[r * 4096 + 2048 + tid * 8]);
    GLD_LDS16(sl + tid * 8,        &XS[(3 + r) * 4096 + tid * 8]);
    GLD_LDS16(sl + 2048 + tid * 8, &XS[(3 + r) * 4096 + 2048 + tid * 8]);
  }
  __syncthreads();

  floatx4 acc[4];
#pragma unroll
  for (int t = 0; t < 4; ++t) acc[t] = (floatx4){0.f, 0.f, 0.f, 0.f};
  const bf16x8 ZF = {0, 0, 0, 0, 0, 0, 0, 0};
  const int og = wave * 16 + r16;

#pragma unroll
  for (int tap = 0; tap < 9; ++tap) {
    const int ky = tap / 3, kx = tap % 3;
    const int yy = y + ky - 1;
    if (yy < 0 || yy >= HH) continue;
    const unsigned short* wt = wth + ((tap * 64 + og) << 6);
    const unsigned short* wl = wtl + ((tap * 64 + og) << 6);
    const bf16x8 Wh0 = *(const bf16x8*)(wt + quad * 8);
    const bf16x8 Wh1 = *(const bf16x8*)(wt + 32 + quad * 8);
    const bf16x8 Wl0 = *(const bf16x8*)(wl + quad * 8);
    const bf16x8 Wl1 = *(const bf16x8*)(wl + 32 + quad * 8);
#pragma unroll
    for (int t = 0; t < 4; ++t) {
      const int px = t * 16 + r16 + kx - 1;
      const bool ok = (px >= 0) && (px < WW);
      const int pxc = ok ? px : 0;
      const int bh = ky * 4096 + pxc * 64;
      const int bl = bh + 3 * 4096;
      const int o0 = ((quad ^ (pxc & 7)) << 3);
      const int o1 = (((4 + quad) ^ (pxc & 7)) << 3);
      bf16x8 Ah0 = *(const bf16x8*)(XS + bh + o0);
      bf16x8 Ah1 = *(const bf16x8*)(XS + bh + o1);
      bf16x8 Al0 = *(const bf16x8*)(XS + bl + o0);
      bf16x8 Al1 = *(const bf16x8*)(XS + bl + o1);
      if (!ok) { Ah0 = ZF; Ah1 = ZF; Al0 = ZF; Al1 = ZF; }
      acc[t] = __builtin_amdgcn_mfma_f32_16x16x32_bf16(Ah0, Wh0, acc[t], 0, 0, 0);
      acc[t] = __builtin_amdgcn_mfma_f32_16x16x32_bf16(Ah1, Wh1, acc[t], 0, 0, 0);
      acc[t] = __builtin_amdgcn_mfma_f32_16x16x32_bf16(Ah0, Wl0, acc[t], 0, 0, 0);
      acc[t] = __builtin_amdgcn_mfma_f32_16x16x32_bf16(Ah1, Wl1, acc[t], 0, 0, 0);
      acc[t] = __builtin_amdgcn_mfma_f32_16x16x32_bf16(Al0, Wh0, acc[t], 0, 0, 0);
      acc[t] = __builtin_amdgcn_mfma_f32_16x16x32_bf16(Al1, Wh1, acc[t], 0, 0, 0);
    }
  }

#pragma unroll
  for (int t = 0; t < 4; ++t)
#pragma unroll
    for (int r = 0; r < 4; ++r) {
      const int key = t * 16 + quad * 4 + r;
      const int n = y * WW + key;
      const float v = acc[t][r];
      const unsigned short hi = f2bf(v);
      const unsigned short lo = f2bf(v - bf2f(hi));
      fh[((size_t)b * NPIX + n) * CC + swzoff(n, og)] = hi;
      fl[((size_t)b * NPIX + n) * CC + swzoff(n, og)] = lo;
      fv[(((size_t)b * (NPIX >> 6) + y) * CC + og) * 64 + swzvslot(key, og)] = hi;
    }
}

// ---------------------------------------------------------------------------
// 2x2 average pool on swizzled layout (unchanged).
// ---------------------------------------------------------------------------
__global__ void pool2_kernel(const unsigned short* __restrict__ in_h,
                             const unsigned short* __restrict__ in_l,
                             unsigned short* __restrict__ out_h,
                             unsigned short* __restrict__ out_l,
                             unsigned short* __restrict__ out_v, int hw_out) {
  const int idx = blockIdx.x * blockDim.x + threadIdx.x;
  const int c  = idx & 63;
  const int t  = idx >> 6;
  const int xo = t % hw_out;
  const int r  = t / hw_out;
  const int yo = r % hw_out;
  const int b  = r / hw_out;
  const int win = 2 * hw_out;
  const size_t ibase = (size_t)b * win * win * CC;
  float s = 0.f;
#pragma unroll
  for (int dy = 0; dy < 2; ++dy)
#pragma unroll
    for (int dx = 0; dx < 2; ++dx) {
      const int nin = (2*yo+dy) * win + (2*xo+dx);
      const size_t a = ibase + (size_t)nin * CC + swzoff(nin, c);
      s += bf2f(in_h[a]) + bf2f(in_l[a]);
    }
  const float vv = 0.25f * s;
  const unsigned short hi = f2bf(vv);
  const unsigned short lo = f2bf(vv - bf2f(hi));
  const int nout = yo * hw_out + xo;
  const int Nout = hw_out * hw_out;
  const size_t ob = ((size_t)b * Nout + nout) * CC + swzoff(nout, c);
  out_h[ob] = hi;
  out_l[ob] = lo;
  out_v[(((size_t)b * (Nout >> 6) + (nout >> 6)) * CC + c) * 64
        + swzvslot(nout & 63, c)] = hi;
}

// ---------------------------------------------------------------------------
// MFMA flash attention body <NH, KS>: round-11 structure (V staged in LDS,
// 2 blocks/CU — round 12 proved V-from-L2 at 3 blocks/CU regresses 86->108).
// Now a device function so all 3 scales share ONE dispatch (block-range
// dispatch): scale-2/4 blocks start as soon as scale-1 blocks retire.
// ---------------------------------------------------------------------------
#define STR 72   // P-tile LDS row stride (shorts); 144B keeps b128 aligned

template <int NH, int KS>
__device__ __forceinline__ void attn_body(
    int bid,
    const unsigned short* __restrict__ fh,
    const unsigned short* __restrict__ fl,
    const unsigned short* __restrict__ fv,
    float* __restrict__ outF, unsigned short* __restrict__ outB,
    float* __restrict__ outL, int N,
    unsigned short* KVT, unsigned short* PtB) {
  const int tid  = threadIdx.x;
  const int lane = tid & 63;
  const int wave = tid >> 6;
  const int b    = bid & 7;              // XCD-local batch grouping
  const int rest = bid >> 3;
  const int nq   = N / (64 * NH);
  const int qt   = rest % nq;
  const int ks   = rest / nq;            // 0..KS-1
  const int q0   = qt * (64 * NH) + wave * (16 * NH);
  const int nt   = (N >> 6) / KS;
  const int t0   = ks * nt;
  const int r16  = lane & 15;
  const int quad = lane >> 4;
  const int swb  = r16 & 7;

  const unsigned short* fhB = fh + (size_t)b * N * CC;
  const unsigned short* flB = fl + (size_t)b * N * CC;
  const unsigned short* fvB = fv + (size_t)b * N * CC;   // tile-major V^T

  // ---- stage first tile via DMA: 24 chunks of 512 shorts; wave takes 6 ----
  {
    const size_t tb = (size_t)t0 * 4096;
#pragma unroll
    for (int j = 0; j < 6; ++j) {
      const int cid = wave * 6 + j;
      const int arr = cid >> 3, sub = (cid & 7) << 9;
      const unsigned short* g =
          (arr == 0 ? fhB : arr == 1 ? flB : fvB) + tb + sub + lane * 8;
      GLD_LDS16(g, KVT + arr * 4096 + sub + lane * 8);
    }
  }

  // ---- Q fragments per half: scale by log2e, re-split hi/lo, compute M ----
  bf16x8 Qh[NH][2], Ql[NH][2];
  float Mq[NH][4];
#pragma unroll
  for (int h = 0; h < NH; ++h) {
    float Mpart = 0.f;
#pragma unroll
    for (int kss = 0; kss < 2; ++kss) {
      const size_t off = (size_t)(q0 + h * 16 + r16) * CC
                         + ((((kss << 2) + quad) ^ swb) << 3);
      const bf16x8 hh = *(const bf16x8*)(fhB + off);
      const bf16x8 ll = *(const bf16x8*)(flB + off);
      bf16x8 sh, sl;
#pragma unroll
      for (int j = 0; j < 8; ++j) {
        const float f = bf2f((unsigned short)hh[j]) + bf2f((unsigned short)ll[j]);
        const float g = f * LOG2E;
        const unsigned short gh = f2bf(g);
        sh[j] = (short)gh;
        sl[j] = (short)f2bf(g - bf2f(gh));
        Mpart += g * f;                  // = log2e * sum f^2 (partial)
      }
      Qh[h][kss] = sh;
      Ql[h][kss] = sl;
    }
    Mpart += __shfl_xor(Mpart, 16, 64);
    Mpart += __shfl_xor(Mpart, 32, 64);  // per-row |q|^2*log2e at lane r16
#pragma unroll
    for (int r = 0; r < 4; ++r) Mq[h][r] = __shfl(Mpart, quad * 4 + r, 64);
  }

  floatx4 O[NH][4];
  float lrun[NH][4];
#pragma unroll
  for (int h = 0; h < NH; ++h)
#pragma unroll
    for (int ch = 0; ch < 4; ++ch) {
      O[h][ch] = (floatx4){0.f, 0.f, 0.f, 0.f};
      lrun[h][ch] = 0.f;
    }
  unsigned short* pt = PtB + wave * (16 * STR);

  int koff[2];
#pragma unroll
  for (int kss = 0; kss < 2; ++kss) koff[kss] = (((kss << 2) + quad) ^ swb) << 3;

  for (int t = 0; t < nt; ++t) {
    const int cur = t & 1;
    __syncthreads();                    // drains DMA for tile t, syncs block
    if (t + 1 < nt) {                   // issue DMA for tile t+1 now
      const size_t tb = (size_t)(t0 + t + 1) * 4096;
      unsigned short* dst = KVT + (cur ^ 1) * 12288;
#pragma unroll
      for (int j = 0; j < 6; ++j) {
        const int cid = wave * 6 + j;
        const int arr = cid >> 3, sub = (cid & 7) << 9;
        const unsigned short* g =
            (arr == 0 ? fhB : arr == 1 ? flB : fvB) + tb + sub + lane * 8;
        GLD_LDS16(g, dst + arr * 4096 + sub + lane * 8);
      }
    }
    const unsigned short* kh = KVT + cur * 12288;
    const unsigned short* kl = kh + 4096;
    const unsigned short* vt = kh + 8192;

    // ---- S-tiles: K-frags read once, shared across all NH halves ----
    floatx4 S[NH][4];
#pragma unroll
    for (int tt = 0; tt < 4; ++tt) {
      const int kbase = (tt * 16 + r16) * 64;
      const bf16x8 Kh0 = *(const bf16x8*)(kh + kbase + koff[0]);
      const bf16x8 Kh1 = *(const bf16x8*)(kh + kbase + koff[1]);
      const bf16x8 Kl0 = *(const bf16x8*)(kl + kbase + koff[0]);
      const bf16x8 Kl1 = *(const bf16x8*)(kl + kbase + koff[1]);
#pragma unroll
      for (int h = 0; h < NH; ++h) {
        floatx4 s = (floatx4){0.f, 0.f, 0.f, 0.f};
        s = __builtin_amdgcn_mfma_f32_16x16x32_bf16(Qh[h][0], Kh0, s, 0, 0, 0);
        s = __builtin_amdgcn_mfma_f32_16x16x32_bf16(Qh[h][1], Kh1, s, 0, 0, 0);
        s = __builtin_amdgcn_mfma_f32_16x16x32_bf16(Ql[h][0], Kh0, s, 0, 0, 0);
        s = __builtin_amdgcn_mfma_f32_16x16x32_bf16(Ql[h][1], Kh1, s, 0, 0, 0);
        s = __builtin_amdgcn_mfma_f32_16x16x32_bf16(Qh[h][0], Kl0, s, 0, 0, 0);
        s = __builtin_amdgcn_mfma_f32_16x16x32_bf16(Qh[h][1], Kl1, s, 0, 0, 0);
        S[h][tt] = s;
      }
    }

    // ---- per half: fixed-shift softmax, P round-trip (shared Pt rows) ----
    bf16x8 Pf[NH][2];
#pragma unroll
    for (int h = 0; h < NH; ++h) {
#pragma unroll
      for (int r = 0; r < 4; ++r) {
        float ls = 0.f;
#pragma unroll
        for (int tt = 0; tt < 4; ++tt) {
          const float p = __builtin_amdgcn_exp2f(S[h][tt][r] - Mq[h][r]);
          S[h][tt][r] = p;
          ls += p;
        }
        lrun[h][r] += ls;
      }
#pragma unroll
      for (int tt = 0; tt < 4; ++tt)
#pragma unroll
        for (int r = 0; r < 4; ++r)
          pt[(quad * 4 + r) * STR + tt * 16 + r16] = f2bf(S[h][tt][r]);
#pragma unroll
      for (int kss = 0; kss < 2; ++kss)
        Pf[h][kss] = *(const bf16x8*)(pt + r16 * STR + kss * 32 + quad * 8);
    }

    // ---- O += P*V: V-frags read once, shared across all NH halves ----
#pragma unroll
    for (int kss = 0; kss < 2; ++kss)
#pragma unroll
      for (int ch = 0; ch < 4; ++ch) {
        const bf16x8 Vf = *(const bf16x8*)(vt + (ch * 16 + r16) * 64 + koff[kss]);
#pragma unroll
        for (int h = 0; h < NH; ++h)
          O[h][ch] = __builtin_amdgcn_mfma_f32_16x16x32_bf16(Pf[h][kss], Vf,
                                                            O[h][ch], 0, 0, 0);
      }
  }

  // ---- epilogue ----
#pragma unroll
  for (int h = 0; h < NH; ++h) {
#pragma unroll
    for (int r = 0; r < 4; ++r) {
      float lt = lrun[h][r];
      lt += __shfl_xor(lt, 1, 16);
      lt += __shfl_xor(lt, 2, 16);
      lt += __shfl_xor(lt, 4, 16);
      lt += __shfl_xor(lt, 8, 16);
      if (KS == 1) {
        lrun[h][r] = 1.f / lt;
      } else if (r16 == 0) {
        outL[(size_t)ks * BB * N + (size_t)b * N + q0 + h * 16 + quad * 4 + r] = lt;
      }
    }
#pragma unroll
    for (int ch = 0; ch < 4; ++ch)
#pragma unroll
      for (int r = 0; r < 4; ++r) {
        const size_t qi = (size_t)b * N + q0 + h * 16 + quad * 4 + r;
        if (KS == 1) {
          outF[qi * CC + ch * 16 + r16] = O[h][ch][r] * lrun[h][r];
        } else {
          outB[(size_t)ks * BB * N * CC + qi * CC + ch * 16 + r16] =
              f2bf(O[h][ch][r]);
        }
      }
  }
}

// Merged dispatch: [0,512) scale-1 NH=4/KS=4; [512,1024) scale-2 NH=1/KS=4;
// [1024,1056) scale-4 NH=1/KS=1.
__global__ __launch_bounds__(256, 2) void attn_all(
    const unsigned short* __restrict__ fh1, const unsigned short* __restrict__ fl1,
    const unsigned short* __restrict__ fv1,
    unsigned short* __restrict__ Op1, float* __restrict__ Lp1,
    const unsigned short* __restrict__ fh2, const unsigned short* __restrict__ fl2,
    const unsigned short* __restrict__ fv2,
    unsigned short* __restrict__ Op2, float* __restrict__ Lp2,
    const unsigned short* __restrict__ fh4, const unsigned short* __restrict__ fl4,
    const unsigned short* __restrict__ fv4, float* __restrict__ a4) {
  __shared__ __align__(16) unsigned short KVT[2][3 * 4096];
  __shared__ __align__(16) unsigned short Pt[4][16 * STR];
  const int bid = blockIdx.x;
  if (bid < 512) {
    attn_body<4, 4>(bid, fh1, fl1, fv1, nullptr, Op1, Lp1, NPIX,
                    &KVT[0][0], &Pt[0][0]);
  } else if (bid < 1024) {
    attn_body<1, 4>(bid - 512, fh2, fl2, fv2, nullptr, Op2, Lp2, 1024,
                    &KVT[0][0], &Pt[0][0]);
  } else {
    attn_body<1, 1>(bid - 1024, fh4, fl4, fv4, a4, nullptr, nullptr, 256,
                    &KVT[0][0], &Pt[0][0]);
  }
}

// ---------------------------------------------------------------------------
// combine (scale-2 only): sum 4 bf16 O-partials + l (coalesced along c),
// normalize, LDS-transpose, write CHANNEL-MAJOR fp32 outC[b][c][n].
// ---------------------------------------------------------------------------
template <int KS>
__global__ __launch_bounds__(256) void combine_kernel(
    const unsigned short* __restrict__ Op, const float* __restrict__ Lp,
    float* __restrict__ outC, int N) {
  __shared__ float T[64][65];
  const int tid = threadIdx.x;
  const int nt  = N >> 6;
  const int b   = blockIdx.x / nt;
  const int n0  = (blockIdx.x % nt) * 64;
  const int nl  = tid >> 2;
  const int ck  = (tid & 3) * 16;
  const int n   = n0 + nl;

  float lv = 0.f;
#pragma unroll
  for (int ks = 0; ks < KS; ++ks)
    lv += Lp[(size_t)ks * BB * N + (size_t)b * N + n];
  const float inv = 1.f / lv;

  float v[16];
#pragma unroll
  for (int j = 0; j < 16; ++j) v[j] = 0.f;
#pragma unroll
  for (int ks = 0; ks < KS; ++ks) {
    const unsigned short* src =
        Op + (size_t)ks * BB * N * CC + ((size_t)b * N + n) * CC + ck;
    const ushort8 u0 = *(const ushort8*)(src);
    const ushort8 u1 = *(const ushort8*)(src + 8);
#pragma unroll
    for (int j = 0; j < 8; ++j) {
      v[j]     += bf2f(u0[j]);
      v[8 + j] += bf2f(u1[j]);
    }
  }
#pragma unroll
  for (int j = 0; j < 16; ++j) T[ck + j][nl] = v[j] * inv;
  __syncthreads();

  const int cw = tid >> 2;
  const int nk = (tid & 3) * 16;
  float* dst = outC + ((size_t)b * CC + cw) * N + n0 + nk;
#pragma unroll
  for (int j = 0; j < 16; j += 4) {
    *(float4*)(dst + j) = make_float4(T[cw][nk + j], T[cw][nk + j + 1],
                                      T[cw][nk + j + 2], T[cw][nk + j + 3]);
  }
}

// ---------------------------------------------------------------------------
// final2: FUSED scale-1 combine + output assembly. Block = (b, y-row).
// Phase 1: combine 4 bf16 O-partials of row y (coalesced along c), normalize,
// LDS-transpose -> T[c][x].  Phase 2: out = x + T + up2(a2c) + up4(a4),
// coalesced NCHW writes. Kills a1c's 8.4MB write + 8.4MB read + 1 launch.
// ---------------------------------------------------------------------------
__global__ __launch_bounds__(256) void final2_kernel(
    const float* __restrict__ xin,
    const unsigned short* __restrict__ Op1, const float* __restrict__ Lp1,
    const float* __restrict__ a2c, const float* __restrict__ a4,
    float* __restrict__ out) {
  __shared__ float T[64][65];
  const int tid = threadIdx.x;
  const int y = blockIdx.x & 63;
  const int b = blockIdx.x >> 6;
  const size_t S1 = (size_t)BB * NPIX * CC;
  const size_t T1 = (size_t)BB * NPIX;

  {  // ---- phase 1: combine row y ----
    const int nl = tid >> 2;
    const int ck = (tid & 3) * 16;
    const int n  = y * 64 + nl;
    float lv = 0.f;
#pragma unroll
    for (int ks = 0; ks < 4; ++ks)
      lv += Lp1[(size_t)ks * T1 + (size_t)b * NPIX + n];
    const float inv = 1.f / lv;
    float v[16];
#pragma unroll
    for (int j = 0; j < 16; ++j) v[j] = 0.f;
#pragma unroll
    for (int ks = 0; ks < 4; ++ks) {
      const unsigned short* src =
          Op1 + (size_t)ks * S1 + ((size_t)b * NPIX + n) * CC + ck;
      const ushort8 u0 = *(const ushort8*)(src);
      const ushort8 u1 = *(const ushort8*)(src + 8);
#pragma unroll
      for (int j = 0; j < 8; ++j) {
        v[j]     += bf2f(u0[j]);
        v[8 + j] += bf2f(u1[j]);
      }
    }
#pragma unroll
    for (int j = 0; j < 16; ++j) T[ck + j][nl] = v[j] * inv;
  }
  __syncthreads();

  // ---- phase 2: assemble output row ----
  const int c  = tid >> 2;
  const int xk = (tid & 3) * 16;
  const float* xrow = xin + (((size_t)b * CC + c) * HH + y) * WW;
  float* orow = out + (((size_t)b * CC + c) * HH + y) * WW;

  // scale-2 y params (shared across the 16 x)
  const float ty2 = y * 0.5f - 0.25f;
  const int iy2 = (int)floorf(ty2);
  const float wy2 = ty2 - iy2;
  const int iy20 = max(iy2, 0), iy21 = min(iy2 + 1, 31);
  const float* b2 = a2c + ((size_t)b * CC + c) * 1024;
  // scale-4 y params
  const float ty4 = y * 0.25f - 0.375f;
  const int iy4 = (int)floorf(ty4);
  const float wy4 = ty4 - iy4;
  const int iy40 = max(iy4, 0), iy41 = min(iy4 + 1, 15);
  const float* b4 = a4 + (size_t)b * 256 * 64 + c;

#pragma unroll
  for (int j = 0; j < 16; ++j) {
    const int xx = xk + j;
    float r = xrow[xx] + T[c][xx];
    {  // scale 2
      const float tx = xx * 0.5f - 0.25f;
      const int ix = (int)floorf(tx);
      const float wx = tx - ix;
      const int ix0 = max(ix, 0), ix1 = min(ix + 1, 31);
      const float v00 = b2[iy20 * 32 + ix0], v01 = b2[iy20 * 32 + ix1];
      const float v10 = b2[iy21 * 32 + ix0], v11 = b2[iy21 * 32 + ix1];
      r += (1.f-wy2)*((1.f-wx)*v00 + wx*v01) + wy2*((1.f-wx)*v10 + wx*v11);
    }
    {  // scale 4
      const float tx = xx * 0.25f - 0.375f;
      const int ix = (int)floorf(tx);
      const float wx = tx - ix;
      const int ix0 = max(ix, 0), ix1 = min(ix + 1, 15);
      const float v00 = b4[(iy40*16+ix0)*64], v01 = b4[(iy40*16+ix1)*64];
      const float v10 = b4[(iy41*16+ix0)*64], v11 = b4[(iy41*16+ix1)*64];
      r += (1.f-wy4)*((1.f-wx)*v00 + wx*v01) + wy4*((1.f-wx)*v10 + wx*v11);
    }
    orow[xx] = r;
  }
}

// ---------------------------------------------------------------------------
extern "C" void kernel_launch(void* const* d_in, const int* in_sizes, int n_in,
                              void* d_out, int out_size, void* d_ws,
                              size_t ws_size, hipStream_t stream) {
  const float* x = (const float*)d_in[0];
  const float* w = (const float*)d_in[1];
  float* out = (float*)d_out;

  unsigned short* fh1 = (unsigned short*)d_ws;            // [8][4096][64] swz
  unsigned short* fl1 = fh1 + (size_t)BB*NPIX*CC;
  unsigned short* fv1 = fl1 + (size_t)BB*NPIX*CC;         // tile-major V^T
  unsigned short* fh2 = fv1 + (size_t)BB*NPIX*CC;         // [8][1024][64]
  unsigned short* fl2 = fh2 + (size_t)BB*1024*CC;
  unsigned short* fv2 = fl2 + (size_t)BB*1024*CC;
  unsigned short* fh4 = fv2 + (size_t)BB*1024*CC;         // [8][256][64]
  unsigned short* fl4 = fh4 + (size_t)BB*256*CC;
  unsigned short* fv4 = fl4 + (size_t)BB*256*CC;
  unsigned short* Op1 = fv4 + (size_t)BB*256*CC;          // [4][8][4096][64] bf16
  float* Lp1 = (float*)(Op1 + 4*(size_t)BB*NPIX*CC);      // [4][8][4096]
  unsigned short* Op2 = (unsigned short*)(Lp1 + 4*(size_t)BB*NPIX);  // [4][8][1024][64]
  float* Lp2 = (float*)(Op2 + 4*(size_t)BB*1024*CC);      // [4][8][1024]
  float* a4  = Lp2 + 4*(size_t)BB*1024;                   // [8][256][64] fp32

  // Dead-time aliases (zero workspace growth):
  //   XT/WT (dead after conv_mfma) alias Op1/Op2 (written by attn later)
  //   a2c (combine2 out) aliases fh2+fl2 (dead after attn_all)
  unsigned short* xth = (unsigned short*)Op1;             // 4.19 MB
  unsigned short* xtl = xth + (size_t)BB*NPIX*CC;         // 4.19 MB
  unsigned short* wth = (unsigned short*)Op2;             // 72 KB
  unsigned short* wtl = wth + 9*64*64;                    // 72 KB
  float* a2c = (float*)fh2;                               // [8][64][1024] fp32

  prep_kernel<<<656, 256, 0, stream>>>(x, w, xth, xtl, wth, wtl);
  conv_mfma<<<dim3(64, 8), 256, 0, stream>>>(xth, xtl, wth, wtl, fh1, fl1, fv1);
  pool2_kernel<<<(BB*1024*CC)/256, 256, 0, stream>>>(fh1, fl1, fh2, fl2, fv2, 32);
  pool2_kernel<<<(BB*256*CC)/256, 256, 0, stream>>>(fh2, fl2, fh4, fl4, fv4, 16);
  attn_all<<<1056, 256, 0, stream>>>(fh1, fl1, fv1, Op1, Lp1,
                                     fh2, fl2, fv2, Op2, Lp2,
                                     fh4, fl4, fv4, a4);
  combine_kernel<4><<<BB * (1024 / 64), 256, 0, stream>>>(Op2, Lp2, a2c, 1024);
  final2_kernel<<<512, 256, 0, stream>>>(x, Op1, Lp1, a2c, a4, out);
}

// Round 14
// 196.762 us; speedup vs baseline: 1.2152x; 1.0675x over previous
//
#include <hip/hip_runtime.h>
#include <hip/hip_bf16.h>
#include <math.h>

// Problem constants: x [8,64,64,64] fp32 NCHW, W_std [64,64,3,3] fp32 OIHW.
#define BB 8
#define CC 64
#define HH 64
#define WW 64
#define NPIX (HH*WW)   // 4096
#define LOG2E 1.44269504088896340736f

typedef __attribute__((ext_vector_type(8))) short bf16x8;            // MFMA A/B frag
typedef __attribute__((ext_vector_type(4))) float floatx4;           // MFMA C/D frag
typedef __attribute__((ext_vector_type(8))) unsigned short ushort8;  // 16B unit

__device__ inline unsigned short f2bf(float x) {
  __hip_bfloat16 h = __float2bfloat16(x);
  return *reinterpret_cast<unsigned short*>(&h);
}
__device__ inline float bf2f(unsigned short u) {
  __hip_bfloat16 h = *reinterpret_cast<__hip_bfloat16*>(&u);
  return __bfloat162float(h);
}

// XOR swizzle: 16B channel-chunks permuted within each 128B row so MFMA
// fragment reads from LDS (lane stride 128B) spread across all 32 banks.
__device__ inline int swzoff(int n, int c) {
  return (((c >> 3) ^ (n & 7)) << 3) | (c & 7);
}
__device__ inline int swzvslot(int key, int c) {
  return (((key >> 3) ^ (c & 7)) << 3) | (key & 7);
}

// 16B global -> LDS DMA
#define GLD_LDS16(gp, lp)                                                     \
  __builtin_amdgcn_global_load_lds(                                           \
      (const __attribute__((address_space(1))) void*)(gp),                    \
      (__attribute__((address_space(3))) void*)(lp), 16, 0, 0)

// ---------------------------------------------------------------------------
// prep: merged xt (512 blocks) + wprep (144 blocks).
// ---------------------------------------------------------------------------
__global__ __launch_bounds__(256) void prep_kernel(
    const float* __restrict__ xin, const float* __restrict__ w,
    unsigned short* __restrict__ xth, unsigned short* __restrict__ xtl,
    unsigned short* __restrict__ wth, unsigned short* __restrict__ wtl) {
  __shared__ float XL[64][65];
  const int bid = blockIdx.x;
  const int tid = threadIdx.x;
  if (bid < 512) {            // ---- xt ----
    const int y = bid & 63, b = bid >> 6;
    const int xq = tid & 15, cw = tid >> 4;
    const float* xb = xin + (size_t)b * CC * NPIX + y * WW;
#pragma unroll
    for (int p = 0; p < 4; ++p) {
      const int c = p * 16 + cw;
      const float4 v = *(const float4*)(xb + (size_t)c * NPIX + xq * 4);
      XL[c][xq * 4 + 0] = v.x; XL[c][xq * 4 + 1] = v.y;
      XL[c][xq * 4 + 2] = v.z; XL[c][xq * 4 + 3] = v.w;
    }
    __syncthreads();
    const int px = tid & 63, cp = tid >> 6;
    const size_t nb = ((size_t)b * NPIX + y * WW + px) * CC;
    ushort8 vh[2], vl[2];
#pragma unroll
    for (int j = 0; j < 16; ++j) {
      const float v = XL[cp * 16 + j][px];
      const unsigned short hh = f2bf(v);
      vh[j >> 3][j & 7] = hh;
      vl[j >> 3][j & 7] = f2bf(v - bf2f(hh));
    }
#pragma unroll
    for (int k = 0; k < 2; ++k) {
      const int ch = cp * 2 + k;
      const int off = ((ch ^ (px & 7)) << 3);
      *(ushort8*)(xth + nb + off) = vh[k];
      *(ushort8*)(xtl + nb + off) = vl[k];
    }
  } else {                    // ---- wprep: Laplacian folded into weights ----
    const int idx = (bid - 512) * 256 + tid;    // 9*64*64 = 36864
    const int c   = idx & 63;
    const int o   = (idx >> 6) & 63;
    const int tap = idx >> 12;
    float v = w[((o * 64 + c) * 9) + tap];
    if (o == c) {
      const float lapk[9] = {0.f, 1.f, 0.f, 1.f, -4.f, 1.f, 0.f, 1.f, 0.f};
      v += lapk[tap];
    }
    const unsigned short hi = f2bf(v);
    wth[(tap * 64 + o) * 64 + c] = hi;
    wtl[(tap * 64 + o) * 64 + c] = f2bf(v - bf2f(hi));
  }
}

// ---------------------------------------------------------------------------
// conv_mfma: implicit-GEMM conv (unchanged from round 7).
// ---------------------------------------------------------------------------
__global__ __launch_bounds__(256, 2) void conv_mfma(
    const unsigned short* __restrict__ xth,
    const unsigned short* __restrict__ xtl,
    const unsigned short* __restrict__ wth,
    const unsigned short* __restrict__ wtl,
    unsigned short* __restrict__ fh, unsigned short* __restrict__ fl,
    unsigned short* __restrict__ fv) {
  __shared__ __align__(16) unsigned short XS[6 * 4096];

  const int tid  = threadIdx.x;
  const int lane = tid & 63;
  const int wave = tid >> 6;
  const int r16  = lane & 15;
  const int quad = lane >> 4;
  const int y = blockIdx.x, b = blockIdx.y;

#pragma unroll
  for (int r = 0; r < 3; ++r) {
    const int yy = min(max(y - 1 + r, 0), HH - 1);
    const unsigned short* sh = xth + ((size_t)b * NPIX + yy * WW) * CC;
    const unsigned short* sl = xtl + ((size_t)b * NPIX + yy * WW) * CC;
    GLD_LDS16(sh + tid * 8,        &XS[r * 4096 + tid * 8]);
    GLD_LDS16(sh + 2048 + tid * 8, &XS[r * 4096 + 2048 + tid * 8]);
    GLD_LDS16(sl + tid * 8,        &XS[(3 + r) * 4096 + tid * 8]);
    GLD_LDS16(sl + 2048 + tid * 8, &XS[(3 + r) * 4096 + 2048 + tid * 8]);
  }
  __syncthreads();

  floatx4 acc[4];
#pragma unroll
  for (int t = 0; t < 4; ++t) acc[t] = (floatx4){0.f, 0.f, 0.f, 0.f};
  const bf16x8 ZF = {0, 0, 0, 0, 0, 0, 0, 0};
  const int og = wave * 16 + r16;

#pragma unroll
  for (int tap = 0; tap < 9; ++tap) {
    const int ky = tap / 3, kx = tap % 3;
    const int yy = y + ky - 1;
    if (yy < 0 || yy >= HH) continue;
    const unsigned short* wt = wth + ((tap * 64 + og) << 6);
    const unsigned short* wl = wtl + ((tap * 64 + og) << 6);
    const bf16x8 Wh0 = *(const bf16x8*)(wt + quad * 8);
    const bf16x8 Wh1 = *(const bf16x8*)(wt + 32 + quad * 8);
    const bf16x8 Wl0 = *(const bf16x8*)(wl + quad * 8);
    const bf16x8 Wl1 = *(const bf16x8*)(wl + 32 + quad * 8);
#pragma unroll
    for (int t = 0; t < 4; ++t) {
      const int px = t * 16 + r16 + kx - 1;
      const bool ok = (px >= 0) && (px < WW);
      const int pxc = ok ? px : 0;
      const int bh = ky * 4096 + pxc * 64;
      const int bl = bh + 3 * 4096;
      const int o0 = ((quad ^ (pxc & 7)) << 3);
      const int o1 = (((4 + quad) ^ (pxc & 7)) << 3);
      bf16x8 Ah0 = *(const bf16x8*)(XS + bh + o0);
      bf16x8 Ah1 = *(const bf16x8*)(XS + bh + o1);
      bf16x8 Al0 = *(const bf16x8*)(XS + bl + o0);
      bf16x8 Al1 = *(const bf16x8*)(XS + bl + o1);
      if (!ok) { Ah0 = ZF; Ah1 = ZF; Al0 = ZF; Al1 = ZF; }
      acc[t] = __builtin_amdgcn_mfma_f32_16x16x32_bf16(Ah0, Wh0, acc[t], 0, 0, 0);
      acc[t] = __builtin_amdgcn_mfma_f32_16x16x32_bf16(Ah1, Wh1, acc[t], 0, 0, 0);
      acc[t] = __builtin_amdgcn_mfma_f32_16x16x32_bf16(Ah0, Wl0, acc[t], 0, 0, 0);
      acc[t] = __builtin_amdgcn_mfma_f32_16x16x32_bf16(Ah1, Wl1, acc[t], 0, 0, 0);
      acc[t] = __builtin_amdgcn_mfma_f32_16x16x32_bf16(Al0, Wh0, acc[t], 0, 0, 0);
      acc[t] = __builtin_amdgcn_mfma_f32_16x16x32_bf16(Al1, Wh1, acc[t], 0, 0, 0);
    }
  }

#pragma unroll
  for (int t = 0; t < 4; ++t)
#pragma unroll
    for (int r = 0; r < 4; ++r) {
      const int key = t * 16 + quad * 4 + r;
      const int n = y * WW + key;
      const float v = acc[t][r];
      const unsigned short hi = f2bf(v);
      const unsigned short lo = f2bf(v - bf2f(hi));
      fh[((size_t)b * NPIX + n) * CC + swzoff(n, og)] = hi;
      fl[((size_t)b * NPIX + n) * CC + swzoff(n, og)] = lo;
      fv[(((size_t)b * (NPIX >> 6) + y) * CC + og) * 64 + swzvslot(key, og)] = hi;
    }
}

// ---------------------------------------------------------------------------
// pools: merged pool2 (blocks [0,2048)) + pool4-direct (blocks [2048,2560)).
// pool4 reads the 4x4 feat window directly (no dependency on pool2 output).
// ---------------------------------------------------------------------------
__global__ void pools_kernel(const unsigned short* __restrict__ in_h,
                             const unsigned short* __restrict__ in_l,
                             unsigned short* __restrict__ h2,
                             unsigned short* __restrict__ l2,
                             unsigned short* __restrict__ v2,
                             unsigned short* __restrict__ h4,
                             unsigned short* __restrict__ l4,
                             unsigned short* __restrict__ v4) {
  const int bid = blockIdx.x;
  if (bid < 2048) {           // ---- pool2: 64x64 -> 32x32 ----
    const int idx = bid * 256 + threadIdx.x;
    const int c  = idx & 63;
    const int t  = idx >> 6;
    const int xo = t & 31;
    const int yo = (t >> 5) & 31;
    const int b  = t >> 10;
    const size_t ibase = (size_t)b * NPIX * CC;
    float s = 0.f;
#pragma unroll
    for (int dy = 0; dy < 2; ++dy)
#pragma unroll
      for (int dx = 0; dx < 2; ++dx) {
        const int nin = (2*yo+dy) * 64 + (2*xo+dx);
        const size_t a = ibase + (size_t)nin * CC + swzoff(nin, c);
        s += bf2f(in_h[a]) + bf2f(in_l[a]);
      }
    const float vv = 0.25f * s;
    const unsigned short hi = f2bf(vv);
    const unsigned short lo = f2bf(vv - bf2f(hi));
    const int nout = yo * 32 + xo;
    const size_t ob = ((size_t)b * 1024 + nout) * CC + swzoff(nout, c);
    h2[ob] = hi;
    l2[ob] = lo;
    v2[(((size_t)b * 16 + (nout >> 6)) * CC + c) * 64 + swzvslot(nout & 63, c)] = hi;
  } else {                    // ---- pool4: 64x64 -> 16x16 (direct) ----
    const int idx = (bid - 2048) * 256 + threadIdx.x;
    const int c  = idx & 63;
    const int t  = idx >> 6;
    const int xo = t & 15;
    const int yo = (t >> 4) & 15;
    const int b  = t >> 8;
    const size_t ibase = (size_t)b * NPIX * CC;
    float s = 0.f;
#pragma unroll
    for (int dy = 0; dy < 4; ++dy)
#pragma unroll
      for (int dx = 0; dx < 4; ++dx) {
        const int nin = (4*yo+dy) * 64 + (4*xo+dx);
        const size_t a = ibase + (size_t)nin * CC + swzoff(nin, c);
        s += bf2f(in_h[a]) + bf2f(in_l[a]);
      }
    const float vv = 0.0625f * s;
    const unsigned short hi = f2bf(vv);
    const unsigned short lo = f2bf(vv - bf2f(hi));
    const int nout = yo * 16 + xo;
    const size_t ob = ((size_t)b * 256 + nout) * CC + swzoff(nout, c);
    h4[ob] = hi;
    l4[ob] = lo;
    v4[(((size_t)b * 4 + (nout >> 6)) * CC + c) * 64 + swzvslot(nout & 63, c)] = hi;
  }
}

// ---------------------------------------------------------------------------
// MFMA flash attention <NH, KS>, round-14 restructure:
//   PER-TT SOFTMAX FUSION: exp2 + P-write happen immediately after each
//   16-key S-tile, so S registers die at once (live set ~130 vs 192) and
//   the VALU softmax work interleaves with the next tt's MFMAs. Rounds
//   9-13 showed ~100 cyc wall per MFMA (vs 4.85 ideal) with no pipe >31% —
//   dependency-stall bound; this + amdgpu_waves_per_eu(2,2) (compiler may
//   use up to 256 VGPR since LDS caps us at 2 blocks/CU anyway) attacks it.
//   Pt is now per-(wave,half): 4 x NH x 16 rows.
// ---------------------------------------------------------------------------
#define STR 72   // P-tile LDS row stride (shorts); 144B keeps b128 aligned

template <int NH, int KS>
__device__ __forceinline__ void attn_body(
    int bid,
    const unsigned short* __restrict__ fh,
    const unsigned short* __restrict__ fl,
    const unsigned short* __restrict__ fv,
    float* __restrict__ outF, unsigned short* __restrict__ outB,
    float* __restrict__ outL, int N,
    unsigned short* KVT, unsigned short* PtB) {
  const int tid  = threadIdx.x;
  const int lane = tid & 63;
  const int wave = tid >> 6;
  const int b    = bid & 7;              // XCD-local batch grouping
  const int rest = bid >> 3;
  const int nq   = N / (64 * NH);
  const int qt   = rest % nq;
  const int ks   = rest / nq;            // 0..KS-1
  const int q0   = qt * (64 * NH) + wave * (16 * NH);
  const int nt   = (N >> 6) / KS;
  const int t0   = ks * nt;
  const int r16  = lane & 15;
  const int quad = lane >> 4;
  const int swb  = r16 & 7;

  const unsigned short* fhB = fh + (size_t)b * N * CC;
  const unsigned short* flB = fl + (size_t)b * N * CC;
  const unsigned short* fvB = fv + (size_t)b * N * CC;   // tile-major V^T

  // ---- stage first tile via DMA: 24 chunks of 512 shorts; wave takes 6 ----
  {
    const size_t tb = (size_t)t0 * 4096;
#pragma unroll
    for (int j = 0; j < 6; ++j) {
      const int cid = wave * 6 + j;
      const int arr = cid >> 3, sub = (cid & 7) << 9;
      const unsigned short* g =
          (arr == 0 ? fhB : arr == 1 ? flB : fvB) + tb + sub + lane * 8;
      GLD_LDS16(g, KVT + arr * 4096 + sub + lane * 8);
    }
  }

  // ---- Q fragments per half: scale by log2e, re-split hi/lo, compute M ----
  bf16x8 Qh[NH][2], Ql[NH][2];
  float Mq[NH][4];
#pragma unroll
  for (int h = 0; h < NH; ++h) {
    float Mpart = 0.f;
#pragma unroll
    for (int kss = 0; kss < 2; ++kss) {
      const size_t off = (size_t)(q0 + h * 16 + r16) * CC
                         + ((((kss << 2) + quad) ^ swb) << 3);
      const bf16x8 hh = *(const bf16x8*)(fhB + off);
      const bf16x8 ll = *(const bf16x8*)(flB + off);
      bf16x8 sh, sl;
#pragma unroll
      for (int j = 0; j < 8; ++j) {
        const float f = bf2f((unsigned short)hh[j]) + bf2f((unsigned short)ll[j]);
        const float g = f * LOG2E;
        const unsigned short gh = f2bf(g);
        sh[j] = (short)gh;
        sl[j] = (short)f2bf(g - bf2f(gh));
        Mpart += g * f;                  // = log2e * sum f^2 (partial)
      }
      Qh[h][kss] = sh;
      Ql[h][kss] = sl;
    }
    Mpart += __shfl_xor(Mpart, 16, 64);
    Mpart += __shfl_xor(Mpart, 32, 64);  // per-row |q|^2*log2e at lane r16
#pragma unroll
    for (int r = 0; r < 4; ++r) Mq[h][r] = __shfl(Mpart, quad * 4 + r, 64);
  }

  floatx4 O[NH][4];
  float lrun[NH][4];
#pragma unroll
  for (int h = 0; h < NH; ++h)
#pragma unroll
    for (int ch = 0; ch < 4; ++ch) {
      O[h][ch] = (floatx4){0.f, 0.f, 0.f, 0.f};
      lrun[h][ch] = 0.f;
    }
  unsigned short* ptw = PtB + wave * (NH * 16 * STR);

  int koff[2];
#pragma unroll
  for (int kss = 0; kss < 2; ++kss) koff[kss] = (((kss << 2) + quad) ^ swb) << 3;

  for (int t = 0; t < nt; ++t) {
    const int cur = t & 1;
    __syncthreads();                    // drains DMA for tile t, syncs block
    if (t + 1 < nt) {                   // issue DMA for tile t+1 now
      const size_t tb = (size_t)(t0 + t + 1) * 4096;
      unsigned short* dst = KVT + (cur ^ 1) * 12288;
#pragma unroll
      for (int j = 0; j < 6; ++j) {
        const int cid = wave * 6 + j;
        const int arr = cid >> 3, sub = (cid & 7) << 9;
        const unsigned short* g =
            (arr == 0 ? fhB : arr == 1 ? flB : fvB) + tb + sub + lane * 8;
        GLD_LDS16(g, dst + arr * 4096 + sub + lane * 8);
      }
    }
    const unsigned short* kh = KVT + cur * 12288;
    const unsigned short* kl = kh + 4096;
    const unsigned short* vt = kh + 8192;

    // ---- S-tiles with FUSED per-tt softmax: S regs die immediately ----
#pragma unroll
    for (int tt = 0; tt < 4; ++tt) {
      const int kbase = (tt * 16 + r16) * 64;
      const bf16x8 Kh0 = *(const bf16x8*)(kh + kbase + koff[0]);
      const bf16x8 Kh1 = *(const bf16x8*)(kh + kbase + koff[1]);
      const bf16x8 Kl0 = *(const bf16x8*)(kl + kbase + koff[0]);
      const bf16x8 Kl1 = *(const bf16x8*)(kl + kbase + koff[1]);
#pragma unroll
      for (int h = 0; h < NH; ++h) {
        floatx4 s = (floatx4){0.f, 0.f, 0.f, 0.f};
        s = __builtin_amdgcn_mfma_f32_16x16x32_bf16(Qh[h][0], Kh0, s, 0, 0, 0);
        s = __builtin_amdgcn_mfma_f32_16x16x32_bf16(Qh[h][1], Kh1, s, 0, 0, 0);
        s = __builtin_amdgcn_mfma_f32_16x16x32_bf16(Ql[h][0], Kh0, s, 0, 0, 0);
        s = __builtin_amdgcn_mfma_f32_16x16x32_bf16(Ql[h][1], Kh1, s, 0, 0, 0);
        s = __builtin_amdgcn_mfma_f32_16x16x32_bf16(Qh[h][0], Kl0, s, 0, 0, 0);
        s = __builtin_amdgcn_mfma_f32_16x16x32_bf16(Qh[h][1], Kl1, s, 0, 0, 0);
        unsigned short* pth = ptw + h * (16 * STR);
#pragma unroll
        for (int r = 0; r < 4; ++r) {
          const float p = __builtin_amdgcn_exp2f(s[r] - Mq[h][r]);
          lrun[h][r] += p;
          pth[(quad * 4 + r) * STR + tt * 16 + r16] = f2bf(p);
        }
      }
    }

    // ---- P reads (A-layout) + O += P*V ----
    bf16x8 Pf[NH][2];
#pragma unroll
    for (int h = 0; h < NH; ++h)
#pragma unroll
      for (int kss = 0; kss < 2; ++kss)
        Pf[h][kss] = *(const bf16x8*)(ptw + h * (16 * STR) + r16 * STR
                                      + kss * 32 + quad * 8);
#pragma unroll
    for (int kss = 0; kss < 2; ++kss)
#pragma unroll
      for (int ch = 0; ch < 4; ++ch) {
        const bf16x8 Vf = *(const bf16x8*)(vt + (ch * 16 + r16) * 64 + koff[kss]);
#pragma unroll
        for (int h = 0; h < NH; ++h)
          O[h][ch] = __builtin_amdgcn_mfma_f32_16x16x32_bf16(Pf[h][kss], Vf,
                                                            O[h][ch], 0, 0, 0);
      }
  }

  // ---- epilogue ----
#pragma unroll
  for (int h = 0; h < NH; ++h) {
#pragma unroll
    for (int r = 0; r < 4; ++r) {
      float lt = lrun[h][r];
      lt += __shfl_xor(lt, 1, 16);
      lt += __shfl_xor(lt, 2, 16);
      lt += __shfl_xor(lt, 4, 16);
      lt += __shfl_xor(lt, 8, 16);
      if (KS == 1) {
        lrun[h][r] = 1.f / lt;
      } else if (r16 == 0) {
        outL[(size_t)ks * BB * N + (size_t)b * N + q0 + h * 16 + quad * 4 + r] = lt;
      }
    }
#pragma unroll
    for (int ch = 0; ch < 4; ++ch)
#pragma unroll
      for (int r = 0; r < 4; ++r) {
        const size_t qi = (size_t)b * N + q0 + h * 16 + quad * 4 + r;
        if (KS == 1) {
          outF[qi * CC + ch * 16 + r16] = O[h][ch][r] * lrun[h][r];
        } else {
          outB[(size_t)ks * BB * N * CC + qi * CC + ch * 16 + r16] =
              f2bf(O[h][ch][r]);
        }
      }
  }
}

// Merged dispatch: [0,512) scale-1 NH=2/KS=2; [512,768) scale-2 NH=1/KS=2;
// [768,800) scale-4 NH=1/KS=1.
__global__ __launch_bounds__(256)
__attribute__((amdgpu_waves_per_eu(2, 2))) void attn_all(
    const unsigned short* __restrict__ fh1, const unsigned short* __restrict__ fl1,
    const unsigned short* __restrict__ fv1,
    unsigned short* __restrict__ Op1, float* __restrict__ Lp1,
    const unsigned short* __restrict__ fh2, const unsigned short* __restrict__ fl2,
    const unsigned short* __restrict__ fv2,
    unsigned short* __restrict__ Op2, float* __restrict__ Lp2,
    const unsigned short* __restrict__ fh4, const unsigned short* __restrict__ fl4,
    const unsigned short* __restrict__ fv4, float* __restrict__ a4) {
  __shared__ __align__(16) unsigned short KVT[2][3 * 4096];
  __shared__ __align__(16) unsigned short Pt[4][2 * 16 * STR];
  const int bid = blockIdx.x;
  if (bid < 512) {
    attn_body<2, 2>(bid, fh1, fl1, fv1, nullptr, Op1, Lp1, NPIX,
                    &KVT[0][0], &Pt[0][0]);
  } else if (bid < 768) {
    attn_body<1, 2>(bid - 512, fh2, fl2, fv2, nullptr, Op2, Lp2, 1024,
                    &KVT[0][0], &Pt[0][0]);
  } else {
    attn_body<1, 1>(bid - 768, fh4, fl4, fv4, a4, nullptr, nullptr, 256,
                    &KVT[0][0], &Pt[0][0]);
  }
}

// ---------------------------------------------------------------------------
// combine (scale-2): sum KS bf16 O-partials + l (coalesced along c),
// normalize, LDS-transpose, write CHANNEL-MAJOR fp32 outC[b][c][n].
// ---------------------------------------------------------------------------
template <int KS>
__global__ __launch_bounds__(256) void combine_kernel(
    const unsigned short* __restrict__ Op, const float* __restrict__ Lp,
    float* __restrict__ outC, int N) {
  __shared__ float T[64][65];
  const int tid = threadIdx.x;
  const int nt  = N >> 6;
  const int b   = blockIdx.x / nt;
  const int n0  = (blockIdx.x % nt) * 64;
  const int nl  = tid >> 2;
  const int ck  = (tid & 3) * 16;
  const int n   = n0 + nl;

  float lv = 0.f;
#pragma unroll
  for (int ks = 0; ks < KS; ++ks)
    lv += Lp[(size_t)ks * BB * N + (size_t)b * N + n];
  const float inv = 1.f / lv;

  float v[16];
#pragma unroll
  for (int j = 0; j < 16; ++j) v[j] = 0.f;
#pragma unroll
  for (int ks = 0; ks < KS; ++ks) {
    const unsigned short* src =
        Op + (size_t)ks * BB * N * CC + ((size_t)b * N + n) * CC + ck;
    const ushort8 u0 = *(const ushort8*)(src);
    const ushort8 u1 = *(const ushort8*)(src + 8);
#pragma unroll
    for (int j = 0; j < 8; ++j) {
      v[j]     += bf2f(u0[j]);
      v[8 + j] += bf2f(u1[j]);
    }
  }
#pragma unroll
  for (int j = 0; j < 16; ++j) T[ck + j][nl] = v[j] * inv;
  __syncthreads();

  const int cw = tid >> 2;
  const int nk = (tid & 3) * 16;
  float* dst = outC + ((size_t)b * CC + cw) * N + n0 + nk;
#pragma unroll
  for (int j = 0; j < 16; j += 4) {
    *(float4*)(dst + j) = make_float4(T[cw][nk + j], T[cw][nk + j + 1],
                                      T[cw][nk + j + 2], T[cw][nk + j + 3]);
  }
}

// ---------------------------------------------------------------------------
// final2: FUSED scale-1 combine (KS=2 partials) + output assembly.
// ---------------------------------------------------------------------------
__global__ __launch_bounds__(256) void final2_kernel(
    const float* __restrict__ xin,
    const unsigned short* __restrict__ Op1, const float* __restrict__ Lp1,
    const float* __restrict__ a2c, const float* __restrict__ a4,
    float* __restrict__ out) {
  __shared__ float T[64][65];
  const int tid = threadIdx.x;
  const int y = blockIdx.x & 63;
  const int b = blockIdx.x >> 6;
  const size_t S1 = (size_t)BB * NPIX * CC;
  const size_t T1 = (size_t)BB * NPIX;

  {  // ---- phase 1: combine row y ----
    const int nl = tid >> 2;
    const int ck = (tid & 3) * 16;
    const int n  = y * 64 + nl;
    float lv = 0.f;
#pragma unroll
    for (int ks = 0; ks < 2; ++ks)
      lv += Lp1[(size_t)ks * T1 + (size_t)b * NPIX + n];
    const float inv = 1.f / lv;
    float v[16];
#pragma unroll
    for (int j = 0; j < 16; ++j) v[j] = 0.f;
#pragma unroll
    for (int ks = 0; ks < 2; ++ks) {
      const unsigned short* src =
          Op1 + (size_t)ks * S1 + ((size_t)b * NPIX + n) * CC + ck;
      const ushort8 u0 = *(const ushort8*)(src);
      const ushort8 u1 = *(const ushort8*)(src + 8);
#pragma unroll
      for (int j = 0; j < 8; ++j) {
        v[j]     += bf2f(u0[j]);
        v[8 + j] += bf2f(u1[j]);
      }
    }
#pragma unroll
    for (int j = 0; j < 16; ++j) T[ck + j][nl] = v[j] * inv;
  }
  __syncthreads();

  // ---- phase 2: assemble output row ----
  const int c  = tid >> 2;
  const int xk = (tid & 3) * 16;
  const float* xrow = xin + (((size_t)b * CC + c) * HH + y) * WW;
  float* orow = out + (((size_t)b * CC + c) * HH + y) * WW;

  const float ty2 = y * 0.5f - 0.25f;
  const int iy2 = (int)floorf(ty2);
  const float wy2 = ty2 - iy2;
  const int iy20 = max(iy2, 0), iy21 = min(iy2 + 1, 31);
  const float* b2 = a2c + ((size_t)b * CC + c) * 1024;
  const float ty4 = y * 0.25f - 0.375f;
  const int iy4 = (int)floorf(ty4);
  const float wy4 = ty4 - iy4;
  const int iy40 = max(iy4, 0), iy41 = min(iy4 + 1, 15);
  const float* b4 = a4 + (size_t)b * 256 * 64 + c;

#pragma unroll
  for (int j = 0; j < 16; ++j) {
    const int xx = xk + j;
    float r = xrow[xx] + T[c][xx];
    {  // scale 2
      const float tx = xx * 0.5f - 0.25f;
      const int ix = (int)floorf(tx);
      const float wx = tx - ix;
      const int ix0 = max(ix, 0), ix1 = min(ix + 1, 31);
      const float v00 = b2[iy20 * 32 + ix0], v01 = b2[iy20 * 32 + ix1];
      const float v10 = b2[iy21 * 32 + ix0], v11 = b2[iy21 * 32 + ix1];
      r += (1.f-wy2)*((1.f-wx)*v00 + wx*v01) + wy2*((1.f-wx)*v10 + wx*v11);
    }
    {  // scale 4
      const float tx = xx * 0.25f - 0.375f;
      const int ix = (int)floorf(tx);
      const float wx = tx - ix;
      const int ix0 = max(ix, 0), ix1 = min(ix + 1, 15);
      const float v00 = b4[(iy40*16+ix0)*64], v01 = b4[(iy40*16+ix1)*64];
      const float v10 = b4[(iy41*16+ix0)*64], v11 = b4[(iy41*16+ix1)*64];
      r += (1.f-wy4)*((1.f-wx)*v00 + wx*v01) + wy4*((1.f-wx)*v10 + wx*v11);
    }
    orow[xx] = r;
  }
}

// ---------------------------------------------------------------------------
extern "C" void kernel_launch(void* const* d_in, const int* in_sizes, int n_in,
                              void* d_out, int out_size, void* d_ws,
                              size_t ws_size, hipStream_t stream) {
  const float* x = (const float*)d_in[0];
  const float* w = (const float*)d_in[1];
  float* out = (float*)d_out;

  unsigned short* fh1 = (unsigned short*)d_ws;            // [8][4096][64] swz
  unsigned short* fl1 = fh1 + (size_t)BB*NPIX*CC;
  unsigned short* fv1 = fl1 + (size_t)BB*NPIX*CC;         // tile-major V^T
  unsigned short* fh2 = fv1 + (size_t)BB*NPIX*CC;         // [8][1024][64]
  unsigned short* fl2 = fh2 + (size_t)BB*1024*CC;
  unsigned short* fv2 = fl2 + (size_t)BB*1024*CC;
  unsigned short* fh4 = fv2 + (size_t)BB*1024*CC;         // [8][256][64]
  unsigned short* fl4 = fh4 + (size_t)BB*256*CC;
  unsigned short* fv4 = fl4 + (size_t)BB*256*CC;
  unsigned short* Op1 = fv4 + (size_t)BB*256*CC;          // [2][8][4096][64] bf16
  float* Lp1 = (float*)(Op1 + 2*(size_t)BB*NPIX*CC);      // [2][8][4096]
  unsigned short* Op2 = (unsigned short*)(Lp1 + 2*(size_t)BB*NPIX);  // [2][8][1024][64]
  float* Lp2 = (float*)(Op2 + 2*(size_t)BB*1024*CC);      // [2][8][1024]
  float* a4  = Lp2 + 2*(size_t)BB*1024;                   // [8][256][64] fp32

  // Dead-time aliases (zero workspace growth):
  //   XT/WT (dead after conv_mfma) alias Op1/Op2 (written by attn later)
  //   a2c (combine2 out, 2.1MB) aliases fh2+fl2 (dead after attn_all)
  unsigned short* xth = (unsigned short*)Op1;             // 4.19 MB
  unsigned short* xtl = xth + (size_t)BB*NPIX*CC;         // 4.19 MB (= Op1 end)
  unsigned short* wth = (unsigned short*)Op2;             // 72 KB
  unsigned short* wtl = wth + 9*64*64;                    // 72 KB
  float* a2c = (float*)fh2;                               // [8][64][1024] fp32

  prep_kernel<<<656, 256, 0, stream>>>(x, w, xth, xtl, wth, wtl);
  conv_mfma<<<dim3(64, 8), 256, 0, stream>>>(xth, xtl, wth, wtl, fh1, fl1, fv1);
  pools_kernel<<<2560, 256, 0, stream>>>(fh1, fl1, fh2, fl2, fv2, fh4, fl4, fv4);
  attn_all<<<800, 256, 0, stream>>>(fh1, fl1, fv1, Op1, Lp1,
                                    fh2, fl2, fv2, Op2, Lp2,
                                    fh4, fl4, fv4, a4);
  combine_kernel<2><<<BB * (1024 / 64), 256, 0, stream>>>(Op2, Lp2, a2c, 1024);
  final2_kernel<<<512, 256, 0, stream>>>(x, Op1, Lp1, a2c, a4, out);
}

// Round 15
// 180.195 us; speedup vs baseline: 1.3269x; 1.0919x over previous
//
#include <hip/hip_runtime.h>
#include <hip/hip_bf16.h>
#include <math.h>

// Problem constants: x [8,64,64,64] fp32 NCHW, W_std [64,64,3,3] fp32 OIHW.
#define BB 8
#define CC 64
#define HH 64
#define WW 64
#define NPIX (HH*WW)   // 4096
#define LOG2E 1.44269504088896340736f

typedef __attribute__((ext_vector_type(8))) short bf16x8;            // bf16 A/B frag
typedef __attribute__((ext_vector_type(8))) _Float16 half8;          // fp16 A/B frag
typedef __attribute__((ext_vector_type(4))) float floatx4;           // MFMA C/D frag
typedef __attribute__((ext_vector_type(8))) unsigned short ushort8;  // 16B unit

__device__ inline unsigned short f2bf(float x) {
  __hip_bfloat16 h = __float2bfloat16(x);
  return *reinterpret_cast<unsigned short*>(&h);
}
__device__ inline float bf2f(unsigned short u) {
  __hip_bfloat16 h = *reinterpret_cast<__hip_bfloat16*>(&u);
  return __bfloat162float(h);
}
__device__ inline unsigned short f2h(float x) {
  _Float16 h = (_Float16)x;
  return *reinterpret_cast<unsigned short*>(&h);
}
__device__ inline float h2f(unsigned short u) {
  _Float16 h = *reinterpret_cast<_Float16*>(&u);
  return (float)h;
}

// XOR swizzle: 16B channel-chunks permuted within each 128B row so MFMA
// fragment reads from LDS (lane stride 128B) spread across all 32 banks.
__device__ inline int swzoff(int n, int c) {
  return (((c >> 3) ^ (n & 7)) << 3) | (c & 7);
}
__device__ inline int swzvslot(int key, int c) {
  return (((key >> 3) ^ (c & 7)) << 3) | (key & 7);
}

// 16B global -> LDS DMA
#define GLD_LDS16(gp, lp)                                                     \
  __builtin_amdgcn_global_load_lds(                                           \
      (const __attribute__((address_space(1))) void*)(gp),                    \
      (__attribute__((address_space(3))) void*)(lp), 16, 0, 0)

// ---------------------------------------------------------------------------
// prep: merged xt (512 blocks) + wprep (144 blocks). XT/WT stay bf16 hi/lo
// (conv's 3-pass bf16 MFMA path is unchanged).
// ---------------------------------------------------------------------------
__global__ __launch_bounds__(256) void prep_kernel(
    const float* __restrict__ xin, const float* __restrict__ w,
    unsigned short* __restrict__ xth, unsigned short* __restrict__ xtl,
    unsigned short* __restrict__ wth, unsigned short* __restrict__ wtl) {
  __shared__ float XL[64][65];
  const int bid = blockIdx.x;
  const int tid = threadIdx.x;
  if (bid < 512) {            // ---- xt ----
    const int y = bid & 63, b = bid >> 6;
    const int xq = tid & 15, cw = tid >> 4;
    const float* xb = xin + (size_t)b * CC * NPIX + y * WW;
#pragma unroll
    for (int p = 0; p < 4; ++p) {
      const int c = p * 16 + cw;
      const float4 v = *(const float4*)(xb + (size_t)c * NPIX + xq * 4);
      XL[c][xq * 4 + 0] = v.x; XL[c][xq * 4 + 1] = v.y;
      XL[c][xq * 4 + 2] = v.z; XL[c][xq * 4 + 3] = v.w;
    }
    __syncthreads();
    const int px = tid & 63, cp = tid >> 6;
    const size_t nb = ((size_t)b * NPIX + y * WW + px) * CC;
    ushort8 vh[2], vl[2];
#pragma unroll
    for (int j = 0; j < 16; ++j) {
      const float v = XL[cp * 16 + j][px];
      const unsigned short hh = f2bf(v);
      vh[j >> 3][j & 7] = hh;
      vl[j >> 3][j & 7] = f2bf(v - bf2f(hh));
    }
#pragma unroll
    for (int k = 0; k < 2; ++k) {
      const int ch = cp * 2 + k;
      const int off = ((ch ^ (px & 7)) << 3);
      *(ushort8*)(xth + nb + off) = vh[k];
      *(ushort8*)(xtl + nb + off) = vl[k];
    }
  } else {                    // ---- wprep: Laplacian folded into weights ----
    const int idx = (bid - 512) * 256 + tid;    // 9*64*64 = 36864
    const int c   = idx & 63;
    const int o   = (idx >> 6) & 63;
    const int tap = idx >> 12;
    float v = w[((o * 64 + c) * 9) + tap];
    if (o == c) {
      const float lapk[9] = {0.f, 1.f, 0.f, 1.f, -4.f, 1.f, 0.f, 1.f, 0.f};
      v += lapk[tap];
    }
    const unsigned short hi = f2bf(v);
    wth[(tap * 64 + o) * 64 + c] = hi;
    wtl[(tap * 64 + o) * 64 + c] = f2bf(v - bf2f(hi));
  }
}

// ---------------------------------------------------------------------------
// conv_mfma: implicit-GEMM conv (bf16 internals unchanged).
// Epilogue now emits feat as FP16 hi/lo (fh/fl) + bf16 V^T (fv): fp16's
// 11-bit mantissa lets attention compute S in 2 passes with K-hi only.
// ---------------------------------------------------------------------------
__global__ __launch_bounds__(256, 2) void conv_mfma(
    const unsigned short* __restrict__ xth,
    const unsigned short* __restrict__ xtl,
    const unsigned short* __restrict__ wth,
    const unsigned short* __restrict__ wtl,
    unsigned short* __restrict__ fh, unsigned short* __restrict__ fl,
    unsigned short* __restrict__ fv) {
  __shared__ __align__(16) unsigned short XS[6 * 4096];

  const int tid  = threadIdx.x;
  const int lane = tid & 63;
  const int wave = tid >> 6;
  const int r16  = lane & 15;
  const int quad = lane >> 4;
  const int y = blockIdx.x, b = blockIdx.y;

#pragma unroll
  for (int r = 0; r < 3; ++r) {
    const int yy = min(max(y - 1 + r, 0), HH - 1);
    const unsigned short* sh = xth + ((size_t)b * NPIX + yy * WW) * CC;
    const unsigned short* sl = xtl + ((size_t)b * NPIX + yy * WW) * CC;
    GLD_LDS16(sh + tid * 8,        &XS[r * 4096 + tid * 8]);
    GLD_LDS16(sh + 2048 + tid * 8, &XS[r * 4096 + 2048 + tid * 8]);
    GLD_LDS16(sl + tid * 8,        &XS[(3 + r) * 4096 + tid * 8]);
    GLD_LDS16(sl + 2048 + tid * 8, &XS[(3 + r) * 4096 + 2048 + tid * 8]);
  }
  __syncthreads();

  floatx4 acc[4];
#pragma unroll
  for (int t = 0; t < 4; ++t) acc[t] = (floatx4){0.f, 0.f, 0.f, 0.f};
  const bf16x8 ZF = {0, 0, 0, 0, 0, 0, 0, 0};
  const int og = wave * 16 + r16;

#pragma unroll
  for (int tap = 0; tap < 9; ++tap) {
    const int ky = tap / 3, kx = tap % 3;
    const int yy = y + ky - 1;
    if (yy < 0 || yy >= HH) continue;
    const unsigned short* wt = wth + ((tap * 64 + og) << 6);
    const unsigned short* wl = wtl + ((tap * 64 + og) << 6);
    const bf16x8 Wh0 = *(const bf16x8*)(wt + quad * 8);
    const bf16x8 Wh1 = *(const bf16x8*)(wt + 32 + quad * 8);
    const bf16x8 Wl0 = *(const bf16x8*)(wl + quad * 8);
    const bf16x8 Wl1 = *(const bf16x8*)(wl + 32 + quad * 8);
#pragma unroll
    for (int t = 0; t < 4; ++t) {
      const int px = t * 16 + r16 + kx - 1;
      const bool ok = (px >= 0) && (px < WW);
      const int pxc = ok ? px : 0;
      const int bh = ky * 4096 + pxc * 64;
      const int bl = bh + 3 * 4096;
      const int o0 = ((quad ^ (pxc & 7)) << 3);
      const int o1 = (((4 + quad) ^ (pxc & 7)) << 3);
      bf16x8 Ah0 = *(const bf16x8*)(XS + bh + o0);
      bf16x8 Ah1 = *(const bf16x8*)(XS + bh + o1);
      bf16x8 Al0 = *(const bf16x8*)(XS + bl + o0);
      bf16x8 Al1 = *(const bf16x8*)(XS + bl + o1);
      if (!ok) { Ah0 = ZF; Ah1 = ZF; Al0 = ZF; Al1 = ZF; }
      acc[t] = __builtin_amdgcn_mfma_f32_16x16x32_bf16(Ah0, Wh0, acc[t], 0, 0, 0);
      acc[t] = __builtin_amdgcn_mfma_f32_16x16x32_bf16(Ah1, Wh1, acc[t], 0, 0, 0);
      acc[t] = __builtin_amdgcn_mfma_f32_16x16x32_bf16(Ah0, Wl0, acc[t], 0, 0, 0);
      acc[t] = __builtin_amdgcn_mfma_f32_16x16x32_bf16(Ah1, Wl1, acc[t], 0, 0, 0);
      acc[t] = __builtin_amdgcn_mfma_f32_16x16x32_bf16(Al0, Wh0, acc[t], 0, 0, 0);
      acc[t] = __builtin_amdgcn_mfma_f32_16x16x32_bf16(Al1, Wh1, acc[t], 0, 0, 0);
    }
  }

#pragma unroll
  for (int t = 0; t < 4; ++t)
#pragma unroll
    for (int r = 0; r < 4; ++r) {
      const int key = t * 16 + quad * 4 + r;
      const int n = y * WW + key;
      const float v = acc[t][r];
      const unsigned short hi = f2h(v);               // fp16 hi
      const unsigned short lo = f2h(v - h2f(hi));     // fp16 lo
      fh[((size_t)b * NPIX + n) * CC + swzoff(n, og)] = hi;
      fl[((size_t)b * NPIX + n) * CC + swzoff(n, og)] = lo;
      fv[(((size_t)b * (NPIX >> 6) + y) * CC + og) * 64 + swzvslot(key, og)] =
          f2bf(v);                                    // V^T stays bf16
    }
}

// ---------------------------------------------------------------------------
// pools: merged pool2 + pool4-direct. Reads fp16 hi/lo, writes fp16 hi/lo
// (fh/fl) + bf16 (fv).
// ---------------------------------------------------------------------------
__global__ void pools_kernel(const unsigned short* __restrict__ in_h,
                             const unsigned short* __restrict__ in_l,
                             unsigned short* __restrict__ h2,
                             unsigned short* __restrict__ l2,
                             unsigned short* __restrict__ v2,
                             unsigned short* __restrict__ h4,
                             unsigned short* __restrict__ l4,
                             unsigned short* __restrict__ v4) {
  const int bid = blockIdx.x;
  if (bid < 2048) {           // ---- pool2: 64x64 -> 32x32 ----
    const int idx = bid * 256 + threadIdx.x;
    const int c  = idx & 63;
    const int t  = idx >> 6;
    const int xo = t & 31;
    const int yo = (t >> 5) & 31;
    const int b  = t >> 10;
    const size_t ibase = (size_t)b * NPIX * CC;
    float s = 0.f;
#pragma unroll
    for (int dy = 0; dy < 2; ++dy)
#pragma unroll
      for (int dx = 0; dx < 2; ++dx) {
        const int nin = (2*yo+dy) * 64 + (2*xo+dx);
        const size_t a = ibase + (size_t)nin * CC + swzoff(nin, c);
        s += h2f(in_h[a]) + h2f(in_l[a]);
      }
    const float vv = 0.25f * s;
    const unsigned short hi = f2h(vv);
    const int nout = yo * 32 + xo;
    const size_t ob = ((size_t)b * 1024 + nout) * CC + swzoff(nout, c);
    h2[ob] = hi;
    l2[ob] = f2h(vv - h2f(hi));
    v2[(((size_t)b * 16 + (nout >> 6)) * CC + c) * 64 + swzvslot(nout & 63, c)] =
        f2bf(vv);
  } else {                    // ---- pool4: 64x64 -> 16x16 (direct) ----
    const int idx = (bid - 2048) * 256 + threadIdx.x;
    const int c  = idx & 63;
    const int t  = idx >> 6;
    const int xo = t & 15;
    const int yo = (t >> 4) & 15;
    const int b  = t >> 8;
    const size_t ibase = (size_t)b * NPIX * CC;
    float s = 0.f;
#pragma unroll
    for (int dy = 0; dy < 4; ++dy)
#pragma unroll
      for (int dx = 0; dx < 4; ++dx) {
        const int nin = (4*yo+dy) * 64 + (4*xo+dx);
        const size_t a = ibase + (size_t)nin * CC + swzoff(nin, c);
        s += h2f(in_h[a]) + h2f(in_l[a]);
      }
    const float vv = 0.0625f * s;
    const unsigned short hi = f2h(vv);
    const int nout = yo * 16 + xo;
    const size_t ob = ((size_t)b * 256 + nout) * CC + swzoff(nout, c);
    h4[ob] = hi;
    l4[ob] = f2h(vv - h2f(hi));
    v4[(((size_t)b * 4 + (nout >> 6)) * CC + c) * 64 + swzvslot(nout & 63, c)] =
        f2bf(vv);
  }
}

// ---------------------------------------------------------------------------
// MFMA flash attention <NH, KS>, round-15 numerics:
//   fp16 K (HI ONLY): s = (Qh+Ql)·Kh = Q·Kh exactly (Q split fp16 hi/lo);
//   dropped correction Q·Kl ~ 2^-12 rel (~0.4% on p — at the existing bf16-P
//   error level). S-MFMA 6 -> 4 per (tt,h); Kl never staged -> K LDS traffic
//   and staging DMA drop; LDS 67.6 -> 50.4 KB -> 3 blocks/CU.
//   P/V/O stay bf16 (p's dynamic range can exceed fp16 65504).
//   Per-tt fused softmax (round 14) retained.
// ---------------------------------------------------------------------------
#define STR 72   // P-tile LDS row stride (shorts); 144B keeps b128 aligned

template <int NH, int KS>
__device__ __forceinline__ void attn_body(
    int bid,
    const unsigned short* __restrict__ fh,
    const unsigned short* __restrict__ fl,
    const unsigned short* __restrict__ fv,
    float* __restrict__ outF, unsigned short* __restrict__ outB,
    float* __restrict__ outL, int N,
    unsigned short* KVT, unsigned short* PtB) {
  const int tid  = threadIdx.x;
  const int lane = tid & 63;
  const int wave = tid >> 6;
  const int b    = bid & 7;              // XCD-local batch grouping
  const int rest = bid >> 3;
  const int nq   = N / (64 * NH);
  const int qt   = rest % nq;
  const int ks   = rest / nq;            // 0..KS-1
  const int q0   = qt * (64 * NH) + wave * (16 * NH);
  const int nt   = (N >> 6) / KS;
  const int t0   = ks * nt;
  const int r16  = lane & 15;
  const int quad = lane >> 4;
  const int swb  = r16 & 7;

  const unsigned short* fhB = fh + (size_t)b * N * CC;   // fp16 K/Q hi
  const unsigned short* flB = fl + (size_t)b * N * CC;   // fp16 Q lo
  const unsigned short* fvB = fv + (size_t)b * N * CC;   // bf16 tile-major V^T

  // ---- stage first tile via DMA: 16 chunks of 512 shorts; wave takes 4 ----
  {
    const size_t tb = (size_t)t0 * 4096;
#pragma unroll
    for (int j = 0; j < 4; ++j) {
      const int cid = wave * 4 + j;
      const int arr = cid >> 3, sub = (cid & 7) << 9;
      const unsigned short* g = (arr == 0 ? fhB : fvB) + tb + sub + lane * 8;
      GLD_LDS16(g, KVT + arr * 4096 + sub + lane * 8);
    }
  }

  // ---- Q fragments per half: f = h+l, g = f*log2e, fp16 re-split, M ----
  half8 Qh[NH][2], Ql[NH][2];
  float Mq[NH][4];
#pragma unroll
  for (int h = 0; h < NH; ++h) {
    float Mpart = 0.f;
#pragma unroll
    for (int kss = 0; kss < 2; ++kss) {
      const size_t off = (size_t)(q0 + h * 16 + r16) * CC
                         + ((((kss << 2) + quad) ^ swb) << 3);
      const ushort8 hh = *(const ushort8*)(fhB + off);
      const ushort8 ll = *(const ushort8*)(flB + off);
      half8 sh, sl;
#pragma unroll
      for (int j = 0; j < 8; ++j) {
        const float f = h2f(hh[j]) + h2f(ll[j]);
        const float g = f * LOG2E;
        const _Float16 gh = (_Float16)g;
        sh[j] = gh;
        sl[j] = (_Float16)(g - (float)gh);
        Mpart += g * f;                  // = log2e * sum f^2 (partial)
      }
      Qh[h][kss] = sh;
      Ql[h][kss] = sl;
    }
    Mpart += __shfl_xor(Mpart, 16, 64);
    Mpart += __shfl_xor(Mpart, 32, 64);  // per-row |q|^2*log2e at lane r16
#pragma unroll
    for (int r = 0; r < 4; ++r) Mq[h][r] = __shfl(Mpart, quad * 4 + r, 64);
  }

  floatx4 O[NH][4];
  float lrun[NH][4];
#pragma unroll
  for (int h = 0; h < NH; ++h)
#pragma unroll
    for (int ch = 0; ch < 4; ++ch) {
      O[h][ch] = (floatx4){0.f, 0.f, 0.f, 0.f};
      lrun[h][ch] = 0.f;
    }
  unsigned short* ptw = PtB + wave * (NH * 16 * STR);

  int koff[2];
#pragma unroll
  for (int kss = 0; kss < 2; ++kss) koff[kss] = (((kss << 2) + quad) ^ swb) << 3;

  for (int t = 0; t < nt; ++t) {
    const int cur = t & 1;
    __syncthreads();                    // drains DMA for tile t, syncs block
    if (t + 1 < nt) {                   // issue DMA for tile t+1 now
      const size_t tb = (size_t)(t0 + t + 1) * 4096;
      unsigned short* dst = KVT + (cur ^ 1) * 8192;
#pragma unroll
      for (int j = 0; j < 4; ++j) {
        const int cid = wave * 4 + j;
        const int arr = cid >> 3, sub = (cid & 7) << 9;
        const unsigned short* g = (arr == 0 ? fhB : fvB) + tb + sub + lane * 8;
        GLD_LDS16(g, dst + arr * 4096 + sub + lane * 8);
      }
    }
    const unsigned short* kh = KVT + cur * 8192;   // fp16 K hi
    const unsigned short* vt = kh + 4096;          // bf16 V^T

    // ---- S-tiles (4 f16 MFMA) with FUSED per-tt softmax ----
#pragma unroll
    for (int tt = 0; tt < 4; ++tt) {
      const int kbase = (tt * 16 + r16) * 64;
      const half8 Kh0 = *(const half8*)(kh + kbase + koff[0]);
      const half8 Kh1 = *(const half8*)(kh + kbase + koff[1]);
#pragma unroll
      for (int h = 0; h < NH; ++h) {
        floatx4 s = (floatx4){0.f, 0.f, 0.f, 0.f};
        s = __builtin_amdgcn_mfma_f32_16x16x32_f16(Qh[h][0], Kh0, s, 0, 0, 0);
        s = __builtin_amdgcn_mfma_f32_16x16x32_f16(Qh[h][1], Kh1, s, 0, 0, 0);
        s = __builtin_amdgcn_mfma_f32_16x16x32_f16(Ql[h][0], Kh0, s, 0, 0, 0);
        s = __builtin_amdgcn_mfma_f32_16x16x32_f16(Ql[h][1], Kh1, s, 0, 0, 0);
        unsigned short* pth = ptw + h * (16 * STR);
#pragma unroll
        for (int r = 0; r < 4; ++r) {
          const float p = __builtin_amdgcn_exp2f(s[r] - Mq[h][r]);
          lrun[h][r] += p;
          pth[(quad * 4 + r) * STR + tt * 16 + r16] = f2bf(p);
        }
      }
    }

    // ---- P reads (bf16 A-layout) + O += P*V (bf16) ----
    bf16x8 Pf[NH][2];
#pragma unroll
    for (int h = 0; h < NH; ++h)
#pragma unroll
      for (int kss = 0; kss < 2; ++kss)
        Pf[h][kss] = *(const bf16x8*)(ptw + h * (16 * STR) + r16 * STR
                                      + kss * 32 + quad * 8);
#pragma unroll
    for (int kss = 0; kss < 2; ++kss)
#pragma unroll
      for (int ch = 0; ch < 4; ++ch) {
        const bf16x8 Vf = *(const bf16x8*)(vt + (ch * 16 + r16) * 64 + koff[kss]);
#pragma unroll
        for (int h = 0; h < NH; ++h)
          O[h][ch] = __builtin_amdgcn_mfma_f32_16x16x32_bf16(Pf[h][kss], Vf,
                                                            O[h][ch], 0, 0, 0);
      }
  }

  // ---- epilogue ----
#pragma unroll
  for (int h = 0; h < NH; ++h) {
#pragma unroll
    for (int r = 0; r < 4; ++r) {
      float lt = lrun[h][r];
      lt += __shfl_xor(lt, 1, 16);
      lt += __shfl_xor(lt, 2, 16);
      lt += __shfl_xor(lt, 4, 16);
      lt += __shfl_xor(lt, 8, 16);
      if (KS == 1) {
        lrun[h][r] = 1.f / lt;
      } else if (r16 == 0) {
        outL[(size_t)ks * BB * N + (size_t)b * N + q0 + h * 16 + quad * 4 + r] = lt;
      }
    }
#pragma unroll
    for (int ch = 0; ch < 4; ++ch)
#pragma unroll
      for (int r = 0; r < 4; ++r) {
        const size_t qi = (size_t)b * N + q0 + h * 16 + quad * 4 + r;
        if (KS == 1) {
          outF[qi * CC + ch * 16 + r16] = O[h][ch][r] * lrun[h][r];
        } else {
          outB[(size_t)ks * BB * N * CC + qi * CC + ch * 16 + r16] =
              f2bf(O[h][ch][r]);
        }
      }
  }
}

// Merged dispatch: [0,512) scale-1 NH=2/KS=2; [512,768) scale-2 NH=1/KS=2;
// [768,800) scale-4 NH=1/KS=1. LDS 50.4KB -> 3 blocks/CU.
__global__ __launch_bounds__(256, 3) void attn_all(
    const unsigned short* __restrict__ fh1, const unsigned short* __restrict__ fl1,
    const unsigned short* __restrict__ fv1,
    unsigned short* __restrict__ Op1, float* __restrict__ Lp1,
    const unsigned short* __restrict__ fh2, const unsigned short* __restrict__ fl2,
    const unsigned short* __restrict__ fv2,
    unsigned short* __restrict__ Op2, float* __restrict__ Lp2,
    const unsigned short* __restrict__ fh4, const unsigned short* __restrict__ fl4,
    const unsigned short* __restrict__ fv4, float* __restrict__ a4) {
  __shared__ __align__(16) unsigned short KVT[2][2 * 4096];
  __shared__ __align__(16) unsigned short Pt[4][2 * 16 * STR];
  const int bid = blockIdx.x;
  if (bid < 512) {
    attn_body<2, 2>(bid, fh1, fl1, fv1, nullptr, Op1, Lp1, NPIX,
                    &KVT[0][0], &Pt[0][0]);
  } else if (bid < 768) {
    attn_body<1, 2>(bid - 512, fh2, fl2, fv2, nullptr, Op2, Lp2, 1024,
                    &KVT[0][0], &Pt[0][0]);
  } else {
    attn_body<1, 1>(bid - 768, fh4, fl4, fv4, a4, nullptr, nullptr, 256,
                    &KVT[0][0], &Pt[0][0]);
  }
}

// ---------------------------------------------------------------------------
// combine (scale-2): sum KS bf16 O-partials + l (coalesced along c),
// normalize, LDS-transpose, write CHANNEL-MAJOR fp32 outC[b][c][n].
// ---------------------------------------------------------------------------
template <int KS>
__global__ __launch_bounds__(256) void combine_kernel(
    const unsigned short* __restrict__ Op, const float* __restrict__ Lp,
    float* __restrict__ outC, int N) {
  __shared__ float T[64][65];
  const int tid = threadIdx.x;
  const int nt  = N >> 6;
  const int b   = blockIdx.x / nt;
  const int n0  = (blockIdx.x % nt) * 64;
  const int nl  = tid >> 2;
  const int ck  = (tid & 3) * 16;
  const int n   = n0 + nl;

  float lv = 0.f;
#pragma unroll
  for (int ks = 0; ks < KS; ++ks)
    lv += Lp[(size_t)ks * BB * N + (size_t)b * N + n];
  const float inv = 1.f / lv;

  float v[16];
#pragma unroll
  for (int j = 0; j < 16; ++j) v[j] = 0.f;
#pragma unroll
  for (int ks = 0; ks < KS; ++ks) {
    const unsigned short* src =
        Op + (size_t)ks * BB * N * CC + ((size_t)b * N + n) * CC + ck;
    const ushort8 u0 = *(const ushort8*)(src);
    const ushort8 u1 = *(const ushort8*)(src + 8);
#pragma unroll
    for (int j = 0; j < 8; ++j) {
      v[j]     += bf2f(u0[j]);
      v[8 + j] += bf2f(u1[j]);
    }
  }
#pragma unroll
  for (int j = 0; j < 16; ++j) T[ck + j][nl] = v[j] * inv;
  __syncthreads();

  const int cw = tid >> 2;
  const int nk = (tid & 3) * 16;
  float* dst = outC + ((size_t)b * CC + cw) * N + n0 + nk;
#pragma unroll
  for (int j = 0; j < 16; j += 4) {
    *(float4*)(dst + j) = make_float4(T[cw][nk + j], T[cw][nk + j + 1],
                                      T[cw][nk + j + 2], T[cw][nk + j + 3]);
  }
}

// ---------------------------------------------------------------------------
// final2: FUSED scale-1 combine (KS=2 bf16 partials) + output assembly.
// ---------------------------------------------------------------------------
__global__ __launch_bounds__(256) void final2_kernel(
    const float* __restrict__ xin,
    const unsigned short* __restrict__ Op1, const float* __restrict__ Lp1,
    const float* __restrict__ a2c, const float* __restrict__ a4,
    float* __restrict__ out) {
  __shared__ float T[64][65];
  const int tid = threadIdx.x;
  const int y = blockIdx.x & 63;
  const int b = blockIdx.x >> 6;
  const size_t S1 = (size_t)BB * NPIX * CC;
  const size_t T1 = (size_t)BB * NPIX;

  {  // ---- phase 1: combine row y ----
    const int nl = tid >> 2;
    const int ck = (tid & 3) * 16;
    const int n  = y * 64 + nl;
    float lv = 0.f;
#pragma unroll
    for (int ks = 0; ks < 2; ++ks)
      lv += Lp1[(size_t)ks * T1 + (size_t)b * NPIX + n];
    const float inv = 1.f / lv;
    float v[16];
#pragma unroll
    for (int j = 0; j < 16; ++j) v[j] = 0.f;
#pragma unroll
    for (int ks = 0; ks < 2; ++ks) {
      const unsigned short* src =
          Op1 + (size_t)ks * S1 + ((size_t)b * NPIX + n) * CC + ck;
      const ushort8 u0 = *(const ushort8*)(src);
      const ushort8 u1 = *(const ushort8*)(src + 8);
#pragma unroll
      for (int j = 0; j < 8; ++j) {
        v[j]     += bf2f(u0[j]);
        v[8 + j] += bf2f(u1[j]);
      }
    }
#pragma unroll
    for (int j = 0; j < 16; ++j) T[ck + j][nl] = v[j] * inv;
  }
  __syncthreads();

  // ---- phase 2: assemble output row ----
  const int c  = tid >> 2;
  const int xk = (tid & 3) * 16;
  const float* xrow = xin + (((size_t)b * CC + c) * HH + y) * WW;
  float* orow = out + (((size_t)b * CC + c) * HH + y) * WW;

  const float ty2 = y * 0.5f - 0.25f;
  const int iy2 = (int)floorf(ty2);
  const float wy2 = ty2 - iy2;
  const int iy20 = max(iy2, 0), iy21 = min(iy2 + 1, 31);
  const float* b2 = a2c + ((size_t)b * CC + c) * 1024;
  const float ty4 = y * 0.25f - 0.375f;
  const int iy4 = (int)floorf(ty4);
  const float wy4 = ty4 - iy4;
  const int iy40 = max(iy4, 0), iy41 = min(iy4 + 1, 15);
  const float* b4 = a4 + (size_t)b * 256 * 64 + c;

#pragma unroll
  for (int j = 0; j < 16; ++j) {
    const int xx = xk + j;
    float r = xrow[xx] + T[c][xx];
    {  // scale 2
      const float tx = xx * 0.5f - 0.25f;
      const int ix = (int)floorf(tx);
      const float wx = tx - ix;
      const int ix0 = max(ix, 0), ix1 = min(ix + 1, 31);
      const float v00 = b2[iy20 * 32 + ix0], v01 = b2[iy20 * 32 + ix1];
      const float v10 = b2[iy21 * 32 + ix0], v11 = b2[iy21 * 32 + ix1];
      r += (1.f-wy2)*((1.f-wx)*v00 + wx*v01) + wy2*((1.f-wx)*v10 + wx*v11);
    }
    {  // scale 4
      const float tx = xx * 0.25f - 0.375f;
      const int ix = (int)floorf(tx);
      const float wx = tx - ix;
      const int ix0 = max(ix, 0), ix1 = min(ix + 1, 15);
      const float v00 = b4[(iy40*16+ix0)*64], v01 = b4[(iy40*16+ix1)*64];
      const float v10 = b4[(iy41*16+ix0)*64], v11 = b4[(iy41*16+ix1)*64];
      r += (1.f-wy4)*((1.f-wx)*v00 + wx*v01) + wy4*((1.f-wx)*v10 + wx*v11);
    }
    orow[xx] = r;
  }
}

// ---------------------------------------------------------------------------
extern "C" void kernel_launch(void* const* d_in, const int* in_sizes, int n_in,
                              void* d_out, int out_size, void* d_ws,
                              size_t ws_size, hipStream_t stream) {
  const float* x = (const float*)d_in[0];
  const float* w = (const float*)d_in[1];
  float* out = (float*)d_out;

  unsigned short* fh1 = (unsigned short*)d_ws;            // [8][4096][64] fp16 swz
  unsigned short* fl1 = fh1 + (size_t)BB*NPIX*CC;         // fp16 lo
  unsigned short* fv1 = fl1 + (size_t)BB*NPIX*CC;         // bf16 tile-major V^T
  unsigned short* fh2 = fv1 + (size_t)BB*NPIX*CC;         // [8][1024][64]
  unsigned short* fl2 = fh2 + (size_t)BB*1024*CC;
  unsigned short* fv2 = fl2 + (size_t)BB*1024*CC;
  unsigned short* fh4 = fv2 + (size_t)BB*1024*CC;         // [8][256][64]
  unsigned short* fl4 = fh4 + (size_t)BB*256*CC;
  unsigned short* fv4 = fl4 + (size_t)BB*256*CC;
  unsigned short* Op1 = fv4 + (size_t)BB*256*CC;          // [2][8][4096][64] bf16
  float* Lp1 = (float*)(Op1 + 2*(size_t)BB*NPIX*CC);      // [2][8][4096]
  unsigned short* Op2 = (unsigned short*)(Lp1 + 2*(size_t)BB*NPIX);  // [2][8][1024][64]
  float* Lp2 = (float*)(Op2 + 2*(size_t)BB*1024*CC);      // [2][8][1024]
  float* a4  = Lp2 + 2*(size_t)BB*1024;                   // [8][256][64] fp32

  // Dead-time aliases (zero workspace growth):
  //   XT/WT (dead after conv_mfma) alias Op1/Op2 (written by attn later)
  //   a2c (combine2 out, 2.1MB) aliases fh2+fl2 (dead after attn_all)
  unsigned short* xth = (unsigned short*)Op1;             // 4.19 MB
  unsigned short* xtl = xth + (size_t)BB*NPIX*CC;         // 4.19 MB (= Op1 end)
  unsigned short* wth = (unsigned short*)Op2;             // 72 KB
  unsigned short* wtl = wth + 9*64*64;                    // 72 KB
  float* a2c = (float*)fh2;                               // [8][64][1024] fp32

  prep_kernel<<<656, 256, 0, stream>>>(x, w, xth, xtl, wth, wtl);
  conv_mfma<<<dim3(64, 8), 256, 0, stream>>>(xth, xtl, wth, wtl, fh1, fl1, fv1);
  pools_kernel<<<2560, 256, 0, stream>>>(fh1, fl1, fh2, fl2, fv2, fh4, fl4, fv4);
  attn_all<<<800, 256, 0, stream>>>(fh1, fl1, fv1, Op1, Lp1,
                                    fh2, fl2, fv2, Op2, Lp2,
                                    fh4, fl4, fv4, a4);
  combine_kernel<2><<<BB * (1024 / 64), 256, 0, stream>>>(Op2, Lp2, a2c, 1024);
  final2_kernel<<<512, 256, 0, stream>>>(x, Op1, Lp1, a2c, a4, out);
}

// Round 16
// 165.693 us; speedup vs baseline: 1.4430x; 1.0875x over previous
//
#include <hip/hip_runtime.h>
#include <hip/hip_bf16.h>
#include <math.h>

// Problem constants: x [8,64,64,64] fp32 NCHW, W_std [64,64,3,3] fp32 OIHW.
#define BB 8
#define CC 64
#define HH 64
#define WW 64
#define NPIX (HH*WW)   // 4096
#define LOG2E 1.44269504088896340736f

typedef __attribute__((ext_vector_type(8))) short bf16x8;            // bf16 A/B frag
typedef __attribute__((ext_vector_type(8))) _Float16 half8;          // fp16 A/B frag
typedef __attribute__((ext_vector_type(4))) float floatx4;           // MFMA C/D frag
typedef __attribute__((ext_vector_type(8))) unsigned short ushort8;  // 16B unit

__device__ inline unsigned short f2bf(float x) {
  __hip_bfloat16 h = __float2bfloat16(x);
  return *reinterpret_cast<unsigned short*>(&h);
}
// Fast bf16 convert: add round-bias, shift. 2 VALU ops vs ~6-8 for the RNE+NaN
// library path. Valid for +/-, denormals; no NaN/inf in this data path.
__device__ inline unsigned short f2bf_fast(float x) {
  const unsigned u = __float_as_uint(x);
  return (unsigned short)((u + 0x8000u) >> 16);
}
__device__ inline float bf2f(unsigned short u) {
  __hip_bfloat16 h = *reinterpret_cast<__hip_bfloat16*>(&u);
  return __bfloat162float(h);
}
__device__ inline unsigned short f2h(float x) {
  _Float16 h = (_Float16)x;
  return *reinterpret_cast<unsigned short*>(&h);
}
__device__ inline float h2f(unsigned short u) {
  _Float16 h = *reinterpret_cast<_Float16*>(&u);
  return (float)h;
}

// XOR swizzle: 16B channel-chunks permuted within each 128B row so MFMA
// fragment reads from LDS (lane stride 128B) spread across all 32 banks.
__device__ inline int swzoff(int n, int c) {
  return (((c >> 3) ^ (n & 7)) << 3) | (c & 7);
}
__device__ inline int swzvslot(int key, int c) {
  return (((key >> 3) ^ (c & 7)) << 3) | (key & 7);
}

// 16B global -> LDS DMA
#define GLD_LDS16(gp, lp)                                                     \
  __builtin_amdgcn_global_load_lds(                                           \
      (const __attribute__((address_space(1))) void*)(gp),                    \
      (__attribute__((address_space(3))) void*)(lp), 16, 0, 0)

// ---------------------------------------------------------------------------
// prep: merged xt (512 blocks) + wprep (144 blocks). XT/WT stay bf16 hi/lo
// (conv's 3-pass bf16 MFMA path is unchanged).
// ---------------------------------------------------------------------------
__global__ __launch_bounds__(256) void prep_kernel(
    const float* __restrict__ xin, const float* __restrict__ w,
    unsigned short* __restrict__ xth, unsigned short* __restrict__ xtl,
    unsigned short* __restrict__ wth, unsigned short* __restrict__ wtl) {
  __shared__ float XL[64][65];
  const int bid = blockIdx.x;
  const int tid = threadIdx.x;
  if (bid < 512) {            // ---- xt ----
    const int y = bid & 63, b = bid >> 6;
    const int xq = tid & 15, cw = tid >> 4;
    const float* xb = xin + (size_t)b * CC * NPIX + y * WW;
#pragma unroll
    for (int p = 0; p < 4; ++p) {
      const int c = p * 16 + cw;
      const float4 v = *(const float4*)(xb + (size_t)c * NPIX + xq * 4);
      XL[c][xq * 4 + 0] = v.x; XL[c][xq * 4 + 1] = v.y;
      XL[c][xq * 4 + 2] = v.z; XL[c][xq * 4 + 3] = v.w;
    }
    __syncthreads();
    const int px = tid & 63, cp = tid >> 6;
    const size_t nb = ((size_t)b * NPIX + y * WW + px) * CC;
    ushort8 vh[2], vl[2];
#pragma unroll
    for (int j = 0; j < 16; ++j) {
      const float v = XL[cp * 16 + j][px];
      const unsigned short hh = f2bf(v);
      vh[j >> 3][j & 7] = hh;
      vl[j >> 3][j & 7] = f2bf(v - bf2f(hh));
    }
#pragma unroll
    for (int k = 0; k < 2; ++k) {
      const int ch = cp * 2 + k;
      const int off = ((ch ^ (px & 7)) << 3);
      *(ushort8*)(xth + nb + off) = vh[k];
      *(ushort8*)(xtl + nb + off) = vl[k];
    }
  } else {                    // ---- wprep: Laplacian folded into weights ----
    const int idx = (bid - 512) * 256 + tid;    // 9*64*64 = 36864
    const int c   = idx & 63;
    const int o   = (idx >> 6) & 63;
    const int tap = idx >> 12;
    float v = w[((o * 64 + c) * 9) + tap];
    if (o == c) {
      const float lapk[9] = {0.f, 1.f, 0.f, 1.f, -4.f, 1.f, 0.f, 1.f, 0.f};
      v += lapk[tap];
    }
    const unsigned short hi = f2bf(v);
    wth[(tap * 64 + o) * 64 + c] = hi;
    wtl[(tap * 64 + o) * 64 + c] = f2bf(v - bf2f(hi));
  }
}

// ---------------------------------------------------------------------------
// conv_mfma: implicit-GEMM conv (bf16 internals). Epilogue emits feat as
// FP16 hi/lo (fh/fl) + bf16 V^T (fv).
// ---------------------------------------------------------------------------
__global__ __launch_bounds__(256, 2) void conv_mfma(
    const unsigned short* __restrict__ xth,
    const unsigned short* __restrict__ xtl,
    const unsigned short* __restrict__ wth,
    const unsigned short* __restrict__ wtl,
    unsigned short* __restrict__ fh, unsigned short* __restrict__ fl,
    unsigned short* __restrict__ fv) {
  __shared__ __align__(16) unsigned short XS[6 * 4096];

  const int tid  = threadIdx.x;
  const int lane = tid & 63;
  const int wave = tid >> 6;
  const int r16  = lane & 15;
  const int quad = lane >> 4;
  const int y = blockIdx.x, b = blockIdx.y;

#pragma unroll
  for (int r = 0; r < 3; ++r) {
    const int yy = min(max(y - 1 + r, 0), HH - 1);
    const unsigned short* sh = xth + ((size_t)b * NPIX + yy * WW) * CC;
    const unsigned short* sl = xtl + ((size_t)b * NPIX + yy * WW) * CC;
    GLD_LDS16(sh + tid * 8,        &XS[r * 4096 + tid * 8]);
    GLD_LDS16(sh + 2048 + tid * 8, &XS[r * 4096 + 2048 + tid * 8]);
    GLD_LDS16(sl + tid * 8,        &XS[(3 + r) * 4096 + tid * 8]);
    GLD_LDS16(sl + 2048 + tid * 8, &XS[(3 + r) * 4096 + 2048 + tid * 8]);
  }
  __syncthreads();

  floatx4 acc[4];
#pragma unroll
  for (int t = 0; t < 4; ++t) acc[t] = (floatx4){0.f, 0.f, 0.f, 0.f};
  const bf16x8 ZF = {0, 0, 0, 0, 0, 0, 0, 0};
  const int og = wave * 16 + r16;

#pragma unroll
  for (int tap = 0; tap < 9; ++tap) {
    const int ky = tap / 3, kx = tap % 3;
    const int yy = y + ky - 1;
    if (yy < 0 || yy >= HH) continue;
    const unsigned short* wt = wth + ((tap * 64 + og) << 6);
    const unsigned short* wl = wtl + ((tap * 64 + og) << 6);
    const bf16x8 Wh0 = *(const bf16x8*)(wt + quad * 8);
    const bf16x8 Wh1 = *(const bf16x8*)(wt + 32 + quad * 8);
    const bf16x8 Wl0 = *(const bf16x8*)(wl + quad * 8);
    const bf16x8 Wl1 = *(const bf16x8*)(wl + 32 + quad * 8);
#pragma unroll
    for (int t = 0; t < 4; ++t) {
      const int px = t * 16 + r16 + kx - 1;
      const bool ok = (px >= 0) && (px < WW);
      const int pxc = ok ? px : 0;
      const int bh = ky * 4096 + pxc * 64;
      const int bl = bh + 3 * 4096;
      const int o0 = ((quad ^ (pxc & 7)) << 3);
      const int o1 = (((4 + quad) ^ (pxc & 7)) << 3);
      bf16x8 Ah0 = *(const bf16x8*)(XS + bh + o0);
      bf16x8 Ah1 = *(const bf16x8*)(XS + bh + o1);
      bf16x8 Al0 = *(const bf16x8*)(XS + bl + o0);
      bf16x8 Al1 = *(const bf16x8*)(XS + bl + o1);
      if (!ok) { Ah0 = ZF; Ah1 = ZF; Al0 = ZF; Al1 = ZF; }
      acc[t] = __builtin_amdgcn_mfma_f32_16x16x32_bf16(Ah0, Wh0, acc[t], 0, 0, 0);
      acc[t] = __builtin_amdgcn_mfma_f32_16x16x32_bf16(Ah1, Wh1, acc[t], 0, 0, 0);
      acc[t] = __builtin_amdgcn_mfma_f32_16x16x32_bf16(Ah0, Wl0, acc[t], 0, 0, 0);
      acc[t] = __builtin_amdgcn_mfma_f32_16x16x32_bf16(Ah1, Wl1, acc[t], 0, 0, 0);
      acc[t] = __builtin_amdgcn_mfma_f32_16x16x32_bf16(Al0, Wh0, acc[t], 0, 0, 0);
      acc[t] = __builtin_amdgcn_mfma_f32_16x16x32_bf16(Al1, Wh1, acc[t], 0, 0, 0);
    }
  }

#pragma unroll
  for (int t = 0; t < 4; ++t)
#pragma unroll
    for (int r = 0; r < 4; ++r) {
      const int key = t * 16 + quad * 4 + r;
      const int n = y * WW + key;
      const float v = acc[t][r];
      const unsigned short hi = f2h(v);               // fp16 hi
      const unsigned short lo = f2h(v - h2f(hi));     // fp16 lo
      fh[((size_t)b * NPIX + n) * CC + swzoff(n, og)] = hi;
      fl[((size_t)b * NPIX + n) * CC + swzoff(n, og)] = lo;
      fv[(((size_t)b * (NPIX >> 6) + y) * CC + og) * 64 + swzvslot(key, og)] =
          f2bf(v);                                    // V^T stays bf16
    }
}

// ---------------------------------------------------------------------------
// pools: merged pool2 + pool4-direct. Reads fp16 hi/lo, writes fp16 hi/lo
// (fh/fl) + bf16 (fv).
// ---------------------------------------------------------------------------
__global__ void pools_kernel(const unsigned short* __restrict__ in_h,
                             const unsigned short* __restrict__ in_l,
                             unsigned short* __restrict__ h2,
                             unsigned short* __restrict__ l2,
                             unsigned short* __restrict__ v2,
                             unsigned short* __restrict__ h4,
                             unsigned short* __restrict__ l4,
                             unsigned short* __restrict__ v4) {
  const int bid = blockIdx.x;
  if (bid < 2048) {           // ---- pool2: 64x64 -> 32x32 ----
    const int idx = bid * 256 + threadIdx.x;
    const int c  = idx & 63;
    const int t  = idx >> 6;
    const int xo = t & 31;
    const int yo = (t >> 5) & 31;
    const int b  = t >> 10;
    const size_t ibase = (size_t)b * NPIX * CC;
    float s = 0.f;
#pragma unroll
    for (int dy = 0; dy < 2; ++dy)
#pragma unroll
      for (int dx = 0; dx < 2; ++dx) {
        const int nin = (2*yo+dy) * 64 + (2*xo+dx);
        const size_t a = ibase + (size_t)nin * CC + swzoff(nin, c);
        s += h2f(in_h[a]) + h2f(in_l[a]);
      }
    const float vv = 0.25f * s;
    const unsigned short hi = f2h(vv);
    const int nout = yo * 32 + xo;
    const size_t ob = ((size_t)b * 1024 + nout) * CC + swzoff(nout, c);
    h2[ob] = hi;
    l2[ob] = f2h(vv - h2f(hi));
    v2[(((size_t)b * 16 + (nout >> 6)) * CC + c) * 64 + swzvslot(nout & 63, c)] =
        f2bf(vv);
  } else {                    // ---- pool4: 64x64 -> 16x16 (direct) ----
    const int idx = (bid - 2048) * 256 + threadIdx.x;
    const int c  = idx & 63;
    const int t  = idx >> 6;
    const int xo = t & 15;
    const int yo = (t >> 4) & 15;
    const int b  = t >> 8;
    const size_t ibase = (size_t)b * NPIX * CC;
    float s = 0.f;
#pragma unroll
    for (int dy = 0; dy < 4; ++dy)
#pragma unroll
      for (int dx = 0; dx < 4; ++dx) {
        const int nin = (4*yo+dy) * 64 + (4*xo+dx);
        const size_t a = ibase + (size_t)nin * CC + swzoff(nin, c);
        s += h2f(in_h[a]) + h2f(in_l[a]);
      }
    const float vv = 0.0625f * s;
    const unsigned short hi = f2h(vv);
    const int nout = yo * 16 + xo;
    const size_t ob = ((size_t)b * 256 + nout) * CC + swzoff(nout, c);
    h4[ob] = hi;
    l4[ob] = f2h(vv - h2f(hi));
    v4[(((size_t)b * 4 + (nout >> 6)) * CC + c) * 64 + swzvslot(nout & 63, c)] =
        f2bf(vv);
  }
}

// ---------------------------------------------------------------------------
// MFMA flash attention <NH, KS> (round-15 structure; round-16: f2bf_fast in
// the P-write + partial-O epilogue — VALU was the longer pipe at 35% vs
// MFMA 29%, and library __float2bfloat16 is ~6-8 ops vs 2 for add+shift).
// ---------------------------------------------------------------------------
#define STR 72   // P-tile LDS row stride (shorts); 144B keeps b128 aligned

template <int NH, int KS>
__device__ __forceinline__ void attn_body(
    int bid,
    const unsigned short* __restrict__ fh,
    const unsigned short* __restrict__ fl,
    const unsigned short* __restrict__ fv,
    float* __restrict__ outF, unsigned short* __restrict__ outB,
    float* __restrict__ outL, int N,
    unsigned short* KVT, unsigned short* PtB) {
  const int tid  = threadIdx.x;
  const int lane = tid & 63;
  const int wave = tid >> 6;
  const int b    = bid & 7;              // XCD-local batch grouping
  const int rest = bid >> 3;
  const int nq   = N / (64 * NH);
  const int qt   = rest % nq;
  const int ks   = rest / nq;            // 0..KS-1
  const int q0   = qt * (64 * NH) + wave * (16 * NH);
  const int nt   = (N >> 6) / KS;
  const int t0   = ks * nt;
  const int r16  = lane & 15;
  const int quad = lane >> 4;
  const int swb  = r16 & 7;

  const unsigned short* fhB = fh + (size_t)b * N * CC;   // fp16 K/Q hi
  const unsigned short* flB = fl + (size_t)b * N * CC;   // fp16 Q lo
  const unsigned short* fvB = fv + (size_t)b * N * CC;   // bf16 tile-major V^T

  // ---- stage first tile via DMA: 16 chunks of 512 shorts; wave takes 4 ----
  {
    const size_t tb = (size_t)t0 * 4096;
#pragma unroll
    for (int j = 0; j < 4; ++j) {
      const int cid = wave * 4 + j;
      const int arr = cid >> 3, sub = (cid & 7) << 9;
      const unsigned short* g = (arr == 0 ? fhB : fvB) + tb + sub + lane * 8;
      GLD_LDS16(g, KVT + arr * 4096 + sub + lane * 8);
    }
  }

  // ---- Q fragments per half: f = h+l, g = f*log2e, fp16 re-split, M ----
  half8 Qh[NH][2], Ql[NH][2];
  float Mq[NH][4];
#pragma unroll
  for (int h = 0; h < NH; ++h) {
    float Mpart = 0.f;
#pragma unroll
    for (int kss = 0; kss < 2; ++kss) {
      const size_t off = (size_t)(q0 + h * 16 + r16) * CC
                         + ((((kss << 2) + quad) ^ swb) << 3);
      const ushort8 hh = *(const ushort8*)(fhB + off);
      const ushort8 ll = *(const ushort8*)(flB + off);
      half8 sh, sl;
#pragma unroll
      for (int j = 0; j < 8; ++j) {
        const float f = h2f(hh[j]) + h2f(ll[j]);
        const float g = f * LOG2E;
        const _Float16 gh = (_Float16)g;
        sh[j] = gh;
        sl[j] = (_Float16)(g - (float)gh);
        Mpart += g * f;                  // = log2e * sum f^2 (partial)
      }
      Qh[h][kss] = sh;
      Ql[h][kss] = sl;
    }
    Mpart += __shfl_xor(Mpart, 16, 64);
    Mpart += __shfl_xor(Mpart, 32, 64);  // per-row |q|^2*log2e at lane r16
#pragma unroll
    for (int r = 0; r < 4; ++r) Mq[h][r] = __shfl(Mpart, quad * 4 + r, 64);
  }

  floatx4 O[NH][4];
  float lrun[NH][4];
#pragma unroll
  for (int h = 0; h < NH; ++h)
#pragma unroll
    for (int ch = 0; ch < 4; ++ch) {
      O[h][ch] = (floatx4){0.f, 0.f, 0.f, 0.f};
      lrun[h][ch] = 0.f;
    }
  unsigned short* ptw = PtB + wave * (NH * 16 * STR);

  int koff[2];
#pragma unroll
  for (int kss = 0; kss < 2; ++kss) koff[kss] = (((kss << 2) + quad) ^ swb) << 3;

  for (int t = 0; t < nt; ++t) {
    const int cur = t & 1;
    __syncthreads();                    // drains DMA for tile t, syncs block
    if (t + 1 < nt) {                   // issue DMA for tile t+1 now
      const size_t tb = (size_t)(t0 + t + 1) * 4096;
      unsigned short* dst = KVT + (cur ^ 1) * 8192;
#pragma unroll
      for (int j = 0; j < 4; ++j) {
        const int cid = wave * 4 + j;
        const int arr = cid >> 3, sub = (cid & 7) << 9;
        const unsigned short* g = (arr == 0 ? fhB : fvB) + tb + sub + lane * 8;
        GLD_LDS16(g, dst + arr * 4096 + sub + lane * 8);
      }
    }
    const unsigned short* kh = KVT + cur * 8192;   // fp16 K hi
    const unsigned short* vt = kh + 4096;          // bf16 V^T

    // ---- S-tiles (4 f16 MFMA) with FUSED per-tt softmax ----
#pragma unroll
    for (int tt = 0; tt < 4; ++tt) {
      const int kbase = (tt * 16 + r16) * 64;
      const half8 Kh0 = *(const half8*)(kh + kbase + koff[0]);
      const half8 Kh1 = *(const half8*)(kh + kbase + koff[1]);
#pragma unroll
      for (int h = 0; h < NH; ++h) {
        floatx4 s = (floatx4){0.f, 0.f, 0.f, 0.f};
        s = __builtin_amdgcn_mfma_f32_16x16x32_f16(Qh[h][0], Kh0, s, 0, 0, 0);
        s = __builtin_amdgcn_mfma_f32_16x16x32_f16(Qh[h][1], Kh1, s, 0, 0, 0);
        s = __builtin_amdgcn_mfma_f32_16x16x32_f16(Ql[h][0], Kh0, s, 0, 0, 0);
        s = __builtin_amdgcn_mfma_f32_16x16x32_f16(Ql[h][1], Kh1, s, 0, 0, 0);
        unsigned short* pth = ptw + h * (16 * STR);
#pragma unroll
        for (int r = 0; r < 4; ++r) {
          const float p = __builtin_amdgcn_exp2f(s[r] - Mq[h][r]);
          lrun[h][r] += p;
          pth[(quad * 4 + r) * STR + tt * 16 + r16] = f2bf_fast(p);
        }
      }
    }

    // ---- P reads (bf16 A-layout) + O += P*V (bf16) ----
    bf16x8 Pf[NH][2];
#pragma unroll
    for (int h = 0; h < NH; ++h)
#pragma unroll
      for (int kss = 0; kss < 2; ++kss)
        Pf[h][kss] = *(const bf16x8*)(ptw + h * (16 * STR) + r16 * STR
                                      + kss * 32 + quad * 8);
#pragma unroll
    for (int kss = 0; kss < 2; ++kss)
#pragma unroll
      for (int ch = 0; ch < 4; ++ch) {
        const bf16x8 Vf = *(const bf16x8*)(vt + (ch * 16 + r16) * 64 + koff[kss]);
#pragma unroll
        for (int h = 0; h < NH; ++h)
          O[h][ch] = __builtin_amdgcn_mfma_f32_16x16x32_bf16(Pf[h][kss], Vf,
                                                            O[h][ch], 0, 0, 0);
      }
  }

  // ---- epilogue ----
#pragma unroll
  for (int h = 0; h < NH; ++h) {
#pragma unroll
    for (int r = 0; r < 4; ++r) {
      float lt = lrun[h][r];
      lt += __shfl_xor(lt, 1, 16);
      lt += __shfl_xor(lt, 2, 16);
      lt += __shfl_xor(lt, 4, 16);
      lt += __shfl_xor(lt, 8, 16);
      if (KS == 1) {
        lrun[h][r] = 1.f / lt;
      } else if (r16 == 0) {
        outL[(size_t)ks * BB * N + (size_t)b * N + q0 + h * 16 + quad * 4 + r] = lt;
      }
    }
#pragma unroll
    for (int ch = 0; ch < 4; ++ch)
#pragma unroll
      for (int r = 0; r < 4; ++r) {
        const size_t qi = (size_t)b * N + q0 + h * 16 + quad * 4 + r;
        if (KS == 1) {
          outF[qi * CC + ch * 16 + r16] = O[h][ch][r] * lrun[h][r];
        } else {
          outB[(size_t)ks * BB * N * CC + qi * CC + ch * 16 + r16] =
              f2bf_fast(O[h][ch][r]);
        }
      }
  }
}

// Merged dispatch: [0,512) scale-1 NH=2/KS=2; [512,768) scale-2 NH=1/KS=2;
// [768,800) scale-4 NH=1/KS=1. LDS 50.4KB -> 3 blocks/CU.
__global__ __launch_bounds__(256, 3) void attn_all(
    const unsigned short* __restrict__ fh1, const unsigned short* __restrict__ fl1,
    const unsigned short* __restrict__ fv1,
    unsigned short* __restrict__ Op1, float* __restrict__ Lp1,
    const unsigned short* __restrict__ fh2, const unsigned short* __restrict__ fl2,
    const unsigned short* __restrict__ fv2,
    unsigned short* __restrict__ Op2, float* __restrict__ Lp2,
    const unsigned short* __restrict__ fh4, const unsigned short* __restrict__ fl4,
    const unsigned short* __restrict__ fv4, float* __restrict__ a4) {
  __shared__ __align__(16) unsigned short KVT[2][2 * 4096];
  __shared__ __align__(16) unsigned short Pt[4][2 * 16 * STR];
  const int bid = blockIdx.x;
  if (bid < 512) {
    attn_body<2, 2>(bid, fh1, fl1, fv1, nullptr, Op1, Lp1, NPIX,
                    &KVT[0][0], &Pt[0][0]);
  } else if (bid < 768) {
    attn_body<1, 2>(bid - 512, fh2, fl2, fv2, nullptr, Op2, Lp2, 1024,
                    &KVT[0][0], &Pt[0][0]);
  } else {
    attn_body<1, 1>(bid - 768, fh4, fl4, fv4, a4, nullptr, nullptr, 256,
                    &KVT[0][0], &Pt[0][0]);
  }
}

// ---------------------------------------------------------------------------
// final3: FUSED scale-1 combine + scale-2 combine + output assembly.
// Block = (b, y-row).
//   Phase 1 : combine 2 bf16 scale-1 O-partials of row y (coalesced along c),
//             normalize, LDS-transpose -> T[c][x].
//   Phase 1b: combine the TWO scale-2 source rows (iy20, iy21) this y needs
//             from Op2/Lp2 (coalesced), normalize -> T2[c][row*32+ix].
//             (~2x recompute of a tiny array; kills the combine launch +
//             a2c round-trip — round-16 launch-count cut.)
//   Phase 2 : out = x + T + bilinear(T2) + up4(a4), coalesced NCHW writes.
// ---------------------------------------------------------------------------
__global__ __launch_bounds__(256) void final3_kernel(
    const float* __restrict__ xin,
    const unsigned short* __restrict__ Op1, const float* __restrict__ Lp1,
    const unsigned short* __restrict__ Op2, const float* __restrict__ Lp2,
    const float* __restrict__ a4, float* __restrict__ out) {
  __shared__ float T[64][65];
  __shared__ float T2[64][66];
  const int tid = threadIdx.x;
  const int y = blockIdx.x & 63;
  const int b = blockIdx.x >> 6;
  const size_t S1 = (size_t)BB * NPIX * CC;
  const size_t T1 = (size_t)BB * NPIX;
  const size_t S2 = (size_t)BB * 1024 * CC;
  const size_t L2 = (size_t)BB * 1024;

  // scale-2 y params (uniform)
  const float ty2 = y * 0.5f - 0.25f;
  const int iy2 = (int)floorf(ty2);
  const float wy2 = ty2 - iy2;
  const int iy20 = max(iy2, 0), iy21 = min(iy2 + 1, 31);

  const int nl = tid >> 2;             // 0..63
  const int ck = (tid & 3) * 16;       // c chunk

  {  // ---- phase 1: combine scale-1 row y ----
    const int n = y * 64 + nl;
    float lv = Lp1[(size_t)b * NPIX + n] + Lp1[T1 + (size_t)b * NPIX + n];
    const float inv = 1.f / lv;
    float v[16];
#pragma unroll
    for (int j = 0; j < 16; ++j) v[j] = 0.f;
#pragma unroll
    for (int ks = 0; ks < 2; ++ks) {
      const unsigned short* src =
          Op1 + (size_t)ks * S1 + ((size_t)b * NPIX + n) * CC + ck;
      const ushort8 u0 = *(const ushort8*)(src);
      const ushort8 u1 = *(const ushort8*)(src + 8);
#pragma unroll
      for (int j = 0; j < 8; ++j) {
        v[j]     += bf2f(u0[j]);
        v[8 + j] += bf2f(u1[j]);
      }
    }
#pragma unroll
    for (int j = 0; j < 16; ++j) T[ck + j][nl] = v[j] * inv;
  }
  {  // ---- phase 1b: combine scale-2 rows iy20 (nl<32) / iy21 (nl>=32) ----
    const int row = nl >> 5;           // 0 or 1
    const int ix  = nl & 31;
    const int n2  = (row == 0 ? iy20 : iy21) * 32 + ix;
    float lv = Lp2[(size_t)b * 1024 + n2] + Lp2[L2 + (size_t)b * 1024 + n2];
    const float inv = 1.f / lv;
    float v[16];
#pragma unroll
    for (int j = 0; j < 16; ++j) v[j] = 0.f;
#pragma unroll
    for (int ks = 0; ks < 2; ++ks) {
      const unsigned short* src =
          Op2 + (size_t)ks * S2 + ((size_t)b * 1024 + n2) * CC + ck;
      const ushort8 u0 = *(const ushort8*)(src);
      const ushort8 u1 = *(const ushort8*)(src + 8);
#pragma unroll
      for (int j = 0; j < 8; ++j) {
        v[j]     += bf2f(u0[j]);
        v[8 + j] += bf2f(u1[j]);
      }
    }
#pragma unroll
    for (int j = 0; j < 16; ++j) T2[ck + j][nl] = v[j] * inv;
  }
  __syncthreads();

  // ---- phase 2: assemble output row ----
  const int c  = tid >> 2;
  const int xk = (tid & 3) * 16;
  const float* xrow = xin + (((size_t)b * CC + c) * HH + y) * WW;
  float* orow = out + (((size_t)b * CC + c) * HH + y) * WW;

  const float ty4 = y * 0.25f - 0.375f;
  const int iy4 = (int)floorf(ty4);
  const float wy4 = ty4 - iy4;
  const int iy40 = max(iy4, 0), iy41 = min(iy4 + 1, 15);
  const float* b4 = a4 + (size_t)b * 256 * 64 + c;

#pragma unroll
  for (int j = 0; j < 16; ++j) {
    const int xx = xk + j;
    float r = xrow[xx] + T[c][xx];
    {  // scale 2 (rows pre-combined in T2: cols 0-31 = iy20, 32-63 = iy21)
      const float tx = xx * 0.5f - 0.25f;
      const int ix = (int)floorf(tx);
      const float wx = tx - ix;
      const int ix0 = max(ix, 0), ix1 = min(ix + 1, 31);
      const float v00 = T2[c][ix0],      v01 = T2[c][ix1];
      const float v10 = T2[c][32 + ix0], v11 = T2[c][32 + ix1];
      r += (1.f-wy2)*((1.f-wx)*v00 + wx*v01) + wy2*((1.f-wx)*v10 + wx*v11);
    }
    {  // scale 4
      const float tx = xx * 0.25f - 0.375f;
      const int ix = (int)floorf(tx);
      const float wx = tx - ix;
      const int ix0 = max(ix, 0), ix1 = min(ix + 1, 15);
      const float v00 = b4[(iy40*16+ix0)*64], v01 = b4[(iy40*16+ix1)*64];
      const float v10 = b4[(iy41*16+ix0)*64], v11 = b4[(iy41*16+ix1)*64];
      r += (1.f-wy4)*((1.f-wx)*v00 + wx*v01) + wy4*((1.f-wx)*v10 + wx*v11);
    }
    orow[xx] = r;
  }
}

// ---------------------------------------------------------------------------
extern "C" void kernel_launch(void* const* d_in, const int* in_sizes, int n_in,
                              void* d_out, int out_size, void* d_ws,
                              size_t ws_size, hipStream_t stream) {
  const float* x = (const float*)d_in[0];
  const float* w = (const float*)d_in[1];
  float* out = (float*)d_out;

  unsigned short* fh1 = (unsigned short*)d_ws;            // [8][4096][64] fp16 swz
  unsigned short* fl1 = fh1 + (size_t)BB*NPIX*CC;         // fp16 lo
  unsigned short* fv1 = fl1 + (size_t)BB*NPIX*CC;         // bf16 tile-major V^T
  unsigned short* fh2 = fv1 + (size_t)BB*NPIX*CC;         // [8][1024][64]
  unsigned short* fl2 = fh2 + (size_t)BB*1024*CC;
  unsigned short* fv2 = fl2 + (size_t)BB*1024*CC;
  unsigned short* fh4 = fv2 + (size_t)BB*1024*CC;         // [8][256][64]
  unsigned short* fl4 = fh4 + (size_t)BB*256*CC;
  unsigned short* fv4 = fl4 + (size_t)BB*256*CC;
  unsigned short* Op1 = fv4 + (size_t)BB*256*CC;          // [2][8][4096][64] bf16
  float* Lp1 = (float*)(Op1 + 2*(size_t)BB*NPIX*CC);      // [2][8][4096]
  unsigned short* Op2 = (unsigned short*)(Lp1 + 2*(size_t)BB*NPIX);  // [2][8][1024][64]
  float* Lp2 = (float*)(Op2 + 2*(size_t)BB*1024*CC);      // [2][8][1024]
  float* a4  = Lp2 + 2*(size_t)BB*1024;                   // [8][256][64] fp32

  // Dead-time aliases (zero workspace growth):
  //   XT/WT (dead after conv_mfma) alias Op1/Op2 (written by attn later)
  unsigned short* xth = (unsigned short*)Op1;             // 4.19 MB
  unsigned short* xtl = xth + (size_t)BB*NPIX*CC;         // 4.19 MB (= Op1 end)
  unsigned short* wth = (unsigned short*)Op2;             // 72 KB
  unsigned short* wtl = wth + 9*64*64;                    // 72 KB

  prep_kernel<<<656, 256, 0, stream>>>(x, w, xth, xtl, wth, wtl);
  conv_mfma<<<dim3(64, 8), 256, 0, stream>>>(xth, xtl, wth, wtl, fh1, fl1, fv1);
  pools_kernel<<<2560, 256, 0, stream>>>(fh1, fl1, fh2, fl2, fv2, fh4, fl4, fv4);
  attn_all<<<800, 256, 0, stream>>>(fh1, fl1, fv1, Op1, Lp1,
                                    fh2, fl2, fv2, Op2, Lp2,
                                    fh4, fl4, fv4, a4);
  final3_kernel<<<512, 256, 0, stream>>>(x, Op1, Lp1, Op2, Lp2, a4, out);
}

// Round 17
// 156.093 us; speedup vs baseline: 1.5318x; 1.0615x over previous
//
#include <hip/hip_runtime.h>
#include <hip/hip_bf16.h>
#include <math.h>

// Problem constants: x [8,64,64,64] fp32 NCHW, W_std [64,64,3,3] fp32 OIHW.
#define BB 8
#define CC 64
#define HH 64
#define WW 64
#define NPIX (HH*WW)   // 4096
#define LOG2E 1.44269504088896340736f

typedef __attribute__((ext_vector_type(8))) short bf16x8;            // bf16 A/B frag
typedef __attribute__((ext_vector_type(8))) _Float16 half8;          // fp16 A/B frag (K=32)
typedef __attribute__((ext_vector_type(4))) _Float16 half4;          // fp16 A/B frag (K=16)
typedef __attribute__((ext_vector_type(4))) float floatx4;           // MFMA C/D frag
typedef __attribute__((ext_vector_type(8))) unsigned short ushort8;  // 16B unit

__device__ inline unsigned short f2bf(float x) {
  __hip_bfloat16 h = __float2bfloat16(x);
  return *reinterpret_cast<unsigned short*>(&h);
}
__device__ inline unsigned short f2bf_fast(float x) {
  const unsigned u = __float_as_uint(x);
  return (unsigned short)((u + 0x8000u) >> 16);
}
__device__ inline float bf2f(unsigned short u) {
  __hip_bfloat16 h = *reinterpret_cast<__hip_bfloat16*>(&u);
  return __bfloat162float(h);
}
__device__ inline unsigned short f2h(float x) {
  _Float16 h = (_Float16)x;
  return *reinterpret_cast<unsigned short*>(&h);
}
__device__ inline float h2f(unsigned short u) {
  _Float16 h = *reinterpret_cast<_Float16*>(&u);
  return (float)h;
}

// XOR swizzle: 16B channel-chunks permuted within each 128B row so MFMA
// fragment reads from LDS (lane stride 128B) spread across all 32 banks.
__device__ inline int swzoff(int n, int c) {
  return (((c >> 3) ^ (n & 7)) << 3) | (c & 7);
}
__device__ inline int swzvslot(int key, int c) {
  return (((key >> 3) ^ (c & 7)) << 3) | (key & 7);
}

// 16B global -> LDS DMA
#define GLD_LDS16(gp, lp)                                                     \
  __builtin_amdgcn_global_load_lds(                                           \
      (const __attribute__((address_space(1))) void*)(gp),                    \
      (__attribute__((address_space(3))) void*)(lp), 16, 0, 0)

// ---------------------------------------------------------------------------
// prep: merged xt (512 blocks) + wprep (144 blocks). XT/WT stay bf16 hi/lo.
// ---------------------------------------------------------------------------
__global__ __launch_bounds__(256) void prep_kernel(
    const float* __restrict__ xin, const float* __restrict__ w,
    unsigned short* __restrict__ xth, unsigned short* __restrict__ xtl,
    unsigned short* __restrict__ wth, unsigned short* __restrict__ wtl) {
  __shared__ float XL[64][65];
  const int bid = blockIdx.x;
  const int tid = threadIdx.x;
  if (bid < 512) {            // ---- xt ----
    const int y = bid & 63, b = bid >> 6;
    const int xq = tid & 15, cw = tid >> 4;
    const float* xb = xin + (size_t)b * CC * NPIX + y * WW;
#pragma unroll
    for (int p = 0; p < 4; ++p) {
      const int c = p * 16 + cw;
      const float4 v = *(const float4*)(xb + (size_t)c * NPIX + xq * 4);
      XL[c][xq * 4 + 0] = v.x; XL[c][xq * 4 + 1] = v.y;
      XL[c][xq * 4 + 2] = v.z; XL[c][xq * 4 + 3] = v.w;
    }
    __syncthreads();
    const int px = tid & 63, cp = tid >> 6;
    const size_t nb = ((size_t)b * NPIX + y * WW + px) * CC;
    ushort8 vh[2], vl[2];
#pragma unroll
    for (int j = 0; j < 16; ++j) {
      const float v = XL[cp * 16 + j][px];
      const unsigned short hh = f2bf(v);
      vh[j >> 3][j & 7] = hh;
      vl[j >> 3][j & 7] = f2bf(v - bf2f(hh));
    }
#pragma unroll
    for (int k = 0; k < 2; ++k) {
      const int ch = cp * 2 + k;
      const int off = ((ch ^ (px & 7)) << 3);
      *(ushort8*)(xth + nb + off) = vh[k];
      *(ushort8*)(xtl + nb + off) = vl[k];
    }
  } else {                    // ---- wprep: Laplacian folded into weights ----
    const int idx = (bid - 512) * 256 + tid;    // 9*64*64 = 36864
    const int c   = idx & 63;
    const int o   = (idx >> 6) & 63;
    const int tap = idx >> 12;
    float v = w[((o * 64 + c) * 9) + tap];
    if (o == c) {
      const float lapk[9] = {0.f, 1.f, 0.f, 1.f, -4.f, 1.f, 0.f, 1.f, 0.f};
      v += lapk[tap];
    }
    const unsigned short hi = f2bf(v);
    wth[(tap * 64 + o) * 64 + c] = hi;
    wtl[(tap * 64 + o) * 64 + c] = f2bf(v - bf2f(hi));
  }
}

// ---------------------------------------------------------------------------
// conv_mfma: implicit-GEMM conv (bf16 internals). Epilogue emits feat as
// FP16 hi/lo (fh/fl) + FP16 V^T (fv — round 17: V now fp16 for the 16x16x16
// f16 PV MFMA; more mantissa than bf16).
// ---------------------------------------------------------------------------
__global__ __launch_bounds__(256, 2) void conv_mfma(
    const unsigned short* __restrict__ xth,
    const unsigned short* __restrict__ xtl,
    const unsigned short* __restrict__ wth,
    const unsigned short* __restrict__ wtl,
    unsigned short* __restrict__ fh, unsigned short* __restrict__ fl,
    unsigned short* __restrict__ fv) {
  __shared__ __align__(16) unsigned short XS[6 * 4096];

  const int tid  = threadIdx.x;
  const int lane = tid & 63;
  const int wave = tid >> 6;
  const int r16  = lane & 15;
  const int quad = lane >> 4;
  const int y = blockIdx.x, b = blockIdx.y;

#pragma unroll
  for (int r = 0; r < 3; ++r) {
    const int yy = min(max(y - 1 + r, 0), HH - 1);
    const unsigned short* sh = xth + ((size_t)b * NPIX + yy * WW) * CC;
    const unsigned short* sl = xtl + ((size_t)b * NPIX + yy * WW) * CC;
    GLD_LDS16(sh + tid * 8,        &XS[r * 4096 + tid * 8]);
    GLD_LDS16(sh + 2048 + tid * 8, &XS[r * 4096 + 2048 + tid * 8]);
    GLD_LDS16(sl + tid * 8,        &XS[(3 + r) * 4096 + tid * 8]);
    GLD_LDS16(sl + 2048 + tid * 8, &XS[(3 + r) * 4096 + 2048 + tid * 8]);
  }
  __syncthreads();

  floatx4 acc[4];
#pragma unroll
  for (int t = 0; t < 4; ++t) acc[t] = (floatx4){0.f, 0.f, 0.f, 0.f};
  const bf16x8 ZF = {0, 0, 0, 0, 0, 0, 0, 0};
  const int og = wave * 16 + r16;

#pragma unroll
  for (int tap = 0; tap < 9; ++tap) {
    const int ky = tap / 3, kx = tap % 3;
    const int yy = y + ky - 1;
    if (yy < 0 || yy >= HH) continue;
    const unsigned short* wt = wth + ((tap * 64 + og) << 6);
    const unsigned short* wl = wtl + ((tap * 64 + og) << 6);
    const bf16x8 Wh0 = *(const bf16x8*)(wt + quad * 8);
    const bf16x8 Wh1 = *(const bf16x8*)(wt + 32 + quad * 8);
    const bf16x8 Wl0 = *(const bf16x8*)(wl + quad * 8);
    const bf16x8 Wl1 = *(const bf16x8*)(wl + 32 + quad * 8);
#pragma unroll
    for (int t = 0; t < 4; ++t) {
      const int px = t * 16 + r16 + kx - 1;
      const bool ok = (px >= 0) && (px < WW);
      const int pxc = ok ? px : 0;
      const int bh = ky * 4096 + pxc * 64;
      const int bl = bh + 3 * 4096;
      const int o0 = ((quad ^ (pxc & 7)) << 3);
      const int o1 = (((4 + quad) ^ (pxc & 7)) << 3);
      bf16x8 Ah0 = *(const bf16x8*)(XS + bh + o0);
      bf16x8 Ah1 = *(const bf16x8*)(XS + bh + o1);
      bf16x8 Al0 = *(const bf16x8*)(XS + bl + o0);
      bf16x8 Al1 = *(const bf16x8*)(XS + bl + o1);
      if (!ok) { Ah0 = ZF; Ah1 = ZF; Al0 = ZF; Al1 = ZF; }
      acc[t] = __builtin_amdgcn_mfma_f32_16x16x32_bf16(Ah0, Wh0, acc[t], 0, 0, 0);
      acc[t] = __builtin_amdgcn_mfma_f32_16x16x32_bf16(Ah1, Wh1, acc[t], 0, 0, 0);
      acc[t] = __builtin_amdgcn_mfma_f32_16x16x32_bf16(Ah0, Wl0, acc[t], 0, 0, 0);
      acc[t] = __builtin_amdgcn_mfma_f32_16x16x32_bf16(Ah1, Wl1, acc[t], 0, 0, 0);
      acc[t] = __builtin_amdgcn_mfma_f32_16x16x32_bf16(Al0, Wh0, acc[t], 0, 0, 0);
      acc[t] = __builtin_amdgcn_mfma_f32_16x16x32_bf16(Al1, Wh1, acc[t], 0, 0, 0);
    }
  }

#pragma unroll
  for (int t = 0; t < 4; ++t)
#pragma unroll
    for (int r = 0; r < 4; ++r) {
      const int key = t * 16 + quad * 4 + r;
      const int n = y * WW + key;
      const float v = acc[t][r];
      const unsigned short hi = f2h(v);               // fp16 hi
      const unsigned short lo = f2h(v - h2f(hi));     // fp16 lo
      fh[((size_t)b * NPIX + n) * CC + swzoff(n, og)] = hi;
      fl[((size_t)b * NPIX + n) * CC + swzoff(n, og)] = lo;
      fv[(((size_t)b * (NPIX >> 6) + y) * CC + og) * 64 + swzvslot(key, og)] =
          f2h(v);                                     // V^T fp16
    }
}

// ---------------------------------------------------------------------------
// pools: merged pool2 + pool4-direct. Reads fp16 hi/lo, writes fp16 hi/lo
// (fh/fl) + fp16 (fv).
// ---------------------------------------------------------------------------
__global__ void pools_kernel(const unsigned short* __restrict__ in_h,
                             const unsigned short* __restrict__ in_l,
                             unsigned short* __restrict__ h2,
                             unsigned short* __restrict__ l2,
                             unsigned short* __restrict__ v2,
                             unsigned short* __restrict__ h4,
                             unsigned short* __restrict__ l4,
                             unsigned short* __restrict__ v4) {
  const int bid = blockIdx.x;
  if (bid < 2048) {           // ---- pool2: 64x64 -> 32x32 ----
    const int idx = bid * 256 + threadIdx.x;
    const int c  = idx & 63;
    const int t  = idx >> 6;
    const int xo = t & 31;
    const int yo = (t >> 5) & 31;
    const int b  = t >> 10;
    const size_t ibase = (size_t)b * NPIX * CC;
    float s = 0.f;
#pragma unroll
    for (int dy = 0; dy < 2; ++dy)
#pragma unroll
      for (int dx = 0; dx < 2; ++dx) {
        const int nin = (2*yo+dy) * 64 + (2*xo+dx);
        const size_t a = ibase + (size_t)nin * CC + swzoff(nin, c);
        s += h2f(in_h[a]) + h2f(in_l[a]);
      }
    const float vv = 0.25f * s;
    const unsigned short hi = f2h(vv);
    const int nout = yo * 32 + xo;
    const size_t ob = ((size_t)b * 1024 + nout) * CC + swzoff(nout, c);
    h2[ob] = hi;
    l2[ob] = f2h(vv - h2f(hi));
    v2[(((size_t)b * 16 + (nout >> 6)) * CC + c) * 64 + swzvslot(nout & 63, c)] =
        f2h(vv);
  } else {                    // ---- pool4: 64x64 -> 16x16 (direct) ----
    const int idx = (bid - 2048) * 256 + threadIdx.x;
    const int c  = idx & 63;
    const int t  = idx >> 6;
    const int xo = t & 15;
    const int yo = (t >> 4) & 15;
    const int b  = t >> 8;
    const size_t ibase = (size_t)b * NPIX * CC;
    float s = 0.f;
#pragma unroll
    for (int dy = 0; dy < 4; ++dy)
#pragma unroll
      for (int dx = 0; dx < 4; ++dx) {
        const int nin = (4*yo+dy) * 64 + (4*xo+dx);
        const size_t a = ibase + (size_t)nin * CC + swzoff(nin, c);
        s += h2f(in_h[a]) + h2f(in_l[a]);
      }
    const float vv = 0.0625f * s;
    const unsigned short hi = f2h(vv);
    const int nout = yo * 16 + xo;
    const size_t ob = ((size_t)b * 256 + nout) * CC + swzoff(nout, c);
    h4[ob] = hi;
    l4[ob] = f2h(vv - h2f(hi));
    v4[(((size_t)b * 4 + (nout >> 6)) * CC + c) * 64 + swzvslot(nout & 63, c)] =
        f2h(vv);
  }
}

// ---------------------------------------------------------------------------
// MFMA flash attention <NH, KS> — round-17 S-TRANSPOSE restructure:
//   S^T = MFMA(A=K, B=Q): same K LDS reads and Q registers, roles swapped
//   (A/B layouts are mirror images). Lane then holds P^T in D-layout
//   (key=quad*4+r, q=r16) — which IS the A-frag layout of a 16x16x16 MFMA
//   (A[m=r16][k=quad*4+j]). So P goes exp2 -> half4 register -> PV MFMA
//   directly: NO LDS P round-trip (round-16 counters: 32 ds_write_b16 +
//   8 b128 reads/tile + 1.12M bank conflicts — that was the bottleneck).
//   Pt eliminated -> LDS 32KB -> 4 blocks/CU. Mq and l are now per-lane
//   scalars (q=r16): no broadcast shuffles. O's D-layout is unchanged
//   (row=q=quad*4+r, col=c=ch*16+r16) so the epilogue/consumers are
//   untouched except l comes via one width-16 shfl.
// ---------------------------------------------------------------------------
template <int NH, int KS>
__device__ __forceinline__ void attn_body(
    int bid,
    const unsigned short* __restrict__ fh,
    const unsigned short* __restrict__ fl,
    const unsigned short* __restrict__ fv,
    float* __restrict__ outF, unsigned short* __restrict__ outB,
    float* __restrict__ outL, int N,
    unsigned short* KVT) {
  const int tid  = threadIdx.x;
  const int lane = tid & 63;
  const int wave = tid >> 6;
  const int b    = bid & 7;              // XCD-local batch grouping
  const int rest = bid >> 3;
  const int nq   = N / (64 * NH);
  const int qt   = rest % nq;
  const int ks   = rest / nq;            // 0..KS-1
  const int q0   = qt * (64 * NH) + wave * (16 * NH);
  const int nt   = (N >> 6) / KS;
  const int t0   = ks * nt;
  const int r16  = lane & 15;
  const int quad = lane >> 4;
  const int swb  = r16 & 7;

  const unsigned short* fhB = fh + (size_t)b * N * CC;   // fp16 K/Q hi
  const unsigned short* flB = fl + (size_t)b * N * CC;   // fp16 Q lo
  const unsigned short* fvB = fv + (size_t)b * N * CC;   // fp16 tile-major V^T

  // ---- stage first tile via DMA: 16 chunks of 512 shorts; wave takes 4 ----
  {
    const size_t tb = (size_t)t0 * 4096;
#pragma unroll
    for (int j = 0; j < 4; ++j) {
      const int cid = wave * 4 + j;
      const int arr = cid >> 3, sub = (cid & 7) << 9;
      const unsigned short* g = (arr == 0 ? fhB : fvB) + tb + sub + lane * 8;
      GLD_LDS16(g, KVT + arr * 4096 + sub + lane * 8);
    }
  }

  // ---- Q fragments per half: f = h+l, g = f*log2e, fp16 re-split, M ----
  half8 Qh[NH][2], Ql[NH][2];
  float Mq[NH];
#pragma unroll
  for (int h = 0; h < NH; ++h) {
    float Mpart = 0.f;
#pragma unroll
    for (int kss = 0; kss < 2; ++kss) {
      const size_t off = (size_t)(q0 + h * 16 + r16) * CC
                         + ((((kss << 2) + quad) ^ swb) << 3);
      const ushort8 hh = *(const ushort8*)(fhB + off);
      const ushort8 ll = *(const ushort8*)(flB + off);
      half8 sh, sl;
#pragma unroll
      for (int j = 0; j < 8; ++j) {
        const float f = h2f(hh[j]) + h2f(ll[j]);
        const float g = f * LOG2E;
        const _Float16 gh = (_Float16)g;
        sh[j] = gh;
        sl[j] = (_Float16)(g - (float)gh);
        Mpart += g * f;                  // = log2e * sum f^2 (partial)
      }
      Qh[h][kss] = sh;
      Ql[h][kss] = sl;
    }
    Mpart += __shfl_xor(Mpart, 16, 64);
    Mpart += __shfl_xor(Mpart, 32, 64);  // M for q = r16, replicated
    Mq[h] = Mpart;                       // per-lane SCALAR (q = r16)
  }

  floatx4 O[NH][4];
  float lloc[NH];
#pragma unroll
  for (int h = 0; h < NH; ++h) {
    lloc[h] = 0.f;
#pragma unroll
    for (int ch = 0; ch < 4; ++ch) O[h][ch] = (floatx4){0.f, 0.f, 0.f, 0.f};
  }

  int koff[2];
#pragma unroll
  for (int kss = 0; kss < 2; ++kss) koff[kss] = (((kss << 2) + quad) ^ swb) << 3;
  // V b64 fragment slot within a 64-short row, per tt (keys quad*4..+3):
  //   key = tt*16 + quad*4 + j -> slot = (((tt*2+(quad>>1))^swb)<<3)+((quad&1)<<2)
  const int vq = ((quad & 1) << 2);

  for (int t = 0; t < nt; ++t) {
    const int cur = t & 1;
    __syncthreads();                    // drains DMA for tile t, syncs block
    if (t + 1 < nt) {                   // issue DMA for tile t+1 now
      const size_t tb = (size_t)(t0 + t + 1) * 4096;
      unsigned short* dst = KVT + (cur ^ 1) * 8192;
#pragma unroll
      for (int j = 0; j < 4; ++j) {
        const int cid = wave * 4 + j;
        const int arr = cid >> 3, sub = (cid & 7) << 9;
        const unsigned short* g = (arr == 0 ? fhB : fvB) + tb + sub + lane * 8;
        GLD_LDS16(g, dst + arr * 4096 + sub + lane * 8);
      }
    }
    const unsigned short* kh = KVT + cur * 8192;   // fp16 K hi
    const unsigned short* vt = kh + 4096;          // fp16 V^T

#pragma unroll
    for (int tt = 0; tt < 4; ++tt) {
      const int kbase = (tt * 16 + r16) * 64;
      const half8 Kh0 = *(const half8*)(kh + kbase + koff[0]);
      const half8 Kh1 = *(const half8*)(kh + kbase + koff[1]);
      // V fragments for this tt (shared across halves): 4 x b64
      const int vslot = (((tt * 2 + (quad >> 1)) ^ swb) << 3) + vq;
      half4 Vf[4];
#pragma unroll
      for (int ch = 0; ch < 4; ++ch)
        Vf[ch] = *(const half4*)(vt + (ch * 16 + r16) * 64 + vslot);
#pragma unroll
      for (int h = 0; h < NH; ++h) {
        // S^T tile: A = K (rows = keys), B = Q (cols = q)
        floatx4 s = (floatx4){0.f, 0.f, 0.f, 0.f};
        s = __builtin_amdgcn_mfma_f32_16x16x32_f16(Kh0, Qh[h][0], s, 0, 0, 0);
        s = __builtin_amdgcn_mfma_f32_16x16x32_f16(Kh1, Qh[h][1], s, 0, 0, 0);
        s = __builtin_amdgcn_mfma_f32_16x16x32_f16(Kh0, Ql[h][0], s, 0, 0, 0);
        s = __builtin_amdgcn_mfma_f32_16x16x32_f16(Kh1, Ql[h][1], s, 0, 0, 0);
        // fixed-shift softmax; P^T lands directly in 16x16x16 A-layout
        const float p0 = __builtin_amdgcn_exp2f(s[0] - Mq[h]);
        const float p1 = __builtin_amdgcn_exp2f(s[1] - Mq[h]);
        const float p2 = __builtin_amdgcn_exp2f(s[2] - Mq[h]);
        const float p3 = __builtin_amdgcn_exp2f(s[3] - Mq[h]);
        lloc[h] += (p0 + p1) + (p2 + p3);
        const half4 Pf = {(_Float16)p0, (_Float16)p1, (_Float16)p2, (_Float16)p3};
#pragma unroll
        for (int ch = 0; ch < 4; ++ch)
          O[h][ch] = __builtin_amdgcn_mfma_f32_16x16x16f16(Pf, Vf[ch],
                                                           O[h][ch], 0, 0, 0);
      }
    }
  }

  // ---- epilogue: l = quad-reduce(lloc), spread to rows, store ----
#pragma unroll
  for (int h = 0; h < NH; ++h) {
    float lt = lloc[h];
    lt += __shfl_xor(lt, 16, 64);
    lt += __shfl_xor(lt, 32, 64);       // l for q = r16, replicated
    float lq[4];
#pragma unroll
    for (int r = 0; r < 4; ++r) lq[r] = __shfl(lt, quad * 4 + r, 16);
    if (KS != 1 && r16 == 0) {
#pragma unroll
      for (int r = 0; r < 4; ++r)
        outL[(size_t)ks * BB * N + (size_t)b * N + q0 + h * 16 + quad * 4 + r] =
            lq[r];
    }
#pragma unroll
    for (int ch = 0; ch < 4; ++ch)
#pragma unroll
      for (int r = 0; r < 4; ++r) {
        const size_t qi = (size_t)b * N + q0 + h * 16 + quad * 4 + r;
        if (KS == 1) {
          outF[qi * CC + ch * 16 + r16] = O[h][ch][r] / lq[r];
        } else {
          outB[(size_t)ks * BB * N * CC + qi * CC + ch * 16 + r16] =
              f2bf_fast(O[h][ch][r]);
        }
      }
  }
}

// Merged dispatch: [0,512) scale-1 NH=2/KS=2; [512,768) scale-2 NH=1/KS=2;
// [768,800) scale-4 NH=1/KS=1. LDS 32KB -> 4 blocks/CU.
__global__ __launch_bounds__(256, 4) void attn_all(
    const unsigned short* __restrict__ fh1, const unsigned short* __restrict__ fl1,
    const unsigned short* __restrict__ fv1,
    unsigned short* __restrict__ Op1, float* __restrict__ Lp1,
    const unsigned short* __restrict__ fh2, const unsigned short* __restrict__ fl2,
    const unsigned short* __restrict__ fv2,
    unsigned short* __restrict__ Op2, float* __restrict__ Lp2,
    const unsigned short* __restrict__ fh4, const unsigned short* __restrict__ fl4,
    const unsigned short* __restrict__ fv4, float* __restrict__ a4) {
  __shared__ __align__(16) unsigned short KVT[2][2 * 4096];
  const int bid = blockIdx.x;
  if (bid < 512) {
    attn_body<2, 2>(bid, fh1, fl1, fv1, nullptr, Op1, Lp1, NPIX, &KVT[0][0]);
  } else if (bid < 768) {
    attn_body<1, 2>(bid - 512, fh2, fl2, fv2, nullptr, Op2, Lp2, 1024,
                    &KVT[0][0]);
  } else {
    attn_body<1, 1>(bid - 768, fh4, fl4, fv4, a4, nullptr, nullptr, 256,
                    &KVT[0][0]);
  }
}

// ---------------------------------------------------------------------------
// final3: FUSED scale-1 combine + scale-2 combine + output assembly.
// (unchanged from round 16)
// ---------------------------------------------------------------------------
__global__ __launch_bounds__(256) void final3_kernel(
    const float* __restrict__ xin,
    const unsigned short* __restrict__ Op1, const float* __restrict__ Lp1,
    const unsigned short* __restrict__ Op2, const float* __restrict__ Lp2,
    const float* __restrict__ a4, float* __restrict__ out) {
  __shared__ float T[64][65];
  __shared__ float T2[64][66];
  const int tid = threadIdx.x;
  const int y = blockIdx.x & 63;
  const int b = blockIdx.x >> 6;
  const size_t S1 = (size_t)BB * NPIX * CC;
  const size_t T1 = (size_t)BB * NPIX;
  const size_t S2 = (size_t)BB * 1024 * CC;
  const size_t L2 = (size_t)BB * 1024;

  const float ty2 = y * 0.5f - 0.25f;
  const int iy2 = (int)floorf(ty2);
  const float wy2 = ty2 - iy2;
  const int iy20 = max(iy2, 0), iy21 = min(iy2 + 1, 31);

  const int nl = tid >> 2;             // 0..63
  const int ck = (tid & 3) * 16;       // c chunk

  {  // ---- phase 1: combine scale-1 row y ----
    const int n = y * 64 + nl;
    float lv = Lp1[(size_t)b * NPIX + n] + Lp1[T1 + (size_t)b * NPIX + n];
    const float inv = 1.f / lv;
    float v[16];
#pragma unroll
    for (int j = 0; j < 16; ++j) v[j] = 0.f;
#pragma unroll
    for (int ks = 0; ks < 2; ++ks) {
      const unsigned short* src =
          Op1 + (size_t)ks * S1 + ((size_t)b * NPIX + n) * CC + ck;
      const ushort8 u0 = *(const ushort8*)(src);
      const ushort8 u1 = *(const ushort8*)(src + 8);
#pragma unroll
      for (int j = 0; j < 8; ++j) {
        v[j]     += bf2f(u0[j]);
        v[8 + j] += bf2f(u1[j]);
      }
    }
#pragma unroll
    for (int j = 0; j < 16; ++j) T[ck + j][nl] = v[j] * inv;
  }
  {  // ---- phase 1b: combine scale-2 rows iy20 (nl<32) / iy21 (nl>=32) ----
    const int row = nl >> 5;
    const int ix  = nl & 31;
    const int n2  = (row == 0 ? iy20 : iy21) * 32 + ix;
    float lv = Lp2[(size_t)b * 1024 + n2] + Lp2[L2 + (size_t)b * 1024 + n2];
    const float inv = 1.f / lv;
    float v[16];
#pragma unroll
    for (int j = 0; j < 16; ++j) v[j] = 0.f;
#pragma unroll
    for (int ks = 0; ks < 2; ++ks) {
      const unsigned short* src =
          Op2 + (size_t)ks * S2 + ((size_t)b * 1024 + n2) * CC + ck;
      const ushort8 u0 = *(const ushort8*)(src);
      const ushort8 u1 = *(const ushort8*)(src + 8);
#pragma unroll
      for (int j = 0; j < 8; ++j) {
        v[j]     += bf2f(u0[j]);
        v[8 + j] += bf2f(u1[j]);
      }
    }
#pragma unroll
    for (int j = 0; j < 16; ++j) T2[ck + j][nl] = v[j] * inv;
  }
  __syncthreads();

  // ---- phase 2: assemble output row ----
  const int c  = tid >> 2;
  const int xk = (tid & 3) * 16;
  const float* xrow = xin + (((size_t)b * CC + c) * HH + y) * WW;
  float* orow = out + (((size_t)b * CC + c) * HH + y) * WW;

  const float ty4 = y * 0.25f - 0.375f;
  const int iy4 = (int)floorf(ty4);
  const float wy4 = ty4 - iy4;
  const int iy40 = max(iy4, 0), iy41 = min(iy4 + 1, 15);
  const float* b4 = a4 + (size_t)b * 256 * 64 + c;

#pragma unroll
  for (int j = 0; j < 16; ++j) {
    const int xx = xk + j;
    float r = xrow[xx] + T[c][xx];
    {  // scale 2 (rows pre-combined in T2: cols 0-31 = iy20, 32-63 = iy21)
      const float tx = xx * 0.5f - 0.25f;
      const int ix = (int)floorf(tx);
      const float wx = tx - ix;
      const int ix0 = max(ix, 0), ix1 = min(ix + 1, 31);
      const float v00 = T2[c][ix0],      v01 = T2[c][ix1];
      const float v10 = T2[c][32 + ix0], v11 = T2[c][32 + ix1];
      r += (1.f-wy2)*((1.f-wx)*v00 + wx*v01) + wy2*((1.f-wx)*v10 + wx*v11);
    }
    {  // scale 4
      const float tx = xx * 0.25f - 0.375f;
      const int ix = (int)floorf(tx);
      const float wx = tx - ix;
      const int ix0 = max(ix, 0), ix1 = min(ix + 1, 15);
      const float v00 = b4[(iy40*16+ix0)*64], v01 = b4[(iy40*16+ix1)*64];
      const float v10 = b4[(iy41*16+ix0)*64], v11 = b4[(iy41*16+ix1)*64];
      r += (1.f-wy4)*((1.f-wx)*v00 + wx*v01) + wy4*((1.f-wx)*v10 + wx*v11);
    }
    orow[xx] = r;
  }
}

// ---------------------------------------------------------------------------
extern "C" void kernel_launch(void* const* d_in, const int* in_sizes, int n_in,
                              void* d_out, int out_size, void* d_ws,
                              size_t ws_size, hipStream_t stream) {
  const float* x = (const float*)d_in[0];
  const float* w = (const float*)d_in[1];
  float* out = (float*)d_out;

  unsigned short* fh1 = (unsigned short*)d_ws;            // [8][4096][64] fp16 swz
  unsigned short* fl1 = fh1 + (size_t)BB*NPIX*CC;         // fp16 lo
  unsigned short* fv1 = fl1 + (size_t)BB*NPIX*CC;         // fp16 tile-major V^T
  unsigned short* fh2 = fv1 + (size_t)BB*NPIX*CC;         // [8][1024][64]
  unsigned short* fl2 = fh2 + (size_t)BB*1024*CC;
  unsigned short* fv2 = fl2 + (size_t)BB*1024*CC;
  unsigned short* fh4 = fv2 + (size_t)BB*1024*CC;         // [8][256][64]
  unsigned short* fl4 = fh4 + (size_t)BB*256*CC;
  unsigned short* fv4 = fl4 + (size_t)BB*256*CC;
  unsigned short* Op1 = fv4 + (size_t)BB*256*CC;          // [2][8][4096][64] bf16
  float* Lp1 = (float*)(Op1 + 2*(size_t)BB*NPIX*CC);      // [2][8][4096]
  unsigned short* Op2 = (unsigned short*)(Lp1 + 2*(size_t)BB*NPIX);  // [2][8][1024][64]
  float* Lp2 = (float*)(Op2 + 2*(size_t)BB*1024*CC);      // [2][8][1024]
  float* a4  = Lp2 + 2*(size_t)BB*1024;                   // [8][256][64] fp32

  // Dead-time aliases (zero workspace growth):
  //   XT/WT (dead after conv_mfma) alias Op1/Op2 (written by attn later)
  unsigned short* xth = (unsigned short*)Op1;             // 4.19 MB
  unsigned short* xtl = xth + (size_t)BB*NPIX*CC;         // 4.19 MB (= Op1 end)
  unsigned short* wth = (unsigned short*)Op2;             // 72 KB
  unsigned short* wtl = wth + 9*64*64;                    // 72 KB

  prep_kernel<<<656, 256, 0, stream>>>(x, w, xth, xtl, wth, wtl);
  conv_mfma<<<dim3(64, 8), 256, 0, stream>>>(xth, xtl, wth, wtl, fh1, fl1, fv1);
  pools_kernel<<<2560, 256, 0, stream>>>(fh1, fl1, fh2, fl2, fv2, fh4, fl4, fv4);
  attn_all<<<800, 256, 0, stream>>>(fh1, fl1, fv1, Op1, Lp1,
                                    fh2, fl2, fv2, Op2, Lp2,
                                    fh4, fl4, fv4, a4);
  final3_kernel<<<512, 256, 0, stream>>>(x, Op1, Lp1, Op2, Lp2, a4, out);
}

// Round 18
// 154.477 us; speedup vs baseline: 1.5478x; 1.0105x over previous
//
#include <hip/hip_runtime.h>
#include <hip/hip_bf16.h>
#include <math.h>

// Problem constants: x [8,64,64,64] fp32 NCHW, W_std [64,64,3,3] fp32 OIHW.
#define BB 8
#define CC 64
#define HH 64
#define WW 64
#define NPIX (HH*WW)   // 4096
#define LOG2E 1.44269504088896340736f

typedef __attribute__((ext_vector_type(8))) short bf16x8;            // bf16 A/B frag
typedef __attribute__((ext_vector_type(8))) _Float16 half8;          // fp16 A/B frag (K=32)
typedef __attribute__((ext_vector_type(4))) _Float16 half4;          // fp16 A/B frag (K=16)
typedef __attribute__((ext_vector_type(4))) float floatx4;           // MFMA C/D frag
typedef __attribute__((ext_vector_type(8))) unsigned short ushort8;  // 16B unit

__device__ inline unsigned short f2bf(float x) {
  __hip_bfloat16 h = __float2bfloat16(x);
  return *reinterpret_cast<unsigned short*>(&h);
}
__device__ inline unsigned short f2bf_fast(float x) {
  const unsigned u = __float_as_uint(x);
  return (unsigned short)((u + 0x8000u) >> 16);
}
__device__ inline float bf2f(unsigned short u) {
  __hip_bfloat16 h = *reinterpret_cast<__hip_bfloat16*>(&u);
  return __bfloat162float(h);
}
__device__ inline unsigned short f2h(float x) {
  _Float16 h = (_Float16)x;
  return *reinterpret_cast<unsigned short*>(&h);
}
__device__ inline float h2f(unsigned short u) {
  _Float16 h = *reinterpret_cast<_Float16*>(&u);
  return (float)h;
}

// XOR swizzle for K/Q rows: 16B chunks permuted within each 128B row.
__device__ inline int swzoff(int n, int c) {
  return (((c >> 3) ^ (n & 7)) << 3) | (c & 7);
}
// V^T swizzle — ROUND 18: b64-granular. Row = channel c (64 shorts); the 16
// b64-slots are permuted by slot4 = (key>>2) ^ (c&15) so the attention's
// ds_read_b64 V-fragments spread 64 lanes exactly 4 per bank-pair (= the
// 4-cycle wave minimum; old key>>3 swizzle gave 8 -> 4.75M conflicts).
__device__ inline int swzvslot(int key, int c) {
  return ((((key >> 2) ^ (c & 15)) << 2)) | (key & 3);
}

// 16B global -> LDS DMA
#define GLD_LDS16(gp, lp)                                                     \
  __builtin_amdgcn_global_load_lds(                                           \
      (const __attribute__((address_space(1))) void*)(gp),                    \
      (__attribute__((address_space(3))) void*)(lp), 16, 0, 0)

// ---------------------------------------------------------------------------
// prep: merged xt (512 blocks) + wprep (144 blocks). XT/WT stay bf16 hi/lo.
// ---------------------------------------------------------------------------
__global__ __launch_bounds__(256) void prep_kernel(
    const float* __restrict__ xin, const float* __restrict__ w,
    unsigned short* __restrict__ xth, unsigned short* __restrict__ xtl,
    unsigned short* __restrict__ wth, unsigned short* __restrict__ wtl) {
  __shared__ float XL[64][65];
  const int bid = blockIdx.x;
  const int tid = threadIdx.x;
  if (bid < 512) {            // ---- xt ----
    const int y = bid & 63, b = bid >> 6;
    const int xq = tid & 15, cw = tid >> 4;
    const float* xb = xin + (size_t)b * CC * NPIX + y * WW;
#pragma unroll
    for (int p = 0; p < 4; ++p) {
      const int c = p * 16 + cw;
      const float4 v = *(const float4*)(xb + (size_t)c * NPIX + xq * 4);
      XL[c][xq * 4 + 0] = v.x; XL[c][xq * 4 + 1] = v.y;
      XL[c][xq * 4 + 2] = v.z; XL[c][xq * 4 + 3] = v.w;
    }
    __syncthreads();
    const int px = tid & 63, cp = tid >> 6;
    const size_t nb = ((size_t)b * NPIX + y * WW + px) * CC;
    ushort8 vh[2], vl[2];
#pragma unroll
    for (int j = 0; j < 16; ++j) {
      const float v = XL[cp * 16 + j][px];
      const unsigned short hh = f2bf(v);
      vh[j >> 3][j & 7] = hh;
      vl[j >> 3][j & 7] = f2bf(v - bf2f(hh));
    }
#pragma unroll
    for (int k = 0; k < 2; ++k) {
      const int ch = cp * 2 + k;
      const int off = ((ch ^ (px & 7)) << 3);
      *(ushort8*)(xth + nb + off) = vh[k];
      *(ushort8*)(xtl + nb + off) = vl[k];
    }
  } else {                    // ---- wprep: Laplacian folded into weights ----
    const int idx = (bid - 512) * 256 + tid;    // 9*64*64 = 36864
    const int c   = idx & 63;
    const int o   = (idx >> 6) & 63;
    const int tap = idx >> 12;
    float v = w[((o * 64 + c) * 9) + tap];
    if (o == c) {
      const float lapk[9] = {0.f, 1.f, 0.f, 1.f, -4.f, 1.f, 0.f, 1.f, 0.f};
      v += lapk[tap];
    }
    const unsigned short hi = f2bf(v);
    wth[(tap * 64 + o) * 64 + c] = hi;
    wtl[(tap * 64 + o) * 64 + c] = f2bf(v - bf2f(hi));
  }
}

// ---------------------------------------------------------------------------
// conv_mfma: implicit-GEMM conv (bf16 internals). Epilogue emits feat as
// FP16 hi/lo (fh/fl) + FP16 V^T (fv, b64-granular swizzle).
// ---------------------------------------------------------------------------
__global__ __launch_bounds__(256, 2) void conv_mfma(
    const unsigned short* __restrict__ xth,
    const unsigned short* __restrict__ xtl,
    const unsigned short* __restrict__ wth,
    const unsigned short* __restrict__ wtl,
    unsigned short* __restrict__ fh, unsigned short* __restrict__ fl,
    unsigned short* __restrict__ fv) {
  __shared__ __align__(16) unsigned short XS[6 * 4096];

  const int tid  = threadIdx.x;
  const int lane = tid & 63;
  const int wave = tid >> 6;
  const int r16  = lane & 15;
  const int quad = lane >> 4;
  const int y = blockIdx.x, b = blockIdx.y;

#pragma unroll
  for (int r = 0; r < 3; ++r) {
    const int yy = min(max(y - 1 + r, 0), HH - 1);
    const unsigned short* sh = xth + ((size_t)b * NPIX + yy * WW) * CC;
    const unsigned short* sl = xtl + ((size_t)b * NPIX + yy * WW) * CC;
    GLD_LDS16(sh + tid * 8,        &XS[r * 4096 + tid * 8]);
    GLD_LDS16(sh + 2048 + tid * 8, &XS[r * 4096 + 2048 + tid * 8]);
    GLD_LDS16(sl + tid * 8,        &XS[(3 + r) * 4096 + tid * 8]);
    GLD_LDS16(sl + 2048 + tid * 8, &XS[(3 + r) * 4096 + 2048 + tid * 8]);
  }
  __syncthreads();

  floatx4 acc[4];
#pragma unroll
  for (int t = 0; t < 4; ++t) acc[t] = (floatx4){0.f, 0.f, 0.f, 0.f};
  const bf16x8 ZF = {0, 0, 0, 0, 0, 0, 0, 0};
  const int og = wave * 16 + r16;

#pragma unroll
  for (int tap = 0; tap < 9; ++tap) {
    const int ky = tap / 3, kx = tap % 3;
    const int yy = y + ky - 1;
    if (yy < 0 || yy >= HH) continue;
    const unsigned short* wt = wth + ((tap * 64 + og) << 6);
    const unsigned short* wl = wtl + ((tap * 64 + og) << 6);
    const bf16x8 Wh0 = *(const bf16x8*)(wt + quad * 8);
    const bf16x8 Wh1 = *(const bf16x8*)(wt + 32 + quad * 8);
    const bf16x8 Wl0 = *(const bf16x8*)(wl + quad * 8);
    const bf16x8 Wl1 = *(const bf16x8*)(wl + 32 + quad * 8);
#pragma unroll
    for (int t = 0; t < 4; ++t) {
      const int px = t * 16 + r16 + kx - 1;
      const bool ok = (px >= 0) && (px < WW);
      const int pxc = ok ? px : 0;
      const int bh = ky * 4096 + pxc * 64;
      const int bl = bh + 3 * 4096;
      const int o0 = ((quad ^ (pxc & 7)) << 3);
      const int o1 = (((4 + quad) ^ (pxc & 7)) << 3);
      bf16x8 Ah0 = *(const bf16x8*)(XS + bh + o0);
      bf16x8 Ah1 = *(const bf16x8*)(XS + bh + o1);
      bf16x8 Al0 = *(const bf16x8*)(XS + bl + o0);
      bf16x8 Al1 = *(const bf16x8*)(XS + bl + o1);
      if (!ok) { Ah0 = ZF; Ah1 = ZF; Al0 = ZF; Al1 = ZF; }
      acc[t] = __builtin_amdgcn_mfma_f32_16x16x32_bf16(Ah0, Wh0, acc[t], 0, 0, 0);
      acc[t] = __builtin_amdgcn_mfma_f32_16x16x32_bf16(Ah1, Wh1, acc[t], 0, 0, 0);
      acc[t] = __builtin_amdgcn_mfma_f32_16x16x32_bf16(Ah0, Wl0, acc[t], 0, 0, 0);
      acc[t] = __builtin_amdgcn_mfma_f32_16x16x32_bf16(Ah1, Wl1, acc[t], 0, 0, 0);
      acc[t] = __builtin_amdgcn_mfma_f32_16x16x32_bf16(Al0, Wh0, acc[t], 0, 0, 0);
      acc[t] = __builtin_amdgcn_mfma_f32_16x16x32_bf16(Al1, Wh1, acc[t], 0, 0, 0);
    }
  }

#pragma unroll
  for (int t = 0; t < 4; ++t)
#pragma unroll
    for (int r = 0; r < 4; ++r) {
      const int key = t * 16 + quad * 4 + r;
      const int n = y * WW + key;
      const float v = acc[t][r];
      const unsigned short hi = f2h(v);               // fp16 hi
      const unsigned short lo = f2h(v - h2f(hi));     // fp16 lo
      fh[((size_t)b * NPIX + n) * CC + swzoff(n, og)] = hi;
      fl[((size_t)b * NPIX + n) * CC + swzoff(n, og)] = lo;
      fv[(((size_t)b * (NPIX >> 6) + y) * CC + og) * 64 + swzvslot(key, og)] =
          f2h(v);                                     // V^T fp16
    }
}

// ---------------------------------------------------------------------------
// pools: merged pool2 + pool4-direct. Reads fp16 hi/lo, writes fp16 hi/lo
// (fh/fl) + fp16 (fv).
// ---------------------------------------------------------------------------
__global__ void pools_kernel(const unsigned short* __restrict__ in_h,
                             const unsigned short* __restrict__ in_l,
                             unsigned short* __restrict__ h2,
                             unsigned short* __restrict__ l2,
                             unsigned short* __restrict__ v2,
                             unsigned short* __restrict__ h4,
                             unsigned short* __restrict__ l4,
                             unsigned short* __restrict__ v4) {
  const int bid = blockIdx.x;
  if (bid < 2048) {           // ---- pool2: 64x64 -> 32x32 ----
    const int idx = bid * 256 + threadIdx.x;
    const int c  = idx & 63;
    const int t  = idx >> 6;
    const int xo = t & 31;
    const int yo = (t >> 5) & 31;
    const int b  = t >> 10;
    const size_t ibase = (size_t)b * NPIX * CC;
    float s = 0.f;
#pragma unroll
    for (int dy = 0; dy < 2; ++dy)
#pragma unroll
      for (int dx = 0; dx < 2; ++dx) {
        const int nin = (2*yo+dy) * 64 + (2*xo+dx);
        const size_t a = ibase + (size_t)nin * CC + swzoff(nin, c);
        s += h2f(in_h[a]) + h2f(in_l[a]);
      }
    const float vv = 0.25f * s;
    const unsigned short hi = f2h(vv);
    const int nout = yo * 32 + xo;
    const size_t ob = ((size_t)b * 1024 + nout) * CC + swzoff(nout, c);
    h2[ob] = hi;
    l2[ob] = f2h(vv - h2f(hi));
    v2[(((size_t)b * 16 + (nout >> 6)) * CC + c) * 64 + swzvslot(nout & 63, c)] =
        f2h(vv);
  } else {                    // ---- pool4: 64x64 -> 16x16 (direct) ----
    const int idx = (bid - 2048) * 256 + threadIdx.x;
    const int c  = idx & 63;
    const int t  = idx >> 6;
    const int xo = t & 15;
    const int yo = (t >> 4) & 15;
    const int b  = t >> 8;
    const size_t ibase = (size_t)b * NPIX * CC;
    float s = 0.f;
#pragma unroll
    for (int dy = 0; dy < 4; ++dy)
#pragma unroll
      for (int dx = 0; dx < 4; ++dx) {
        const int nin = (4*yo+dy) * 64 + (4*xo+dx);
        const size_t a = ibase + (size_t)nin * CC + swzoff(nin, c);
        s += h2f(in_h[a]) + h2f(in_l[a]);
      }
    const float vv = 0.0625f * s;
    const unsigned short hi = f2h(vv);
    const int nout = yo * 16 + xo;
    const size_t ob = ((size_t)b * 256 + nout) * CC + swzoff(nout, c);
    h4[ob] = hi;
    l4[ob] = f2h(vv - h2f(hi));
    v4[(((size_t)b * 4 + (nout >> 6)) * CC + c) * 64 + swzvslot(nout & 63, c)] =
        f2h(vv);
  }
}

// ---------------------------------------------------------------------------
// MFMA flash attention <NH, KS> — round-17 S-transpose structure; round-18:
// b64-granular V swizzle (conflict fix) + scale-1 KS=4 for 4 blocks/CU.
// ---------------------------------------------------------------------------
template <int NH, int KS>
__device__ __forceinline__ void attn_body(
    int bid,
    const unsigned short* __restrict__ fh,
    const unsigned short* __restrict__ fl,
    const unsigned short* __restrict__ fv,
    float* __restrict__ outF, unsigned short* __restrict__ outB,
    float* __restrict__ outL, int N,
    unsigned short* KVT) {
  const int tid  = threadIdx.x;
  const int lane = tid & 63;
  const int wave = tid >> 6;
  const int b    = bid & 7;              // XCD-local batch grouping
  const int rest = bid >> 3;
  const int nq   = N / (64 * NH);
  const int qt   = rest % nq;
  const int ks   = rest / nq;            // 0..KS-1
  const int q0   = qt * (64 * NH) + wave * (16 * NH);
  const int nt   = (N >> 6) / KS;
  const int t0   = ks * nt;
  const int r16  = lane & 15;
  const int quad = lane >> 4;
  const int swb  = r16 & 7;

  const unsigned short* fhB = fh + (size_t)b * N * CC;   // fp16 K/Q hi
  const unsigned short* flB = fl + (size_t)b * N * CC;   // fp16 Q lo
  const unsigned short* fvB = fv + (size_t)b * N * CC;   // fp16 tile-major V^T

  // ---- stage first tile via DMA: 16 chunks of 512 shorts; wave takes 4 ----
  {
    const size_t tb = (size_t)t0 * 4096;
#pragma unroll
    for (int j = 0; j < 4; ++j) {
      const int cid = wave * 4 + j;
      const int arr = cid >> 3, sub = (cid & 7) << 9;
      const unsigned short* g = (arr == 0 ? fhB : fvB) + tb + sub + lane * 8;
      GLD_LDS16(g, KVT + arr * 4096 + sub + lane * 8);
    }
  }

  // ---- Q fragments per half: f = h+l, g = f*log2e, fp16 re-split, M ----
  half8 Qh[NH][2], Ql[NH][2];
  float Mq[NH];
#pragma unroll
  for (int h = 0; h < NH; ++h) {
    float Mpart = 0.f;
#pragma unroll
    for (int kss = 0; kss < 2; ++kss) {
      const size_t off = (size_t)(q0 + h * 16 + r16) * CC
                         + ((((kss << 2) + quad) ^ swb) << 3);
      const ushort8 hh = *(const ushort8*)(fhB + off);
      const ushort8 ll = *(const ushort8*)(flB + off);
      half8 sh, sl;
#pragma unroll
      for (int j = 0; j < 8; ++j) {
        const float f = h2f(hh[j]) + h2f(ll[j]);
        const float g = f * LOG2E;
        const _Float16 gh = (_Float16)g;
        sh[j] = gh;
        sl[j] = (_Float16)(g - (float)gh);
        Mpart += g * f;                  // = log2e * sum f^2 (partial)
      }
      Qh[h][kss] = sh;
      Ql[h][kss] = sl;
    }
    Mpart += __shfl_xor(Mpart, 16, 64);
    Mpart += __shfl_xor(Mpart, 32, 64);  // M for q = r16, replicated
    Mq[h] = Mpart;                       // per-lane SCALAR (q = r16)
  }

  floatx4 O[NH][4];
  float lloc[NH];
#pragma unroll
  for (int h = 0; h < NH; ++h) {
    lloc[h] = 0.f;
#pragma unroll
    for (int ch = 0; ch < 4; ++ch) O[h][ch] = (floatx4){0.f, 0.f, 0.f, 0.f};
  }

  int koff[2];
#pragma unroll
  for (int kss = 0; kss < 2; ++kss) koff[kss] = (((kss << 2) + quad) ^ swb) << 3;

  for (int t = 0; t < nt; ++t) {
    const int cur = t & 1;
    __syncthreads();                    // drains DMA for tile t, syncs block
    if (t + 1 < nt) {                   // issue DMA for tile t+1 now
      const size_t tb = (size_t)(t0 + t + 1) * 4096;
      unsigned short* dst = KVT + (cur ^ 1) * 8192;
#pragma unroll
      for (int j = 0; j < 4; ++j) {
        const int cid = wave * 4 + j;
        const int arr = cid >> 3, sub = (cid & 7) << 9;
        const unsigned short* g = (arr == 0 ? fhB : fvB) + tb + sub + lane * 8;
        GLD_LDS16(g, dst + arr * 4096 + sub + lane * 8);
      }
    }
    const unsigned short* kh = KVT + cur * 8192;   // fp16 K hi
    const unsigned short* vt = kh + 4096;          // fp16 V^T

#pragma unroll
    for (int tt = 0; tt < 4; ++tt) {
      const int kbase = (tt * 16 + r16) * 64;
      const half8 Kh0 = *(const half8*)(kh + kbase + koff[0]);
      const half8 Kh1 = *(const half8*)(kh + kbase + koff[1]);
      // V fragments for this tt: b64 at b64-granular swizzled slot
      const int vslot = (((tt * 4 + quad) ^ r16) << 2);
      half4 Vf[4];
#pragma unroll
      for (int ch = 0; ch < 4; ++ch)
        Vf[ch] = *(const half4*)(vt + (ch * 16 + r16) * 64 + vslot);
#pragma unroll
      for (int h = 0; h < NH; ++h) {
        // S^T tile: A = K (rows = keys), B = Q (cols = q)
        floatx4 s = (floatx4){0.f, 0.f, 0.f, 0.f};
        s = __builtin_amdgcn_mfma_f32_16x16x32_f16(Kh0, Qh[h][0], s, 0, 0, 0);
        s = __builtin_amdgcn_mfma_f32_16x16x32_f16(Kh1, Qh[h][1], s, 0, 0, 0);
        s = __builtin_amdgcn_mfma_f32_16x16x32_f16(Kh0, Ql[h][0], s, 0, 0, 0);
        s = __builtin_amdgcn_mfma_f32_16x16x32_f16(Kh1, Ql[h][1], s, 0, 0, 0);
        // fixed-shift softmax; P^T lands directly in 16x16x16 A-layout
        const float p0 = __builtin_amdgcn_exp2f(s[0] - Mq[h]);
        const float p1 = __builtin_amdgcn_exp2f(s[1] - Mq[h]);
        const float p2 = __builtin_amdgcn_exp2f(s[2] - Mq[h]);
        const float p3 = __builtin_amdgcn_exp2f(s[3] - Mq[h]);
        lloc[h] += (p0 + p1) + (p2 + p3);
        const half4 Pf = {(_Float16)p0, (_Float16)p1, (_Float16)p2, (_Float16)p3};
#pragma unroll
        for (int ch = 0; ch < 4; ++ch)
          O[h][ch] = __builtin_amdgcn_mfma_f32_16x16x16f16(Pf, Vf[ch],
                                                           O[h][ch], 0, 0, 0);
      }
    }
  }

  // ---- epilogue: l = reduce(lloc), spread to rows, store ----
#pragma unroll
  for (int h = 0; h < NH; ++h) {
    float lt = lloc[h];
    lt += __shfl_xor(lt, 16, 64);
    lt += __shfl_xor(lt, 32, 64);       // l for q = r16, replicated
    float lq[4];
#pragma unroll
    for (int r = 0; r < 4; ++r) lq[r] = __shfl(lt, quad * 4 + r, 16);
    if (KS != 1 && r16 == 0) {
#pragma unroll
      for (int r = 0; r < 4; ++r)
        outL[(size_t)ks * BB * N + (size_t)b * N + q0 + h * 16 + quad * 4 + r] =
            lq[r];
    }
#pragma unroll
    for (int ch = 0; ch < 4; ++ch)
#pragma unroll
      for (int r = 0; r < 4; ++r) {
        const size_t qi = (size_t)b * N + q0 + h * 16 + quad * 4 + r;
        if (KS == 1) {
          outF[qi * CC + ch * 16 + r16] = O[h][ch][r] / lq[r];
        } else {
          outB[(size_t)ks * BB * N * CC + qi * CC + ch * 16 + r16] =
              f2bf_fast(O[h][ch][r]);
        }
      }
  }
}

// Merged dispatch: [0,1024) scale-1 NH=2/KS=4; [1024,1280) scale-2 NH=1/KS=2;
// [1280,1312) scale-4 NH=1/KS=1. LDS 32KB -> 4 blocks/CU; scale-1 grid now
// 1024 blocks so 4/CU is actually reachable (round-17 occupancy was
// grid-limited at 2/CU).
__global__ __launch_bounds__(256, 4) void attn_all(
    const unsigned short* __restrict__ fh1, const unsigned short* __restrict__ fl1,
    const unsigned short* __restrict__ fv1,
    unsigned short* __restrict__ Op1, float* __restrict__ Lp1,
    const unsigned short* __restrict__ fh2, const unsigned short* __restrict__ fl2,
    const unsigned short* __restrict__ fv2,
    unsigned short* __restrict__ Op2, float* __restrict__ Lp2,
    const unsigned short* __restrict__ fh4, const unsigned short* __restrict__ fl4,
    const unsigned short* __restrict__ fv4, float* __restrict__ a4) {
  __shared__ __align__(16) unsigned short KVT[2][2 * 4096];
  const int bid = blockIdx.x;
  if (bid < 1024) {
    attn_body<2, 4>(bid, fh1, fl1, fv1, nullptr, Op1, Lp1, NPIX, &KVT[0][0]);
  } else if (bid < 1280) {
    attn_body<1, 2>(bid - 1024, fh2, fl2, fv2, nullptr, Op2, Lp2, 1024,
                    &KVT[0][0]);
  } else {
    attn_body<1, 1>(bid - 1280, fh4, fl4, fv4, a4, nullptr, nullptr, 256,
                    &KVT[0][0]);
  }
}

// ---------------------------------------------------------------------------
// final3: FUSED scale-1 combine (4 partials) + scale-2 combine (2 partials)
// + output assembly. Block = (b, y-row).
// ---------------------------------------------------------------------------
__global__ __launch_bounds__(256) void final3_kernel(
    const float* __restrict__ xin,
    const unsigned short* __restrict__ Op1, const float* __restrict__ Lp1,
    const unsigned short* __restrict__ Op2, const float* __restrict__ Lp2,
    const float* __restrict__ a4, float* __restrict__ out) {
  __shared__ float T[64][65];
  __shared__ float T2[64][66];
  const int tid = threadIdx.x;
  const int y = blockIdx.x & 63;
  const int b = blockIdx.x >> 6;
  const size_t S1 = (size_t)BB * NPIX * CC;
  const size_t T1 = (size_t)BB * NPIX;
  const size_t S2 = (size_t)BB * 1024 * CC;
  const size_t L2 = (size_t)BB * 1024;

  const float ty2 = y * 0.5f - 0.25f;
  const int iy2 = (int)floorf(ty2);
  const float wy2 = ty2 - iy2;
  const int iy20 = max(iy2, 0), iy21 = min(iy2 + 1, 31);

  const int nl = tid >> 2;             // 0..63
  const int ck = (tid & 3) * 16;       // c chunk

  {  // ---- phase 1: combine scale-1 row y (4 partials) ----
    const int n = y * 64 + nl;
    float lv = 0.f;
#pragma unroll
    for (int ks = 0; ks < 4; ++ks)
      lv += Lp1[(size_t)ks * T1 + (size_t)b * NPIX + n];
    const float inv = 1.f / lv;
    float v[16];
#pragma unroll
    for (int j = 0; j < 16; ++j) v[j] = 0.f;
#pragma unroll
    for (int ks = 0; ks < 4; ++ks) {
      const unsigned short* src =
          Op1 + (size_t)ks * S1 + ((size_t)b * NPIX + n) * CC + ck;
      const ushort8 u0 = *(const ushort8*)(src);
      const ushort8 u1 = *(const ushort8*)(src + 8);
#pragma unroll
      for (int j = 0; j < 8; ++j) {
        v[j]     += bf2f(u0[j]);
        v[8 + j] += bf2f(u1[j]);
      }
    }
#pragma unroll
    for (int j = 0; j < 16; ++j) T[ck + j][nl] = v[j] * inv;
  }
  {  // ---- phase 1b: combine scale-2 rows iy20 (nl<32) / iy21 (nl>=32) ----
    const int row = nl >> 5;
    const int ix  = nl & 31;
    const int n2  = (row == 0 ? iy20 : iy21) * 32 + ix;
    float lv = Lp2[(size_t)b * 1024 + n2] + Lp2[L2 + (size_t)b * 1024 + n2];
    const float inv = 1.f / lv;
    float v[16];
#pragma unroll
    for (int j = 0; j < 16; ++j) v[j] = 0.f;
#pragma unroll
    for (int ks = 0; ks < 2; ++ks) {
      const unsigned short* src =
          Op2 + (size_t)ks * S2 + ((size_t)b * 1024 + n2) * CC + ck;
      const ushort8 u0 = *(const ushort8*)(src);
      const ushort8 u1 = *(const ushort8*)(src + 8);
#pragma unroll
      for (int j = 0; j < 8; ++j) {
        v[j]     += bf2f(u0[j]);
        v[8 + j] += bf2f(u1[j]);
      }
    }
#pragma unroll
    for (int j = 0; j < 16; ++j) T2[ck + j][nl] = v[j] * inv;
  }
  __syncthreads();

  // ---- phase 2: assemble output row ----
  const int c  = tid >> 2;
  const int xk = (tid & 3) * 16;
  const float* xrow = xin + (((size_t)b * CC + c) * HH + y) * WW;
  float* orow = out + (((size_t)b * CC + c) * HH + y) * WW;

  const float ty4 = y * 0.25f - 0.375f;
  const int iy4 = (int)floorf(ty4);
  const float wy4 = ty4 - iy4;
  const int iy40 = max(iy4, 0), iy41 = min(iy4 + 1, 15);
  const float* b4 = a4 + (size_t)b * 256 * 64 + c;

#pragma unroll
  for (int j = 0; j < 16; ++j) {
    const int xx = xk + j;
    float r = xrow[xx] + T[c][xx];
    {  // scale 2 (rows pre-combined in T2: cols 0-31 = iy20, 32-63 = iy21)
      const float tx = xx * 0.5f - 0.25f;
      const int ix = (int)floorf(tx);
      const float wx = tx - ix;
      const int ix0 = max(ix, 0), ix1 = min(ix + 1, 31);
      const float v00 = T2[c][ix0],      v01 = T2[c][ix1];
      const float v10 = T2[c][32 + ix0], v11 = T2[c][32 + ix1];
      r += (1.f-wy2)*((1.f-wx)*v00 + wx*v01) + wy2*((1.f-wx)*v10 + wx*v11);
    }
    {  // scale 4
      const float tx = xx * 0.25f - 0.375f;
      const int ix = (int)floorf(tx);
      const float wx = tx - ix;
      const int ix0 = max(ix, 0), ix1 = min(ix + 1, 15);
      const float v00 = b4[(iy40*16+ix0)*64], v01 = b4[(iy40*16+ix1)*64];
      const float v10 = b4[(iy41*16+ix0)*64], v11 = b4[(iy41*16+ix1)*64];
      r += (1.f-wy4)*((1.f-wx)*v00 + wx*v01) + wy4*((1.f-wx)*v10 + wx*v11);
    }
    orow[xx] = r;
  }
}

// ---------------------------------------------------------------------------
extern "C" void kernel_launch(void* const* d_in, const int* in_sizes, int n_in,
                              void* d_out, int out_size, void* d_ws,
                              size_t ws_size, hipStream_t stream) {
  const float* x = (const float*)d_in[0];
  const float* w = (const float*)d_in[1];
  float* out = (float*)d_out;

  unsigned short* fh1 = (unsigned short*)d_ws;            // [8][4096][64] fp16 swz
  unsigned short* fl1 = fh1 + (size_t)BB*NPIX*CC;         // fp16 lo
  unsigned short* fv1 = fl1 + (size_t)BB*NPIX*CC;         // fp16 tile-major V^T
  unsigned short* fh2 = fv1 + (size_t)BB*NPIX*CC;         // [8][1024][64]
  unsigned short* fl2 = fh2 + (size_t)BB*1024*CC;
  unsigned short* fv2 = fl2 + (size_t)BB*1024*CC;
  unsigned short* fh4 = fv2 + (size_t)BB*1024*CC;         // [8][256][64]
  unsigned short* fl4 = fh4 + (size_t)BB*256*CC;
  unsigned short* fv4 = fl4 + (size_t)BB*256*CC;
  unsigned short* Op1 = fv4 + (size_t)BB*256*CC;          // [4][8][4096][64] bf16
  float* Lp1 = (float*)(Op1 + 4*(size_t)BB*NPIX*CC);      // [4][8][4096]
  unsigned short* Op2 = (unsigned short*)(Lp1 + 4*(size_t)BB*NPIX);  // [2][8][1024][64]
  float* Lp2 = (float*)(Op2 + 2*(size_t)BB*1024*CC);      // [2][8][1024]
  float* a4  = Lp2 + 2*(size_t)BB*1024;                   // [8][256][64] fp32

  // Dead-time aliases (zero workspace growth):
  //   XT/WT (dead after conv_mfma) alias Op1/Op2 (written by attn later)
  unsigned short* xth = (unsigned short*)Op1;             // 4.19 MB
  unsigned short* xtl = xth + (size_t)BB*NPIX*CC;         // 4.19 MB
  unsigned short* wth = (unsigned short*)Op2;             // 72 KB
  unsigned short* wtl = wth + 9*64*64;                    // 72 KB

  prep_kernel<<<656, 256, 0, stream>>>(x, w, xth, xtl, wth, wtl);
  conv_mfma<<<dim3(64, 8), 256, 0, stream>>>(xth, xtl, wth, wtl, fh1, fl1, fv1);
  pools_kernel<<<2560, 256, 0, stream>>>(fh1, fl1, fh2, fl2, fv2, fh4, fl4, fv4);
  attn_all<<<1312, 256, 0, stream>>>(fh1, fl1, fv1, Op1, Lp1,
                                     fh2, fl2, fv2, Op2, Lp2,
                                     fh4, fl4, fv4, a4);
  final3_kernel<<<512, 256, 0, stream>>>(x, Op1, Lp1, Op2, Lp2, a4, out);
}

// Round 19
// 144.549 us; speedup vs baseline: 1.6541x; 1.0687x over previous
//
#include <hip/hip_runtime.h>
#include <hip/hip_bf16.h>
#include <math.h>

// Problem constants: x [8,64,64,64] fp32 NCHW, W_std [64,64,3,3] fp32 OIHW.
#define BB 8
#define CC 64
#define HH 64
#define WW 64
#define NPIX (HH*WW)   // 4096
#define LOG2E 1.44269504088896340736f

typedef __attribute__((ext_vector_type(8))) short bf16x8;            // bf16 A/B frag
typedef __attribute__((ext_vector_type(8))) _Float16 half8;          // fp16 A/B frag (K=32)
typedef __attribute__((ext_vector_type(4))) _Float16 half4;          // fp16 A/B frag (K=16)
typedef __attribute__((ext_vector_type(4))) float floatx4;           // MFMA C/D frag
typedef __attribute__((ext_vector_type(8))) unsigned short ushort8;  // 16B unit

__device__ inline unsigned short f2bf(float x) {
  __hip_bfloat16 h = __float2bfloat16(x);
  return *reinterpret_cast<unsigned short*>(&h);
}
__device__ inline unsigned short f2bf_fast(float x) {
  const unsigned u = __float_as_uint(x);
  return (unsigned short)((u + 0x8000u) >> 16);
}
__device__ inline float bf2f(unsigned short u) {
  __hip_bfloat16 h = *reinterpret_cast<__hip_bfloat16*>(&u);
  return __bfloat162float(h);
}
__device__ inline unsigned short f2h(float x) {
  _Float16 h = (_Float16)x;
  return *reinterpret_cast<unsigned short*>(&h);
}
__device__ inline float h2f(unsigned short u) {
  _Float16 h = *reinterpret_cast<_Float16*>(&u);
  return (float)h;
}

// XOR swizzle for K/Q rows: 16B chunks permuted within each 128B row.
__device__ inline int swzoff(int n, int c) {
  return (((c >> 3) ^ (n & 7)) << 3) | (c & 7);
}
// V^T swizzle: b64-granular (round 18 — measured 4.75M -> 0 conflicts).
__device__ inline int swzvslot(int key, int c) {
  return ((((key >> 2) ^ (c & 15)) << 2)) | (key & 3);
}

// 16B global -> LDS DMA (per-lane global scatter OK; LDS dest = base+lane*16)
#define GLD_LDS16(gp, lp)                                                     \
  __builtin_amdgcn_global_load_lds(                                           \
      (const __attribute__((address_space(1))) void*)(gp),                    \
      (__attribute__((address_space(3))) void*)(lp), 16, 0, 0)

// ---------------------------------------------------------------------------
// wprep: WT[tap][o][c] bf16 hi/lo, depthwise Laplacian folded in.
// (xt is gone — round 19: conv transposes x in-kernel.)
// ---------------------------------------------------------------------------
__global__ __launch_bounds__(256) void wprep_kernel(
    const float* __restrict__ w,
    unsigned short* __restrict__ wth, unsigned short* __restrict__ wtl) {
  const int idx = blockIdx.x * 256 + threadIdx.x;   // 9*64*64 = 36864
  const int c   = idx & 63;
  const int o   = (idx >> 6) & 63;
  const int tap = idx >> 12;
  float v = w[((o * 64 + c) * 9) + tap];
  if (o == c) {
    const float lapk[9] = {0.f, 1.f, 0.f, 1.f, -4.f, 1.f, 0.f, 1.f, 0.f};
    v += lapk[tap];
  }
  const unsigned short hi = f2bf(v);
  wth[(tap * 64 + o) * 64 + c] = hi;
  wtl[(tap * 64 + o) * 64 + c] = f2bf(v - bf2f(hi));
}

// ---------------------------------------------------------------------------
// conv_mfma: implicit-GEMM conv. Round 19: reads x (fp32 NCHW) DIRECTLY —
// per row: DMA 16KB [c][x] fp32 into XLf (per-lane global scatter across
// channel rows, contiguous LDS dest), then transpose+convert to the same
// swizzled bf16 hi/lo XS layout the tap loop always used. Kills the prep-xt
// kernel (16.7MB write + 50MB re-read). LDS 48+16 = 64KB -> 2 blocks/CU.
// ---------------------------------------------------------------------------
__global__ __launch_bounds__(256, 2) void conv_mfma(
    const float* __restrict__ xin,
    const unsigned short* __restrict__ wth,
    const unsigned short* __restrict__ wtl,
    unsigned short* __restrict__ fh, unsigned short* __restrict__ fl,
    unsigned short* __restrict__ fv) {
  __shared__ __align__(16) unsigned short XS[6 * 4096];  // rows hi[0..2], lo[3..5]
  __shared__ __align__(16) float XLf[64 * 64];           // 16KB fp32 staging

  const int tid  = threadIdx.x;
  const int lane = tid & 63;
  const int wave = tid >> 6;
  const int r16  = lane & 15;
  const int quad = lane >> 4;
  const int y = blockIdx.x, b = blockIdx.y;
  const int px = tid & 63, cp = tid >> 6;

  // ---- stage 3 x-rows: DMA fp32 -> XLf, transpose+convert -> XS ----
  const float* xb = xin + (size_t)b * CC * NPIX;
#pragma unroll
  for (int r = 0; r < 3; ++r) {
    const int yy = min(max(y - 1 + r, 0), HH - 1);
    const float* xrow = xb + yy * WW;
#pragma unroll
    for (int j = 0; j < 4; ++j) {
      const int cb = (wave * 4 + j) * 4;        // 4 channel-rows per DMA
      const int cl = cb + (lane >> 4);          // this lane's channel
      const float* g = xrow + (size_t)cl * NPIX + ((lane & 15) << 2);
      GLD_LDS16(g, (char*)XLf + cb * 256 + lane * 16);
    }
    __syncthreads();                            // DMA drained, XLf ready
    ushort8 vh[2], vl[2];
#pragma unroll
    for (int j = 0; j < 16; ++j) {
      const float v = XLf[(cp * 16 + j) * 64 + px];
      const unsigned short hh = f2bf(v);
      vh[j >> 3][j & 7] = hh;
      vl[j >> 3][j & 7] = f2bf(v - bf2f(hh));
    }
    unsigned short* xsh = XS + r * 4096 + px * 64;
    unsigned short* xsl = XS + (3 + r) * 4096 + px * 64;
#pragma unroll
    for (int k = 0; k < 2; ++k) {
      const int ch = cp * 2 + k;
      const int off = ((ch ^ (px & 7)) << 3);
      *(ushort8*)(xsh + off) = vh[k];
      *(ushort8*)(xsl + off) = vl[k];
    }
    __syncthreads();                            // XLf consumed before next DMA
  }

  floatx4 acc[4];
#pragma unroll
  for (int t = 0; t < 4; ++t) acc[t] = (floatx4){0.f, 0.f, 0.f, 0.f};
  const bf16x8 ZF = {0, 0, 0, 0, 0, 0, 0, 0};
  const int og = wave * 16 + r16;

#pragma unroll
  for (int tap = 0; tap < 9; ++tap) {
    const int ky = tap / 3, kx = tap % 3;
    const int yy = y + ky - 1;
    if (yy < 0 || yy >= HH) continue;
    const unsigned short* wt = wth + ((tap * 64 + og) << 6);
    const unsigned short* wl = wtl + ((tap * 64 + og) << 6);
    const bf16x8 Wh0 = *(const bf16x8*)(wt + quad * 8);
    const bf16x8 Wh1 = *(const bf16x8*)(wt + 32 + quad * 8);
    const bf16x8 Wl0 = *(const bf16x8*)(wl + quad * 8);
    const bf16x8 Wl1 = *(const bf16x8*)(wl + 32 + quad * 8);
#pragma unroll
    for (int t = 0; t < 4; ++t) {
      const int px2 = t * 16 + r16 + kx - 1;
      const bool ok = (px2 >= 0) && (px2 < WW);
      const int pxc = ok ? px2 : 0;
      const int bh = ky * 4096 + pxc * 64;
      const int bl = bh + 3 * 4096;
      const int o0 = ((quad ^ (pxc & 7)) << 3);
      const int o1 = (((4 + quad) ^ (pxc & 7)) << 3);
      bf16x8 Ah0 = *(const bf16x8*)(XS + bh + o0);
      bf16x8 Ah1 = *(const bf16x8*)(XS + bh + o1);
      bf16x8 Al0 = *(const bf16x8*)(XS + bl + o0);
      bf16x8 Al1 = *(const bf16x8*)(XS + bl + o1);
      if (!ok) { Ah0 = ZF; Ah1 = ZF; Al0 = ZF; Al1 = ZF; }
      acc[t] = __builtin_amdgcn_mfma_f32_16x16x32_bf16(Ah0, Wh0, acc[t], 0, 0, 0);
      acc[t] = __builtin_amdgcn_mfma_f32_16x16x32_bf16(Ah1, Wh1, acc[t], 0, 0, 0);
      acc[t] = __builtin_amdgcn_mfma_f32_16x16x32_bf16(Ah0, Wl0, acc[t], 0, 0, 0);
      acc[t] = __builtin_amdgcn_mfma_f32_16x16x32_bf16(Ah1, Wl1, acc[t], 0, 0, 0);
      acc[t] = __builtin_amdgcn_mfma_f32_16x16x32_bf16(Al0, Wh0, acc[t], 0, 0, 0);
      acc[t] = __builtin_amdgcn_mfma_f32_16x16x32_bf16(Al1, Wh1, acc[t], 0, 0, 0);
    }
  }

#pragma unroll
  for (int t = 0; t < 4; ++t)
#pragma unroll
    for (int r = 0; r < 4; ++r) {
      const int key = t * 16 + quad * 4 + r;
      const int n = y * WW + key;
      const float v = acc[t][r];
      const unsigned short hi = f2h(v);               // fp16 hi
      const unsigned short lo = f2h(v - h2f(hi));     // fp16 lo
      fh[((size_t)b * NPIX + n) * CC + swzoff(n, og)] = hi;
      fl[((size_t)b * NPIX + n) * CC + swzoff(n, og)] = lo;
      fv[(((size_t)b * (NPIX >> 6) + y) * CC + og) * 64 + swzvslot(key, og)] =
          f2h(v);                                     // V^T fp16
    }
}

// ---------------------------------------------------------------------------
// pools: merged pool2 + pool4-direct (unchanged).
// ---------------------------------------------------------------------------
__global__ void pools_kernel(const unsigned short* __restrict__ in_h,
                             const unsigned short* __restrict__ in_l,
                             unsigned short* __restrict__ h2,
                             unsigned short* __restrict__ l2,
                             unsigned short* __restrict__ v2,
                             unsigned short* __restrict__ h4,
                             unsigned short* __restrict__ l4,
                             unsigned short* __restrict__ v4) {
  const int bid = blockIdx.x;
  if (bid < 2048) {           // ---- pool2: 64x64 -> 32x32 ----
    const int idx = bid * 256 + threadIdx.x;
    const int c  = idx & 63;
    const int t  = idx >> 6;
    const int xo = t & 31;
    const int yo = (t >> 5) & 31;
    const int b  = t >> 10;
    const size_t ibase = (size_t)b * NPIX * CC;
    float s = 0.f;
#pragma unroll
    for (int dy = 0; dy < 2; ++dy)
#pragma unroll
      for (int dx = 0; dx < 2; ++dx) {
        const int nin = (2*yo+dy) * 64 + (2*xo+dx);
        const size_t a = ibase + (size_t)nin * CC + swzoff(nin, c);
        s += h2f(in_h[a]) + h2f(in_l[a]);
      }
    const float vv = 0.25f * s;
    const unsigned short hi = f2h(vv);
    const int nout = yo * 32 + xo;
    const size_t ob = ((size_t)b * 1024 + nout) * CC + swzoff(nout, c);
    h2[ob] = hi;
    l2[ob] = f2h(vv - h2f(hi));
    v2[(((size_t)b * 16 + (nout >> 6)) * CC + c) * 64 + swzvslot(nout & 63, c)] =
        f2h(vv);
  } else {                    // ---- pool4: 64x64 -> 16x16 (direct) ----
    const int idx = (bid - 2048) * 256 + threadIdx.x;
    const int c  = idx & 63;
    const int t  = idx >> 6;
    const int xo = t & 15;
    const int yo = (t >> 4) & 15;
    const int b  = t >> 8;
    const size_t ibase = (size_t)b * NPIX * CC;
    float s = 0.f;
#pragma unroll
    for (int dy = 0; dy < 4; ++dy)
#pragma unroll
      for (int dx = 0; dx < 4; ++dx) {
        const int nin = (4*yo+dy) * 64 + (4*xo+dx);
        const size_t a = ibase + (size_t)nin * CC + swzoff(nin, c);
        s += h2f(in_h[a]) + h2f(in_l[a]);
      }
    const float vv = 0.0625f * s;
    const unsigned short hi = f2h(vv);
    const int nout = yo * 16 + xo;
    const size_t ob = ((size_t)b * 256 + nout) * CC + swzoff(nout, c);
    h4[ob] = hi;
    l4[ob] = f2h(vv - h2f(hi));
    v4[(((size_t)b * 4 + (nout >> 6)) * CC + c) * 64 + swzvslot(nout & 63, c)] =
        f2h(vv);
  }
}

// ---------------------------------------------------------------------------
// MFMA flash attention <NH, KS> — round-19: S = Qh·Kh ONLY (2 MFMA).
// The dropped Ql·Kh correction is the same magnitude (~2^-12·|f|^2) as the
// already-dropped Q·Kl term — keeping it bought no accuracy class. M stays
// exact fp32 (computed from f = hi+lo), so the shift never overflows.
// ---------------------------------------------------------------------------
template <int NH, int KS>
__device__ __forceinline__ void attn_body(
    int bid,
    const unsigned short* __restrict__ fh,
    const unsigned short* __restrict__ fl,
    const unsigned short* __restrict__ fv,
    float* __restrict__ outF, unsigned short* __restrict__ outB,
    float* __restrict__ outL, int N,
    unsigned short* KVT) {
  const int tid  = threadIdx.x;
  const int lane = tid & 63;
  const int wave = tid >> 6;
  const int b    = bid & 7;              // XCD-local batch grouping
  const int rest = bid >> 3;
  const int nq   = N / (64 * NH);
  const int qt   = rest % nq;
  const int ks   = rest / nq;            // 0..KS-1
  const int q0   = qt * (64 * NH) + wave * (16 * NH);
  const int nt   = (N >> 6) / KS;
  const int t0   = ks * nt;
  const int r16  = lane & 15;
  const int quad = lane >> 4;
  const int swb  = r16 & 7;

  const unsigned short* fhB = fh + (size_t)b * N * CC;   // fp16 K/Q hi
  const unsigned short* flB = fl + (size_t)b * N * CC;   // fp16 Q lo
  const unsigned short* fvB = fv + (size_t)b * N * CC;   // fp16 tile-major V^T

  // ---- stage first tile via DMA: 16 chunks of 512 shorts; wave takes 4 ----
  {
    const size_t tb = (size_t)t0 * 4096;
#pragma unroll
    for (int j = 0; j < 4; ++j) {
      const int cid = wave * 4 + j;
      const int arr = cid >> 3, sub = (cid & 7) << 9;
      const unsigned short* g = (arr == 0 ? fhB : fvB) + tb + sub + lane * 8;
      GLD_LDS16(g, KVT + arr * 4096 + sub + lane * 8);
    }
  }

  // ---- Q fragments per half: f = h+l (exact M), Qh = fp16(f*log2e) ----
  half8 Qh[NH][2];
  float Mq[NH];
#pragma unroll
  for (int h = 0; h < NH; ++h) {
    float Mpart = 0.f;
#pragma unroll
    for (int kss = 0; kss < 2; ++kss) {
      const size_t off = (size_t)(q0 + h * 16 + r16) * CC
                         + ((((kss << 2) + quad) ^ swb) << 3);
      const ushort8 hh = *(const ushort8*)(fhB + off);
      const ushort8 ll = *(const ushort8*)(flB + off);
      half8 sh;
#pragma unroll
      for (int j = 0; j < 8; ++j) {
        const float f = h2f(hh[j]) + h2f(ll[j]);
        const float g = f * LOG2E;
        sh[j] = (_Float16)g;
        Mpart += g * f;                  // = log2e * sum f^2 (partial)
      }
      Qh[h][kss] = sh;
    }
    Mpart += __shfl_xor(Mpart, 16, 64);
    Mpart += __shfl_xor(Mpart, 32, 64);  // M for q = r16, replicated
    Mq[h] = Mpart;                       // per-lane SCALAR (q = r16)
  }

  floatx4 O[NH][4];
  float lloc[NH];
#pragma unroll
  for (int h = 0; h < NH; ++h) {
    lloc[h] = 0.f;
#pragma unroll
    for (int ch = 0; ch < 4; ++ch) O[h][ch] = (floatx4){0.f, 0.f, 0.f, 0.f};
  }

  int koff[2];
#pragma unroll
  for (int kss = 0; kss < 2; ++kss) koff[kss] = (((kss << 2) + quad) ^ swb) << 3;

  for (int t = 0; t < nt; ++t) {
    const int cur = t & 1;
    __syncthreads();                    // drains DMA for tile t, syncs block
    if (t + 1 < nt) {                   // issue DMA for tile t+1 now
      const size_t tb = (size_t)(t0 + t + 1) * 4096;
      unsigned short* dst = KVT + (cur ^ 1) * 8192;
#pragma unroll
      for (int j = 0; j < 4; ++j) {
        const int cid = wave * 4 + j;
        const int arr = cid >> 3, sub = (cid & 7) << 9;
        const unsigned short* g = (arr == 0 ? fhB : fvB) + tb + sub + lane * 8;
        GLD_LDS16(g, dst + arr * 4096 + sub + lane * 8);
      }
    }
    const unsigned short* kh = KVT + cur * 8192;   // fp16 K hi
    const unsigned short* vt = kh + 4096;          // fp16 V^T

#pragma unroll
    for (int tt = 0; tt < 4; ++tt) {
      const int kbase = (tt * 16 + r16) * 64;
      const half8 Kh0 = *(const half8*)(kh + kbase + koff[0]);
      const half8 Kh1 = *(const half8*)(kh + kbase + koff[1]);
      // V fragments for this tt: b64 at b64-granular swizzled slot
      const int vslot = (((tt * 4 + quad) ^ r16) << 2);
      half4 Vf[4];
#pragma unroll
      for (int ch = 0; ch < 4; ++ch)
        Vf[ch] = *(const half4*)(vt + (ch * 16 + r16) * 64 + vslot);
#pragma unroll
      for (int h = 0; h < NH; ++h) {
        // S^T tile: A = K (rows = keys), B = Q (cols = q) — 2 MFMA
        floatx4 s = (floatx4){0.f, 0.f, 0.f, 0.f};
        s = __builtin_amdgcn_mfma_f32_16x16x32_f16(Kh0, Qh[h][0], s, 0, 0, 0);
        s = __builtin_amdgcn_mfma_f32_16x16x32_f16(Kh1, Qh[h][1], s, 0, 0, 0);
        // fixed-shift softmax; P^T lands directly in 16x16x16 A-layout
        const float p0 = __builtin_amdgcn_exp2f(s[0] - Mq[h]);
        const float p1 = __builtin_amdgcn_exp2f(s[1] - Mq[h]);
        const float p2 = __builtin_amdgcn_exp2f(s[2] - Mq[h]);
        const float p3 = __builtin_amdgcn_exp2f(s[3] - Mq[h]);
        lloc[h] += (p0 + p1) + (p2 + p3);
        const half4 Pf = {(_Float16)p0, (_Float16)p1, (_Float16)p2, (_Float16)p3};
#pragma unroll
        for (int ch = 0; ch < 4; ++ch)
          O[h][ch] = __builtin_amdgcn_mfma_f32_16x16x16f16(Pf, Vf[ch],
                                                           O[h][ch], 0, 0, 0);
      }
    }
  }

  // ---- epilogue: l = reduce(lloc), spread to rows, store ----
#pragma unroll
  for (int h = 0; h < NH; ++h) {
    float lt = lloc[h];
    lt += __shfl_xor(lt, 16, 64);
    lt += __shfl_xor(lt, 32, 64);       // l for q = r16, replicated
    float lq[4];
#pragma unroll
    for (int r = 0; r < 4; ++r) lq[r] = __shfl(lt, quad * 4 + r, 16);
    if (KS != 1 && r16 == 0) {
#pragma unroll
      for (int r = 0; r < 4; ++r)
        outL[(size_t)ks * BB * N + (size_t)b * N + q0 + h * 16 + quad * 4 + r] =
            lq[r];
    }
#pragma unroll
    for (int ch = 0; ch < 4; ++ch)
#pragma unroll
      for (int r = 0; r < 4; ++r) {
        const size_t qi = (size_t)b * N + q0 + h * 16 + quad * 4 + r;
        if (KS == 1) {
          outF[qi * CC + ch * 16 + r16] = O[h][ch][r] / lq[r];
        } else {
          outB[(size_t)ks * BB * N * CC + qi * CC + ch * 16 + r16] =
              f2bf_fast(O[h][ch][r]);
        }
      }
  }
}

// Merged dispatch: [0,1024) scale-1 NH=2/KS=4; [1024,1280) scale-2 NH=1/KS=2;
// [1280,1312) scale-4 NH=1/KS=1. LDS 32KB -> 4 blocks/CU.
__global__ __launch_bounds__(256, 4) void attn_all(
    const unsigned short* __restrict__ fh1, const unsigned short* __restrict__ fl1,
    const unsigned short* __restrict__ fv1,
    unsigned short* __restrict__ Op1, float* __restrict__ Lp1,
    const unsigned short* __restrict__ fh2, const unsigned short* __restrict__ fl2,
    const unsigned short* __restrict__ fv2,
    unsigned short* __restrict__ Op2, float* __restrict__ Lp2,
    const unsigned short* __restrict__ fh4, const unsigned short* __restrict__ fl4,
    const unsigned short* __restrict__ fv4, float* __restrict__ a4) {
  __shared__ __align__(16) unsigned short KVT[2][2 * 4096];
  const int bid = blockIdx.x;
  if (bid < 1024) {
    attn_body<2, 4>(bid, fh1, fl1, fv1, nullptr, Op1, Lp1, NPIX, &KVT[0][0]);
  } else if (bid < 1280) {
    attn_body<1, 2>(bid - 1024, fh2, fl2, fv2, nullptr, Op2, Lp2, 1024,
                    &KVT[0][0]);
  } else {
    attn_body<1, 1>(bid - 1280, fh4, fl4, fv4, a4, nullptr, nullptr, 256,
                    &KVT[0][0]);
  }
}

// ---------------------------------------------------------------------------
// final3: FUSED scale-1 combine (4 partials) + scale-2 combine (2 partials)
// + output assembly. Block = (b, y-row). (unchanged from round 18)
// ---------------------------------------------------------------------------
__global__ __launch_bounds__(256) void final3_kernel(
    const float* __restrict__ xin,
    const unsigned short* __restrict__ Op1, const float* __restrict__ Lp1,
    const unsigned short* __restrict__ Op2, const float* __restrict__ Lp2,
    const float* __restrict__ a4, float* __restrict__ out) {
  __shared__ float T[64][65];
  __shared__ float T2[64][66];
  const int tid = threadIdx.x;
  const int y = blockIdx.x & 63;
  const int b = blockIdx.x >> 6;
  const size_t S1 = (size_t)BB * NPIX * CC;
  const size_t T1 = (size_t)BB * NPIX;
  const size_t S2 = (size_t)BB * 1024 * CC;
  const size_t L2 = (size_t)BB * 1024;

  const float ty2 = y * 0.5f - 0.25f;
  const int iy2 = (int)floorf(ty2);
  const float wy2 = ty2 - iy2;
  const int iy20 = max(iy2, 0), iy21 = min(iy2 + 1, 31);

  const int nl = tid >> 2;             // 0..63
  const int ck = (tid & 3) * 16;       // c chunk

  {  // ---- phase 1: combine scale-1 row y (4 partials) ----
    const int n = y * 64 + nl;
    float lv = 0.f;
#pragma unroll
    for (int ks = 0; ks < 4; ++ks)
      lv += Lp1[(size_t)ks * T1 + (size_t)b * NPIX + n];
    const float inv = 1.f / lv;
    float v[16];
#pragma unroll
    for (int j = 0; j < 16; ++j) v[j] = 0.f;
#pragma unroll
    for (int ks = 0; ks < 4; ++ks) {
      const unsigned short* src =
          Op1 + (size_t)ks * S1 + ((size_t)b * NPIX + n) * CC + ck;
      const ushort8 u0 = *(const ushort8*)(src);
      const ushort8 u1 = *(const ushort8*)(src + 8);
#pragma unroll
      for (int j = 0; j < 8; ++j) {
        v[j]     += bf2f(u0[j]);
        v[8 + j] += bf2f(u1[j]);
      }
    }
#pragma unroll
    for (int j = 0; j < 16; ++j) T[ck + j][nl] = v[j] * inv;
  }
  {  // ---- phase 1b: combine scale-2 rows iy20 (nl<32) / iy21 (nl>=32) ----
    const int row = nl >> 5;
    const int ix  = nl & 31;
    const int n2  = (row == 0 ? iy20 : iy21) * 32 + ix;
    float lv = Lp2[(size_t)b * 1024 + n2] + Lp2[L2 + (size_t)b * 1024 + n2];
    const float inv = 1.f / lv;
    float v[16];
#pragma unroll
    for (int j = 0; j < 16; ++j) v[j] = 0.f;
#pragma unroll
    for (int ks = 0; ks < 2; ++ks) {
      const unsigned short* src =
          Op2 + (size_t)ks * S2 + ((size_t)b * 1024 + n2) * CC + ck;
      const ushort8 u0 = *(const ushort8*)(src);
      const ushort8 u1 = *(const ushort8*)(src + 8);
#pragma unroll
      for (int j = 0; j < 8; ++j) {
        v[j]     += bf2f(u0[j]);
        v[8 + j] += bf2f(u1[j]);
      }
    }
#pragma unroll
    for (int j = 0; j < 16; ++j) T2[ck + j][nl] = v[j] * inv;
  }
  __syncthreads();

  // ---- phase 2: assemble output row ----
  const int c  = tid >> 2;
  const int xk = (tid & 3) * 16;
  const float* xrow = xin + (((size_t)b * CC + c) * HH + y) * WW;
  float* orow = out + (((size_t)b * CC + c) * HH + y) * WW;

  const float ty4 = y * 0.25f - 0.375f;
  const int iy4 = (int)floorf(ty4);
  const float wy4 = ty4 - iy4;
  const int iy40 = max(iy4, 0), iy41 = min(iy4 + 1, 15);
  const float* b4 = a4 + (size_t)b * 256 * 64 + c;

#pragma unroll
  for (int j = 0; j < 16; ++j) {
    const int xx = xk + j;
    float r = xrow[xx] + T[c][xx];
    {  // scale 2 (rows pre-combined in T2: cols 0-31 = iy20, 32-63 = iy21)
      const float tx = xx * 0.5f - 0.25f;
      const int ix = (int)floorf(tx);
      const float wx = tx - ix;
      const int ix0 = max(ix, 0), ix1 = min(ix + 1, 31);
      const float v00 = T2[c][ix0],      v01 = T2[c][ix1];
      const float v10 = T2[c][32 + ix0], v11 = T2[c][32 + ix1];
      r += (1.f-wy2)*((1.f-wx)*v00 + wx*v01) + wy2*((1.f-wx)*v10 + wx*v11);
    }
    {  // scale 4
      const float tx = xx * 0.25f - 0.375f;
      const int ix = (int)floorf(tx);
      const float wx = tx - ix;
      const int ix0 = max(ix, 0), ix1 = min(ix + 1, 15);
      const float v00 = b4[(iy40*16+ix0)*64], v01 = b4[(iy40*16+ix1)*64];
      const float v10 = b4[(iy41*16+ix0)*64], v11 = b4[(iy41*16+ix1)*64];
      r += (1.f-wy4)*((1.f-wx)*v00 + wx*v01) + wy4*((1.f-wx)*v10 + wx*v11);
    }
    orow[xx] = r;
  }
}

// ---------------------------------------------------------------------------
extern "C" void kernel_launch(void* const* d_in, const int* in_sizes, int n_in,
                              void* d_out, int out_size, void* d_ws,
                              size_t ws_size, hipStream_t stream) {
  const float* x = (const float*)d_in[0];
  const float* w = (const float*)d_in[1];
  float* out = (float*)d_out;

  unsigned short* fh1 = (unsigned short*)d_ws;            // [8][4096][64] fp16 swz
  unsigned short* fl1 = fh1 + (size_t)BB*NPIX*CC;         // fp16 lo
  unsigned short* fv1 = fl1 + (size_t)BB*NPIX*CC;         // fp16 tile-major V^T
  unsigned short* fh2 = fv1 + (size_t)BB*NPIX*CC;         // [8][1024][64]
  unsigned short* fl2 = fh2 + (size_t)BB*1024*CC;
  unsigned short* fv2 = fl2 + (size_t)BB*1024*CC;
  unsigned short* fh4 = fv2 + (size_t)BB*1024*CC;         // [8][256][64]
  unsigned short* fl4 = fh4 + (size_t)BB*256*CC;
  unsigned short* fv4 = fl4 + (size_t)BB*256*CC;
  unsigned short* Op1 = fv4 + (size_t)BB*256*CC;          // [4][8][4096][64] bf16
  float* Lp1 = (float*)(Op1 + 4*(size_t)BB*NPIX*CC);      // [4][8][4096]
  unsigned short* Op2 = (unsigned short*)(Lp1 + 4*(size_t)BB*NPIX);  // [2][8][1024][64]
  float* Lp2 = (float*)(Op2 + 2*(size_t)BB*1024*CC);      // [2][8][1024]
  float* a4  = Lp2 + 2*(size_t)BB*1024;                   // [8][256][64] fp32

  // Dead-time aliases: WT (dead after conv_mfma) aliases Op2 (attn later)
  unsigned short* wth = (unsigned short*)Op2;             // 72 KB
  unsigned short* wtl = wth + 9*64*64;                    // 72 KB

  wprep_kernel<<<144, 256, 0, stream>>>(w, wth, wtl);
  conv_mfma<<<dim3(64, 8), 256, 0, stream>>>(x, wth, wtl, fh1, fl1, fv1);
  pools_kernel<<<2560, 256, 0, stream>>>(fh1, fl1, fh2, fl2, fv2, fh4, fl4, fv4);
  attn_all<<<1312, 256, 0, stream>>>(fh1, fl1, fv1, Op1, Lp1,
                                     fh2, fl2, fv2, Op2, Lp2,
                                     fh4, fl4, fv4, a4);
  final3_kernel<<<512, 256, 0, stream>>>(x, Op1, Lp1, Op2, Lp2, a4, out);
}

// Round 21
// 141.085 us; speedup vs baseline: 1.6947x; 1.0245x over previous
//
#include <hip/hip_runtime.h>
#include <hip/hip_bf16.h>
#include <math.h>

// Problem constants: x [8,64,64,64] fp32 NCHW, W_std [64,64,3,3] fp32 OIHW.
#define BB 8
#define CC 64
#define HH 64
#define WW 64
#define NPIX (HH*WW)   // 4096
#define LOG2E 1.44269504088896340736f

typedef __attribute__((ext_vector_type(8))) short bf16x8;            // bf16 A/B frag
typedef __attribute__((ext_vector_type(8))) _Float16 half8;          // fp16 A/B frag (K=32)
typedef __attribute__((ext_vector_type(4))) _Float16 half4;          // fp16 A/B frag (K=16)
typedef __attribute__((ext_vector_type(4))) float floatx4;           // MFMA C/D frag
typedef __attribute__((ext_vector_type(8))) unsigned short ushort8;  // 16B unit

__device__ inline unsigned short f2bf(float x) {
  __hip_bfloat16 h = __float2bfloat16(x);
  return *reinterpret_cast<unsigned short*>(&h);
}
__device__ inline unsigned short f2bf_fast(float x) {
  const unsigned u = __float_as_uint(x);
  return (unsigned short)((u + 0x8000u) >> 16);
}
__device__ inline float bf2f(unsigned short u) {
  __hip_bfloat16 h = *reinterpret_cast<__hip_bfloat16*>(&u);
  return __bfloat162float(h);
}
__device__ inline unsigned short f2h(float x) {
  _Float16 h = (_Float16)x;
  return *reinterpret_cast<unsigned short*>(&h);
}
__device__ inline float h2f(unsigned short u) {
  _Float16 h = *reinterpret_cast<_Float16*>(&u);
  return (float)h;
}

// XOR swizzle for K/Q rows: 16B chunks permuted within each 128B row.
__device__ inline int swzoff(int n, int c) {
  return (((c >> 3) ^ (n & 7)) << 3) | (c & 7);
}
// V^T swizzle: b64-granular (round 18 — measured 4.75M -> 0 conflicts).
__device__ inline int swzvslot(int key, int c) {
  return ((((key >> 2) ^ (c & 15)) << 2)) | (key & 3);
}

// 16B global -> LDS DMA (per-lane global scatter OK; LDS dest = base+lane*16)
#define GLD_LDS16(gp, lp)                                                     \
  __builtin_amdgcn_global_load_lds(                                           \
      (const __attribute__((address_space(1))) void*)(gp),                    \
      (__attribute__((address_space(3))) void*)(lp), 16, 0, 0)

// ---------------------------------------------------------------------------
// wprep: WT[tap][o][c] bf16 hi/lo, depthwise Laplacian folded in.
// ---------------------------------------------------------------------------
__global__ __launch_bounds__(256) void wprep_kernel(
    const float* __restrict__ w,
    unsigned short* __restrict__ wth, unsigned short* __restrict__ wtl) {
  const int idx = blockIdx.x * 256 + threadIdx.x;   // 9*64*64 = 36864
  const int c   = idx & 63;
  const int o   = (idx >> 6) & 63;
  const int tap = idx >> 12;
  float v = w[((o * 64 + c) * 9) + tap];
  if (o == c) {
    const float lapk[9] = {0.f, 1.f, 0.f, 1.f, -4.f, 1.f, 0.f, 1.f, 0.f};
    v += lapk[tap];
  }
  const unsigned short hi = f2bf(v);
  wth[(tap * 64 + o) * 64 + c] = hi;
  wtl[(tap * 64 + o) * 64 + c] = f2bf(v - bf2f(hi));
}

// ---------------------------------------------------------------------------
// conv_mfma: implicit-GEMM conv. Round 20: SINGLE-PHASE staging — DMA all
// 3 fp32 x-rows (48KB) into the XS region itself, drain ONCE, copy each
// thread's 48 values to registers, barrier, convert/write the swizzled
// bf16 hi/lo layout in place. 6 barriers -> 3, XLf gone, LDS 64 -> 48KB
// -> 3 blocks/CU.
// ---------------------------------------------------------------------------
__global__ __launch_bounds__(256, 3) void conv_mfma(
    const float* __restrict__ xin,
    const unsigned short* __restrict__ wth,
    const unsigned short* __restrict__ wtl,
    unsigned short* __restrict__ fh, unsigned short* __restrict__ fl,
    unsigned short* __restrict__ fv) {
  __shared__ __align__(16) unsigned short XS[6 * 4096];  // 48KB

  const int tid  = threadIdx.x;
  const int lane = tid & 63;
  const int wave = tid >> 6;
  const int r16  = lane & 15;
  const int quad = lane >> 4;
  const int y = blockIdx.x, b = blockIdx.y;
  const int px = tid & 63, cp = tid >> 6;

  // ---- stage: DMA 3 rows fp32 [c][x] into XS bytes [r*16KB ...] ----
  float* XSf = (float*)XS;
  const float* xb = xin + (size_t)b * CC * NPIX;
#pragma unroll
  for (int r = 0; r < 3; ++r) {
    const int yy = min(max(y - 1 + r, 0), HH - 1);
    const float* xrow = xb + yy * WW;
#pragma unroll
    for (int j = 0; j < 4; ++j) {
      const int cb = (wave * 4 + j) * 4;        // 4 channel-rows per DMA
      const int cl = cb + (lane >> 4);
      const float* g = xrow + (size_t)cl * NPIX + ((lane & 15) << 2);
      GLD_LDS16(g, (char*)XSf + r * 16384 + cb * 256 + lane * 16);
    }
  }
  __syncthreads();                              // single DMA drain

  // ---- copy this thread's 48 values to regs (fp32 region dies next) ----
  float xv[3][16];
#pragma unroll
  for (int r = 0; r < 3; ++r)
#pragma unroll
    for (int j = 0; j < 16; ++j)
      xv[r][j] = XSf[r * 4096 + (cp * 16 + j) * 64 + px];
  __syncthreads();                              // all reads done

  // ---- convert/write swizzled bf16 hi/lo in place ----
#pragma unroll
  for (int r = 0; r < 3; ++r) {
    ushort8 vh[2], vl[2];
#pragma unroll
    for (int j = 0; j < 16; ++j) {
      const float v = xv[r][j];
      const unsigned short hh = f2bf(v);
      vh[j >> 3][j & 7] = hh;
      vl[j >> 3][j & 7] = f2bf(v - bf2f(hh));
    }
    unsigned short* xsh = XS + r * 4096 + px * 64;
    unsigned short* xsl = XS + (3 + r) * 4096 + px * 64;
#pragma unroll
    for (int k = 0; k < 2; ++k) {
      const int ch = cp * 2 + k;
      const int off = ((ch ^ (px & 7)) << 3);
      *(ushort8*)(xsh + off) = vh[k];
      *(ushort8*)(xsl + off) = vl[k];
    }
  }
  __syncthreads();                              // XS ready

  floatx4 acc[4];
#pragma unroll
  for (int t = 0; t < 4; ++t) acc[t] = (floatx4){0.f, 0.f, 0.f, 0.f};
  const bf16x8 ZF = {0, 0, 0, 0, 0, 0, 0, 0};
  const int og = wave * 16 + r16;

#pragma unroll
  for (int tap = 0; tap < 9; ++tap) {
    const int ky = tap / 3, kx = tap % 3;
    const int yy = y + ky - 1;
    if (yy < 0 || yy >= HH) continue;
    const unsigned short* wt = wth + ((tap * 64 + og) << 6);
    const unsigned short* wl = wtl + ((tap * 64 + og) << 6);
    const bf16x8 Wh0 = *(const bf16x8*)(wt + quad * 8);
    const bf16x8 Wh1 = *(const bf16x8*)(wt + 32 + quad * 8);
    const bf16x8 Wl0 = *(const bf16x8*)(wl + quad * 8);
    const bf16x8 Wl1 = *(const bf16x8*)(wl + 32 + quad * 8);
#pragma unroll
    for (int t = 0; t < 4; ++t) {
      const int px2 = t * 16 + r16 + kx - 1;
      const bool ok = (px2 >= 0) && (px2 < WW);
      const int pxc = ok ? px2 : 0;
      const int bh = ky * 4096 + pxc * 64;
      const int bl = bh + 3 * 4096;
      const int o0 = ((quad ^ (pxc & 7)) << 3);
      const int o1 = (((4 + quad) ^ (pxc & 7)) << 3);
      bf16x8 Ah0 = *(const bf16x8*)(XS + bh + o0);
      bf16x8 Ah1 = *(const bf16x8*)(XS + bh + o1);
      bf16x8 Al0 = *(const bf16x8*)(XS + bl + o0);
      bf16x8 Al1 = *(const bf16x8*)(XS + bl + o1);
      if (!ok) { Ah0 = ZF; Ah1 = ZF; Al0 = ZF; Al1 = ZF; }
      acc[t] = __builtin_amdgcn_mfma_f32_16x16x32_bf16(Ah0, Wh0, acc[t], 0, 0, 0);
      acc[t] = __builtin_amdgcn_mfma_f32_16x16x32_bf16(Ah1, Wh1, acc[t], 0, 0, 0);
      acc[t] = __builtin_amdgcn_mfma_f32_16x16x32_bf16(Ah0, Wl0, acc[t], 0, 0, 0);
      acc[t] = __builtin_amdgcn_mfma_f32_16x16x32_bf16(Ah1, Wl1, acc[t], 0, 0, 0);
      acc[t] = __builtin_amdgcn_mfma_f32_16x16x32_bf16(Al0, Wh0, acc[t], 0, 0, 0);
      acc[t] = __builtin_amdgcn_mfma_f32_16x16x32_bf16(Al1, Wh1, acc[t], 0, 0, 0);
    }
  }

#pragma unroll
  for (int t = 0; t < 4; ++t)
#pragma unroll
    for (int r = 0; r < 4; ++r) {
      const int key = t * 16 + quad * 4 + r;
      const int n = y * WW + key;
      const float v = acc[t][r];
      const unsigned short hi = f2h(v);               // fp16 hi
      const unsigned short lo = f2h(v - h2f(hi));     // fp16 lo
      fh[((size_t)b * NPIX + n) * CC + swzoff(n, og)] = hi;
      fl[((size_t)b * NPIX + n) * CC + swzoff(n, og)] = lo;
      fv[(((size_t)b * (NPIX >> 6) + y) * CC + og) * 64 + swzvslot(key, og)] =
          f2h(v);                                     // V^T fp16
    }
}

// ---------------------------------------------------------------------------
// pools: merged pool2 + pool4-direct (unchanged).
// ---------------------------------------------------------------------------
__global__ void pools_kernel(const unsigned short* __restrict__ in_h,
                             const unsigned short* __restrict__ in_l,
                             unsigned short* __restrict__ h2,
                             unsigned short* __restrict__ l2,
                             unsigned short* __restrict__ v2,
                             unsigned short* __restrict__ h4,
                             unsigned short* __restrict__ l4,
                             unsigned short* __restrict__ v4) {
  const int bid = blockIdx.x;
  if (bid < 2048) {           // ---- pool2: 64x64 -> 32x32 ----
    const int idx = bid * 256 + threadIdx.x;
    const int c  = idx & 63;
    const int t  = idx >> 6;
    const int xo = t & 31;
    const int yo = (t >> 5) & 31;
    const int b  = t >> 10;
    const size_t ibase = (size_t)b * NPIX * CC;
    float s = 0.f;
#pragma unroll
    for (int dy = 0; dy < 2; ++dy)
#pragma unroll
      for (int dx = 0; dx < 2; ++dx) {
        const int nin = (2*yo+dy) * 64 + (2*xo+dx);
        const size_t a = ibase + (size_t)nin * CC + swzoff(nin, c);
        s += h2f(in_h[a]) + h2f(in_l[a]);
      }
    const float vv = 0.25f * s;
    const unsigned short hi = f2h(vv);
    const int nout = yo * 32 + xo;
    const size_t ob = ((size_t)b * 1024 + nout) * CC + swzoff(nout, c);
    h2[ob] = hi;
    l2[ob] = f2h(vv - h2f(hi));
    v2[(((size_t)b * 16 + (nout >> 6)) * CC + c) * 64 + swzvslot(nout & 63, c)] =
        f2h(vv);
  } else {                    // ---- pool4: 64x64 -> 16x16 (direct) ----
    const int idx = (bid - 2048) * 256 + threadIdx.x;
    const int c  = idx & 63;
    const int t  = idx >> 6;
    const int xo = t & 15;
    const int yo = (t >> 4) & 15;
    const int b  = t >> 8;
    const size_t ibase = (size_t)b * NPIX * CC;
    float s = 0.f;
#pragma unroll
    for (int dy = 0; dy < 4; ++dy)
#pragma unroll
      for (int dx = 0; dx < 4; ++dx) {
        const int nin = (4*yo+dy) * 64 + (4*xo+dx);
        const size_t a = ibase + (size_t)nin * CC + swzoff(nin, c);
        s += h2f(in_h[a]) + h2f(in_l[a]);
      }
    const float vv = 0.0625f * s;
    const unsigned short hi = f2h(vv);
    const int nout = yo * 16 + xo;
    const size_t ob = ((size_t)b * 256 + nout) * CC + swzoff(nout, c);
    h4[ob] = hi;
    l4[ob] = f2h(vv - h2f(hi));
    v4[(((size_t)b * 4 + (nout >> 6)) * CC + c) * 64 + swzvslot(nout & 63, c)] =
        f2h(vv);
  }
}

// ---------------------------------------------------------------------------
// MFMA flash attention <NH, KS> — round-19 structure (S = Qh·Kh only);
// round 20: pk-cvt P pack + pointer-advance DMA addressing.
// ---------------------------------------------------------------------------
template <int NH, int KS>
__device__ __forceinline__ void attn_body(
    int bid,
    const unsigned short* __restrict__ fh,
    const unsigned short* __restrict__ fl,
    const unsigned short* __restrict__ fv,
    float* __restrict__ outF, unsigned short* __restrict__ outB,
    float* __restrict__ outL, int N,
    unsigned short* KVT) {
  const int tid  = threadIdx.x;
  const int lane = tid & 63;
  const int wave = tid >> 6;
  const int b    = bid & 7;              // XCD-local batch grouping
  const int rest = bid >> 3;
  const int nq   = N / (64 * NH);
  const int qt   = rest % nq;
  const int ks   = rest / nq;            // 0..KS-1
  const int q0   = qt * (64 * NH) + wave * (16 * NH);
  const int nt   = (N >> 6) / KS;
  const int t0   = ks * nt;
  const int r16  = lane & 15;
  const int quad = lane >> 4;
  const int swb  = r16 & 7;

  const unsigned short* fhB = fh + (size_t)b * N * CC;   // fp16 K/Q hi
  const unsigned short* flB = fl + (size_t)b * N * CC;   // fp16 Q lo
  const unsigned short* fvB = fv + (size_t)b * N * CC;   // fp16 tile-major V^T

  // ---- per-wave DMA source pointers (advance by 4096 per tile) ----
  const unsigned short* gp[4];
  int ldsoff[4];
#pragma unroll
  for (int j = 0; j < 4; ++j) {
    const int cid = wave * 4 + j;
    const int arr = cid >> 3, sub = (cid & 7) << 9;
    gp[j] = (arr == 0 ? fhB : fvB) + (size_t)t0 * 4096 + sub + lane * 8;
    ldsoff[j] = arr * 4096 + sub + lane * 8;
  }
  // ---- stage first tile ----
#pragma unroll
  for (int j = 0; j < 4; ++j) {
    GLD_LDS16(gp[j], KVT + ldsoff[j]);
    gp[j] += 4096;
  }

  // ---- Q fragments per half: f = h+l (exact M), Qh = fp16(f*log2e) ----
  half8 Qh[NH][2];
  float Mq[NH];
#pragma unroll
  for (int h = 0; h < NH; ++h) {
    float Mpart = 0.f;
#pragma unroll
    for (int kss = 0; kss < 2; ++kss) {
      const size_t off = (size_t)(q0 + h * 16 + r16) * CC
                         + ((((kss << 2) + quad) ^ swb) << 3);
      const ushort8 hh = *(const ushort8*)(fhB + off);
      const ushort8 ll = *(const ushort8*)(flB + off);
      half8 sh;
#pragma unroll
      for (int j = 0; j < 8; ++j) {
        const float f = h2f(hh[j]) + h2f(ll[j]);
        const float g = f * LOG2E;
        sh[j] = (_Float16)g;
        Mpart += g * f;                  // = log2e * sum f^2 (partial)
      }
      Qh[h][kss] = sh;
    }
    Mpart += __shfl_xor(Mpart, 16, 64);
    Mpart += __shfl_xor(Mpart, 32, 64);  // M for q = r16, replicated
    Mq[h] = Mpart;                       // per-lane SCALAR (q = r16)
  }

  floatx4 O[NH][4];
  float lloc[NH];
#pragma unroll
  for (int h = 0; h < NH; ++h) {
    lloc[h] = 0.f;
#pragma unroll
    for (int ch = 0; ch < 4; ++ch) O[h][ch] = (floatx4){0.f, 0.f, 0.f, 0.f};
  }

  int koff[2];
#pragma unroll
  for (int kss = 0; kss < 2; ++kss) koff[kss] = (((kss << 2) + quad) ^ swb) << 3;

  for (int t = 0; t < nt; ++t) {
    const int cur = t & 1;
    __syncthreads();                    // drains DMA for tile t, syncs block
    if (t + 1 < nt) {                   // issue DMA for tile t+1 now
      unsigned short* dst = KVT + (cur ^ 1) * 8192;
#pragma unroll
      for (int j = 0; j < 4; ++j) {
        GLD_LDS16(gp[j], dst + ldsoff[j]);
        gp[j] += 4096;
      }
    }
    const unsigned short* kh = KVT + cur * 8192;   // fp16 K hi
    const unsigned short* vt = kh + 4096;          // fp16 V^T

#pragma unroll
    for (int tt = 0; tt < 4; ++tt) {
      const int kbase = (tt * 16 + r16) * 64;
      const half8 Kh0 = *(const half8*)(kh + kbase + koff[0]);
      const half8 Kh1 = *(const half8*)(kh + kbase + koff[1]);
      // V fragments for this tt: b64 at b64-granular swizzled slot
      const int vslot = (((tt * 4 + quad) ^ r16) << 2);
      half4 Vf[4];
#pragma unroll
      for (int ch = 0; ch < 4; ++ch)
        Vf[ch] = *(const half4*)(vt + (ch * 16 + r16) * 64 + vslot);
#pragma unroll
      for (int h = 0; h < NH; ++h) {
        // S^T tile: A = K (rows = keys), B = Q (cols = q) — 2 MFMA
        floatx4 s = (floatx4){0.f, 0.f, 0.f, 0.f};
        s = __builtin_amdgcn_mfma_f32_16x16x32_f16(Kh0, Qh[h][0], s, 0, 0, 0);
        s = __builtin_amdgcn_mfma_f32_16x16x32_f16(Kh1, Qh[h][1], s, 0, 0, 0);
        // fixed-shift softmax; P^T lands directly in 16x16x16 A-layout
        const float p0 = __builtin_amdgcn_exp2f(s[0] - Mq[h]);
        const float p1 = __builtin_amdgcn_exp2f(s[1] - Mq[h]);
        const float p2 = __builtin_amdgcn_exp2f(s[2] - Mq[h]);
        const float p3 = __builtin_amdgcn_exp2f(s[3] - Mq[h]);
        lloc[h] += (p0 + p1) + (p2 + p3);
        const auto plo = __builtin_amdgcn_cvt_pkrtz(p0, p1);  // __fp16 x2
        const auto phi = __builtin_amdgcn_cvt_pkrtz(p2, p3);
        const half4 Pf = {(_Float16)plo[0], (_Float16)plo[1],
                          (_Float16)phi[0], (_Float16)phi[1]};
#pragma unroll
        for (int ch = 0; ch < 4; ++ch)
          O[h][ch] = __builtin_amdgcn_mfma_f32_16x16x16f16(Pf, Vf[ch],
                                                           O[h][ch], 0, 0, 0);
      }
    }
  }

  // ---- epilogue: l = reduce(lloc), spread to rows, store ----
#pragma unroll
  for (int h = 0; h < NH; ++h) {
    float lt = lloc[h];
    lt += __shfl_xor(lt, 16, 64);
    lt += __shfl_xor(lt, 32, 64);       // l for q = r16, replicated
    float lq[4];
#pragma unroll
    for (int r = 0; r < 4; ++r) lq[r] = __shfl(lt, quad * 4 + r, 16);
    if (KS != 1 && r16 == 0) {
#pragma unroll
      for (int r = 0; r < 4; ++r)
        outL[(size_t)ks * BB * N + (size_t)b * N + q0 + h * 16 + quad * 4 + r] =
            lq[r];
    }
#pragma unroll
    for (int ch = 0; ch < 4; ++ch)
#pragma unroll
      for (int r = 0; r < 4; ++r) {
        const size_t qi = (size_t)b * N + q0 + h * 16 + quad * 4 + r;
        if (KS == 1) {
          outF[qi * CC + ch * 16 + r16] = O[h][ch][r] / lq[r];
        } else {
          outB[(size_t)ks * BB * N * CC + qi * CC + ch * 16 + r16] =
              f2bf_fast(O[h][ch][r]);
        }
      }
  }
}

// Merged dispatch: [0,1024) scale-1 NH=2/KS=4; [1024,1280) scale-2 NH=1/KS=2;
// [1280,1312) scale-4 NH=1/KS=1. LDS 32KB -> 4 blocks/CU.
__global__ __launch_bounds__(256, 4) void attn_all(
    const unsigned short* __restrict__ fh1, const unsigned short* __restrict__ fl1,
    const unsigned short* __restrict__ fv1,
    unsigned short* __restrict__ Op1, float* __restrict__ Lp1,
    const unsigned short* __restrict__ fh2, const unsigned short* __restrict__ fl2,
    const unsigned short* __restrict__ fv2,
    unsigned short* __restrict__ Op2, float* __restrict__ Lp2,
    const unsigned short* __restrict__ fh4, const unsigned short* __restrict__ fl4,
    const unsigned short* __restrict__ fv4, float* __restrict__ a4) {
  __shared__ __align__(16) unsigned short KVT[2][2 * 4096];
  const int bid = blockIdx.x;
  if (bid < 1024) {
    attn_body<2, 4>(bid, fh1, fl1, fv1, nullptr, Op1, Lp1, NPIX, &KVT[0][0]);
  } else if (bid < 1280) {
    attn_body<1, 2>(bid - 1024, fh2, fl2, fv2, nullptr, Op2, Lp2, 1024,
                    &KVT[0][0]);
  } else {
    attn_body<1, 1>(bid - 1280, fh4, fl4, fv4, a4, nullptr, nullptr, 256,
                    &KVT[0][0]);
  }
}

// ---------------------------------------------------------------------------
// final3: FUSED scale-1 combine (4 partials) + scale-2 combine (2 partials)
// + output assembly. Block = (b, y-row). (unchanged)
// ---------------------------------------------------------------------------
__global__ __launch_bounds__(256) void final3_kernel(
    const float* __restrict__ xin,
    const unsigned short* __restrict__ Op1, const float* __restrict__ Lp1,
    const unsigned short* __restrict__ Op2, const float* __restrict__ Lp2,
    const float* __restrict__ a4, float* __restrict__ out) {
  __shared__ float T[64][65];
  __shared__ float T2[64][66];
  const int tid = threadIdx.x;
  const int y = blockIdx.x & 63;
  const int b = blockIdx.x >> 6;
  const size_t S1 = (size_t)BB * NPIX * CC;
  const size_t T1 = (size_t)BB * NPIX;
  const size_t S2 = (size_t)BB * 1024 * CC;
  const size_t L2 = (size_t)BB * 1024;

  const float ty2 = y * 0.5f - 0.25f;
  const int iy2 = (int)floorf(ty2);
  const float wy2 = ty2 - iy2;
  const int iy20 = max(iy2, 0), iy21 = min(iy2 + 1, 31);

  const int nl = tid >> 2;             // 0..63
  const int ck = (tid & 3) * 16;       // c chunk

  {  // ---- phase 1: combine scale-1 row y (4 partials) ----
    const int n = y * 64 + nl;
    float lv = 0.f;
#pragma unroll
    for (int ks = 0; ks < 4; ++ks)
      lv += Lp1[(size_t)ks * T1 + (size_t)b * NPIX + n];
    const float inv = 1.f / lv;
    float v[16];
#pragma unroll
    for (int j = 0; j < 16; ++j) v[j] = 0.f;
#pragma unroll
    for (int ks = 0; ks < 4; ++ks) {
      const unsigned short* src =
          Op1 + (size_t)ks * S1 + ((size_t)b * NPIX + n) * CC + ck;
      const ushort8 u0 = *(const ushort8*)(src);
      const ushort8 u1 = *(const ushort8*)(src + 8);
#pragma unroll
      for (int j = 0; j < 8; ++j) {
        v[j]     += bf2f(u0[j]);
        v[8 + j] += bf2f(u1[j]);
      }
    }
#pragma unroll
    for (int j = 0; j < 16; ++j) T[ck + j][nl] = v[j] * inv;
  }
  {  // ---- phase 1b: combine scale-2 rows iy20 (nl<32) / iy21 (nl>=32) ----
    const int row = nl >> 5;
    const int ix  = nl & 31;
    const int n2  = (row == 0 ? iy20 : iy21) * 32 + ix;
    float lv = Lp2[(size_t)b * 1024 + n2] + Lp2[L2 + (size_t)b * 1024 + n2];
    const float inv = 1.f / lv;
    float v[16];
#pragma unroll
    for (int j = 0; j < 16; ++j) v[j] = 0.f;
#pragma unroll
    for (int ks = 0; ks < 2; ++ks) {
      const unsigned short* src =
          Op2 + (size_t)ks * S2 + ((size_t)b * 1024 + n2) * CC + ck;
      const ushort8 u0 = *(const ushort8*)(src);
      const ushort8 u1 = *(const ushort8*)(src + 8);
#pragma unroll
      for (int j = 0; j < 8; ++j) {
        v[j]     += bf2f(u0[j]);
        v[8 + j] += bf2f(u1[j]);
      }
    }
#pragma unroll
    for (int j = 0; j < 16; ++j) T2[ck + j][nl] = v[j] * inv;
  }
  __syncthreads();

  // ---- phase 2: assemble output row ----
  const int c  = tid >> 2;
  const int xk = (tid & 3) * 16;
  const float* xrow = xin + (((size_t)b * CC + c) * HH + y) * WW;
  float* orow = out + (((size_t)b * CC + c) * HH + y) * WW;

  const float ty4 = y * 0.25f - 0.375f;
  const int iy4 = (int)floorf(ty4);
  const float wy4 = ty4 - iy4;
  const int iy40 = max(iy4, 0), iy41 = min(iy4 + 1, 15);
  const float* b4 = a4 + (size_t)b * 256 * 64 + c;

#pragma unroll
  for (int j = 0; j < 16; ++j) {
    const int xx = xk + j;
    float r = xrow[xx] + T[c][xx];
    {  // scale 2 (rows pre-combined in T2: cols 0-31 = iy20, 32-63 = iy21)
      const float tx = xx * 0.5f - 0.25f;
      const int ix = (int)floorf(tx);
      const float wx = tx - ix;
      const int ix0 = max(ix, 0), ix1 = min(ix + 1, 31);
      const float v00 = T2[c][ix0],      v01 = T2[c][ix1];
      const float v10 = T2[c][32 + ix0], v11 = T2[c][32 + ix1];
      r += (1.f-wy2)*((1.f-wx)*v00 + wx*v01) + wy2*((1.f-wx)*v10 + wx*v11);
    }
    {  // scale 4
      const float tx = xx * 0.25f - 0.375f;
      const int ix = (int)floorf(tx);
      const float wx = tx - ix;
      const int ix0 = max(ix, 0), ix1 = min(ix + 1, 15);
      const float v00 = b4[(iy40*16+ix0)*64], v01 = b4[(iy40*16+ix1)*64];
      const float v10 = b4[(iy41*16+ix0)*64], v11 = b4[(iy41*16+ix1)*64];
      r += (1.f-wy4)*((1.f-wx)*v00 + wx*v01) + wy4*((1.f-wx)*v10 + wx*v11);
    }
    orow[xx] = r;
  }
}

// ---------------------------------------------------------------------------
extern "C" void kernel_launch(void* const* d_in, const int* in_sizes, int n_in,
                              void* d_out, int out_size, void* d_ws,
                              size_t ws_size, hipStream_t stream) {
  const float* x = (const float*)d_in[0];
  const float* w = (const float*)d_in[1];
  float* out = (float*)d_out;

  unsigned short* fh1 = (unsigned short*)d_ws;            // [8][4096][64] fp16 swz
  unsigned short* fl1 = fh1 + (size_t)BB*NPIX*CC;         // fp16 lo
  unsigned short* fv1 = fl1 + (size_t)BB*NPIX*CC;         // fp16 tile-major V^T
  unsigned short* fh2 = fv1 + (size_t)BB*NPIX*CC;         // [8][1024][64]
  unsigned short* fl2 = fh2 + (size_t)BB*1024*CC;
  unsigned short* fv2 = fl2 + (size_t)BB*1024*CC;
  unsigned short* fh4 = fv2 + (size_t)BB*1024*CC;         // [8][256][64]
  unsigned short* fl4 = fh4 + (size_t)BB*256*CC;
  unsigned short* fv4 = fl4 + (size_t)BB*256*CC;
  unsigned short* Op1 = fv4 + (size_t)BB*256*CC;          // [4][8][4096][64] bf16
  float* Lp1 = (float*)(Op1 + 4*(size_t)BB*NPIX*CC);      // [4][8][4096]
  unsigned short* Op2 = (unsigned short*)(Lp1 + 4*(size_t)BB*NPIX);  // [2][8][1024][64]
  float* Lp2 = (float*)(Op2 + 2*(size_t)BB*1024*CC);      // [2][8][1024]
  float* a4  = Lp2 + 2*(size_t)BB*1024;                   // [8][256][64] fp32

  // Dead-time aliases: WT (dead after conv_mfma) aliases Op2 (attn later)
  unsigned short* wth = (unsigned short*)Op2;             // 72 KB
  unsigned short* wtl = wth + 9*64*64;                    // 72 KB

  wprep_kernel<<<144, 256, 0, stream>>>(w, wth, wtl);
  conv_mfma<<<dim3(64, 8), 256, 0, stream>>>(x, wth, wtl, fh1, fl1, fv1);
  pools_kernel<<<2560, 256, 0, stream>>>(fh1, fl1, fh2, fl2, fv2, fh4, fl4, fv4);
  attn_all<<<1312, 256, 0, stream>>>(fh1, fl1, fv1, Op1, Lp1,
                                     fh2, fl2, fv2, Op2, Lp2,
                                     fh4, fl4, fv4, a4);
  final3_kernel<<<512, 256, 0, stream>>>(x, Op1, Lp1, Op2, Lp2, a4, out);
}